// Round 11
// baseline (134.031 us; speedup 1.0000x reference)
//
#include <hip/hip_runtime.h>
#include <hip/hip_bf16.h>
#include <type_traits>

// Problem constants
constexpr int Bc = 2, Hc = 64, Wc = 128, Cc = 256;
constexpr int HEADS = 8, KPT = 9, HIDDEN = 1024;
constexpr int HD = Cc / HEADS;           // 32
constexpr int NPIX = Hc * Wc;            // 8192
constexpr int Mrows = Bc * NPIX;         // 16384
constexpr int NQKV = 512;                // 256 (v) + 144 (off) + 72 (attn) padded to 512

typedef __attribute__((ext_vector_type(4))) float f32x4;
typedef __attribute__((ext_vector_type(8))) short bf16x8;

__device__ __forceinline__ float bf2f(unsigned short u) {
    union { unsigned int i; float f; } c; c.i = ((unsigned int)u) << 16; return c.f;
}
__device__ __forceinline__ unsigned short f2bf(float f) {
    __hip_bfloat16 h = __float2bfloat16(f);
    return *reinterpret_cast<unsigned short*>(&h);
}
__device__ __forceinline__ float gelu_exact(float x) {
    return 0.5f * x * (1.0f + erff(x * 0.70710678118654752f));
}
__device__ __forceinline__ void gl2lds16(const void* g, void* l) {
    __builtin_amdgcn_global_load_lds(
        (const __attribute__((address_space(1))) unsigned int*)g,
        (__attribute__((address_space(3))) unsigned int*)l, 16, 0, 0);
}

// ---------------- LayerNorm over C=256: one WAVE per row, float4 loads (G13) ----------------
template<typename TO>
__global__ __launch_bounds__(256) void ln_kernel(const float* __restrict__ in,
        const float* __restrict__ g, const float* __restrict__ b,
        TO* __restrict__ out) {
    const int r = blockIdx.x * 4 + (threadIdx.x >> 6);
    const int l = threadIdx.x & 63;
    const size_t base = (size_t)r * Cc + l * 4;
    const float4 v = *reinterpret_cast<const float4*>(in + base);
    float s  = v.x + v.y + v.z + v.w;
    float s2 = v.x * v.x + v.y * v.y + v.z * v.z + v.w * v.w;
    #pragma unroll
    for (int o = 32; o > 0; o >>= 1) { s += __shfl_down(s, o); s2 += __shfl_down(s2, o); }
    s = __shfl(s, 0); s2 = __shfl(s2, 0);
    const float mean = s * (1.0f / Cc);
    const float var  = s2 * (1.0f / Cc) - mean * mean;
    const float rstd = rsqrtf(var + 1e-5f);
    const float4 gv = *reinterpret_cast<const float4*>(g + l * 4);
    const float4 bv = *reinterpret_cast<const float4*>(b + l * 4);
    const float o0 = (v.x - mean) * rstd * gv.x + bv.x;
    const float o1 = (v.y - mean) * rstd * gv.y + bv.y;
    const float o2 = (v.z - mean) * rstd * gv.z + bv.z;
    const float o3 = (v.w - mean) * rstd * gv.w + bv.w;
    if constexpr (std::is_same<TO, float>::value) {
        *reinterpret_cast<float4*>(out + base) = make_float4(o0, o1, o2, o3);
    } else {
        ushort4 o;
        o.x = f2bf(o0); o.y = f2bf(o1); o.z = f2bf(o2); o.w = f2bf(o3);
        *reinterpret_cast<ushort4*>(out + base) = o;
    }
}

// ---------------- Weight prep: f32 [K,N] -> bf16 [N,K] (transposed), QKV fused+padded ----
// Also transposes depthwise weights [1024][9] -> [9][1024] f32 for coalesced loads.
__global__ __launch_bounds__(256) void prep_weights(
        const float* __restrict__ w_v, const float* __restrict__ b_v,
        const float* __restrict__ w_off, const float* __restrict__ b_off,
        const float* __restrict__ w_attn, const float* __restrict__ b_attn,
        const float* __restrict__ w_out, const float* __restrict__ w1,
        const float* __restrict__ w2, const float* __restrict__ w_dw,
        unsigned short* __restrict__ qkvT, float* __restrict__ qkvB,
        unsigned short* __restrict__ woutT, unsigned short* __restrict__ w1T,
        unsigned short* __restrict__ w2T, float* __restrict__ wdwT) {
    const int blk = blockIdx.x;
    const int t = threadIdx.x;
    if (blk < NQKV) {                      // qkvT row n, K=256
        const int n = blk;
        float val = 0.0f;
        if (n < 256)       val = w_v[t * 256 + n];
        else if (n < 400)  val = w_off[t * 144 + (n - 256)];
        else if (n < 472)  val = w_attn[t * 72 + (n - 400)];
        qkvT[n * 256 + t] = f2bf(val);
        if (t == 0) {
            float bv = 0.0f;
            if (n < 256)      bv = b_v[n];
            else if (n < 400) bv = b_off[n - 256];
            else if (n < 472) bv = b_attn[n - 400];
            qkvB[n] = bv;
        }
    } else if (blk < NQKV + 256) {         // woutT row n, K=256
        const int n = blk - NQKV;
        woutT[n * 256 + t] = f2bf(w_out[t * 256 + n]);
    } else if (blk < NQKV + 256 + 1024) {  // w1T row n, K=256
        const int n = blk - (NQKV + 256);
        w1T[n * 256 + t] = f2bf(w1[t * 1024 + n]);
    } else if (blk < NQKV + 256 + 1024 + 256) { // w2T row n, K=1024
        const int n = blk - (NQKV + 256 + 1024);
        #pragma unroll
        for (int k = t; k < 1024; k += 256)
            w2T[n * 1024 + k] = f2bf(w2[k * 256 + n]);
    } else {                               // wdwT row j (9 rows)
        const int j = blk - (NQKV + 256 + 1024 + 256);
        #pragma unroll
        for (int c = t; c < HIDDEN; c += 256)
            wdwT[j * HIDDEN + c] = w_dw[c * 9 + j];
    }
}

// ---------------- bf16 MFMA GEMM: Out[M,N] = A[M,K] @ BT[N,K]^T + bias ----------------
// Tile **64 x BN** (BM=128->64 vs R10), BK=64, 512 threads (8 waves).
// Occupancy math (R11): BN=128 -> dbuf LDS 48 KB -> 3 blocks/CU = 6 waves/SIMD;
// BN=64 -> 32 KB -> 4 blocks/CU = 8 waves/SIMD (full CU). Grids double to 1024-2048
// blocks. R9->R10 showed wave-TLP is the binding lever for these small shapes.
// Wave grid: BN=128 -> 2x4 (wave 32x32), BN=64 -> 4x2 (wave 16x32).
// Grid: blockIdx.x = row panel (fastest); col-panel id stride multiple of 8 -> same XCD.
// K-loop: counted-vmcnt 2-tile-ahead pipeline (T4). Epilogue: C-tile staged in the
// (now dead) LDS, then full-sector write-back (R9: cut WRITE 2-4x amplification).
template<int BN, bool GELU, bool RESID, typename TO>
__global__ __launch_bounds__(512) void mfma_gemm(
        const unsigned short* __restrict__ A,   // [M,K] bf16
        const unsigned short* __restrict__ BT,  // [N,K] bf16
        const float* __restrict__ bias,         // [N]
        const float* __restrict__ resid,        // [M,N] f32 (if RESID)
        TO* __restrict__ Out,                   // [M,N]
        int N, int K) {
    constexpr int BM = 64;
    constexpr int WCOLS = (BN == 128) ? 4 : 2;  // waves along N
    constexpr int WROWS = 8 / WCOLS;            // waves along M
    constexpr int MI = BM / (WROWS * 16);       // 16-row fragments per wave (2 / 1)
    constexpr int NI = BN / (WCOLS * 16);       // 16-col fragments per wave (2 / 2)
    constexpr int ACH = (BM / 8) / 8;           // A chunks per wave (1)
    constexpr int BCH = (BN / 8) / 8;           // B chunks per wave (2 / 1)
    constexpr int LA = ACH + BCH;               // per-wave loads per stage (3 / 2)
    constexpr int ABYTES = BM * 128;            // A tile bytes (8 KB)
    constexpr int BUFB = ABYTES + BN * 128;     // A + B tile per buffer
    __shared__ __align__(16) char lds[2 * BUFB];
    const int t = threadIdx.x;
    const int w = t >> 6;
    const int l = t & 63;
    const int row0 = blockIdx.x * BM;
    const int col0 = blockIdx.y * BN;
    const int wr = (w / WCOLS) * (MI * 16);     // wave row offset in tile
    const int wc = (w % WCOLS) * (NI * 16);     // wave col offset in tile

    // staging geometry: chunk = 8 rows x 64 cols (1024 B); lane l -> row c*8+l/8,
    // 16B slot (l%8); source slot is XOR-swizzled so LDS holds swizzled layout.
    const int srow = l >> 3;
    const int selem = ((l & 7) ^ srow) * 8;     // element offset of this lane's 16B

    auto stage = [&](char* buf, int k0) {
        unsigned short* As_ = (unsigned short*)buf;
        unsigned short* Bs_ = (unsigned short*)(buf + ABYTES);
        #pragma unroll
        for (int i = 0; i < ACH; ++i) {         // A tile: BM/8 chunks
            const int c = w + i * 8;
            const int row = c * 8 + srow;
            gl2lds16(A + (size_t)(row0 + row) * K + k0 + selem, As_ + c * 512);
        }
        #pragma unroll
        for (int i = 0; i < BCH; ++i) {         // B tile: BN/8 chunks
            const int c = w + i * 8;
            const int row = c * 8 + srow;
            gl2lds16(BT + (size_t)(col0 + row) * K + k0 + selem, Bs_ + c * 512);
        }
    };

    f32x4 acc[MI][NI] = {};
    const int nt = K / 64;

    // prologue: stage tiles 0 and 1 (2-deep pipeline)
    stage(lds, 0);
    stage(lds + BUFB, 64);

    for (int tt = 0; tt < nt; ++tt) {
        // wait for tile tt's DMA only; tile tt+1's LA loads may stay outstanding
        if (tt + 1 < nt) {
            if constexpr (LA == 3) asm volatile("s_waitcnt vmcnt(3)" ::: "memory");
            else                   asm volatile("s_waitcnt vmcnt(2)" ::: "memory");
        } else {
            asm volatile("s_waitcnt vmcnt(0)" ::: "memory");
        }
        __builtin_amdgcn_s_barrier();
        __builtin_amdgcn_sched_barrier(0);

        const char* Ab = lds + (size_t)(tt & 1) * BUFB;
        const char* Bb = Ab + ABYTES;
        #pragma unroll
        for (int ks = 0; ks < 2; ++ks) {
            const int kb = ks * 64 + (l >> 4) * 16;   // byte offset within 128B row
            bf16x8 af[MI], bfr[NI];
            #pragma unroll
            for (int mi = 0; mi < MI; ++mi) {
                const int row = wr + mi * 16 + (l & 15);
                af[mi] = *(const bf16x8*)(Ab + row * 128 + (kb ^ ((row & 7) << 4)));
            }
            #pragma unroll
            for (int ni = 0; ni < NI; ++ni) {
                const int row = wc + ni * 16 + (l & 15);
                bfr[ni] = *(const bf16x8*)(Bb + row * 128 + (kb ^ ((row & 7) << 4)));
            }
            #pragma unroll
            for (int mi = 0; mi < MI; ++mi)
                #pragma unroll
                for (int ni = 0; ni < NI; ++ni)
                    acc[mi][ni] = __builtin_amdgcn_mfma_f32_16x16x32_bf16(
                        af[mi], bfr[ni], acc[mi][ni], 0, 0, 0);
        }
        // all waves done reading buf[tt&1] before it is re-staged
        __builtin_amdgcn_s_barrier();
        __builtin_amdgcn_sched_barrier(0);
        if (tt + 2 < nt) stage(lds + (size_t)(tt & 1) * BUFB, (tt + 2) * 64);
    }

    // ---- epilogue phase 1: stage C-tile into LDS (256 B per row, row-XOR swizzle) ----
    // MFMA C/D layout: col=l&15, row=(l>>4)*4+reg (guide §3, m89-verified)
    const int lrow = (l >> 4) * 4;
    const int lcol = l & 15;
    #pragma unroll
    for (int ni = 0; ni < NI; ++ni) {
        const int col = wc + ni * 16 + lcol;            // tile-relative col
        const float bb = bias[col0 + col];
        #pragma unroll
        for (int mi = 0; mi < MI; ++mi) {
            #pragma unroll
            for (int r = 0; r < 4; ++r) {
                const int row = wr + mi * 16 + lrow + r;
                float v = acc[mi][ni][r] + bb;
                if constexpr (GELU) v = gelu_exact(v);
                if constexpr (std::is_same<TO, unsigned short>::value) {
                    *(unsigned short*)(lds + row * 256 + ((col * 2) ^ ((row & 7) << 4))) = f2bf(v);
                } else {
                    *(float*)(lds + row * 256 + ((col * 4) ^ ((row & 7) << 4))) = v;
                }
            }
        }
    }
    __syncthreads();
    // ---- epilogue phase 2: full-sector write-back ----
    // 16 lanes cover one complete 256 B row; every 64 B sector from one instruction.
    const int ck = t & 15;                    // 16 B chunk within the 256 B row
    #pragma unroll
    for (int it = 0; it < BM / 32; ++it) {
        const int row = (t >> 4) + it * 32;
        const int bo = ck * 16;
        if constexpr (std::is_same<TO, unsigned short>::value) {
            const int4 val = *(const int4*)(lds + row * 256 + (bo ^ ((row & 7) << 4)));
            *(int4*)(Out + (size_t)(row0 + row) * N + col0 + bo / 2) = val;
        } else {
            float4 val = *(const float4*)(lds + row * 256 + (bo ^ ((row & 7) << 4)));
            if constexpr (RESID) {
                const float4 rv = *(const float4*)(resid + (size_t)(row0 + row) * N + col0 + bo / 4);
                val.x += rv.x; val.y += rv.y; val.z += rv.z; val.w += rv.w;
            }
            *(float4*)((float*)Out + (size_t)(row0 + row) * N + col0 + bo / 4) = val;
        }
    }
}

// ---------------- Deformable sampling + softmax + aggregation (bf16 in/out) ----------------
// F = fused QKV buffer [M, 512]: cols 0-255 v, 256-399 offsets, 400-471 attn logits.
// 4 pixels per block (one wave each); lane tl: head = tl>>3, quad = tl&7 owns 4 channels.
// XCD-chunked block swizzle keeps spatially-neighboring gathers in one XCD's L2.
__global__ __launch_bounds__(256) void sample_kernel(const unsigned short* __restrict__ F,
        const float* __restrict__ refp, unsigned short* __restrict__ agg) {
    constexpr int PPB = 4;                       // pixels per block
    constexpr int nblk = Mrows / PPB;            // 4096
    const int bid = blockIdx.x;
    const int qi = (bid & 7) * (nblk / 8) + (bid >> 3);   // 4096 % 8 == 0 -> bijective
    const int m0 = qi * PPB;
    const int b = m0 / NPIX;
    const int pix0 = m0 - b * NPIX;
    const int t = threadIdx.x;
    __shared__ int4   s_idx[PPB][72];
    __shared__ float4 s_w[PPB][72];
    __shared__ float  s_lg[PPB][72];

    // phase 1: coords + bilinear corners/weights + logits (288 items on 256 threads)
    for (int idx = t; idx < PPB * 72; idx += 256) {
        const int p = idx / 72, hk = idx - p * 72;
        const int head = hk / 9, k = hk - head * 9;
        const int m = m0 + p, pix = pix0 + p;
        const size_t fb = (size_t)m * NQKV;
        const unsigned int ou = *(const unsigned int*)(F + fb + 256 + head * 18 + k * 2);
        const float ox = __uint_as_float(ou << 16);
        const float oy = __uint_as_float(ou & 0xffff0000u);
        const float2 rr = *(const float2*)(refp + ((size_t)pix * KPT + k) * 2);
        const float cx = (rr.x + ox + 1.0f) * 0.5f * (Wc - 1);
        const float cy = (rr.y + oy + 1.0f) * 0.5f * (Hc - 1);
        const float fx = floorf(cx), fy = floorf(cy);
        const float wx = cx - fx, wy = cy - fy;
        const int x0 = min(max((int)fx, 0), Wc - 1);
        const int x1 = min(max((int)fx + 1, 0), Wc - 1);
        const int y0 = min(max((int)fy, 0), Hc - 1);
        const int y1 = min(max((int)fy + 1, 0), Hc - 1);
        s_idx[p][hk] = make_int4(y0 * Wc + x0, y0 * Wc + x1, y1 * Wc + x0, y1 * Wc + x1);
        s_w[p][hk] = make_float4((1.0f - wy) * (1.0f - wx), (1.0f - wy) * wx,
                                 wy * (1.0f - wx), wy * wx);
        s_lg[p][hk] = bf2f(F[fb + 400 + hk]);
    }
    __syncthreads();
    // phase 2: softmax over k per (p, head); premultiply attn into corner weights
    for (int idx = t; idx < PPB * 72; idx += 256) {
        const int p = idx / 72, hk = idx - p * 72;
        const int h9 = (hk / 9) * 9;
        float mx = -1e30f;
        #pragma unroll
        for (int k = 0; k < 9; ++k) mx = fmaxf(mx, s_lg[p][h9 + k]);
        float sm = 0.0f;
        #pragma unroll
        for (int k = 0; k < 9; ++k) sm += __expf(s_lg[p][h9 + k] - mx);
        const float a = __expf(s_lg[p][hk] - mx) / sm;
        float4 w = s_w[p][hk];
        w.x *= a; w.y *= a; w.z *= a; w.w *= a;
        s_w[p][hk] = w;
    }
    __syncthreads();
    // phase 3: gather-accumulate, 4 channels per lane
    const int p = t >> 6, tl = t & 63;
    const int head = tl >> 3, dq = tl & 7;
    const unsigned short* vb = F + (size_t)b * NPIX * NQKV + head * HD + dq * 4;
    float a0 = 0.f, a1 = 0.f, a2 = 0.f, a3 = 0.f;
    #pragma unroll
    for (int k = 0; k < 9; ++k) {
        const int hk = head * 9 + k;
        const int4   ix = s_idx[p][hk];
        const float4 ww = s_w[p][hk];
        {
            const uint2 u = *(const uint2*)(vb + (size_t)ix.x * NQKV);
            a0 += __uint_as_float(u.x << 16) * ww.x;
            a1 += __uint_as_float(u.x & 0xffff0000u) * ww.x;
            a2 += __uint_as_float(u.y << 16) * ww.x;
            a3 += __uint_as_float(u.y & 0xffff0000u) * ww.x;
        }
        {
            const uint2 u = *(const uint2*)(vb + (size_t)ix.y * NQKV);
            a0 += __uint_as_float(u.x << 16) * ww.y;
            a1 += __uint_as_float(u.x & 0xffff0000u) * ww.y;
            a2 += __uint_as_float(u.y << 16) * ww.y;
            a3 += __uint_as_float(u.y & 0xffff0000u) * ww.y;
        }
        {
            const uint2 u = *(const uint2*)(vb + (size_t)ix.z * NQKV);
            a0 += __uint_as_float(u.x << 16) * ww.z;
            a1 += __uint_as_float(u.x & 0xffff0000u) * ww.z;
            a2 += __uint_as_float(u.y << 16) * ww.z;
            a3 += __uint_as_float(u.y & 0xffff0000u) * ww.z;
        }
        {
            const uint2 u = *(const uint2*)(vb + (size_t)ix.w * NQKV);
            a0 += __uint_as_float(u.x << 16) * ww.w;
            a1 += __uint_as_float(u.x & 0xffff0000u) * ww.w;
            a2 += __uint_as_float(u.y << 16) * ww.w;
            a3 += __uint_as_float(u.y & 0xffff0000u) * ww.w;
        }
    }
    ushort4 o;
    o.x = f2bf(a0); o.y = f2bf(a1); o.z = f2bf(a2); o.w = f2bf(a3);
    *reinterpret_cast<ushort4*>(agg + (size_t)(m0 + p) * Cc + tl * 4) = o;
}

// ---------------- Depthwise 3x3 conv (circular W, zero H) + GELU, bf16 in/out ----------------
// Quad-of-pixels per block: each block computes 4 consecutive x positions for all 1024
// channels; thread t owns channels [4t,4t+4) for all 4 outputs.
__global__ __launch_bounds__(256) void dwconv_kernel(const unsigned short* __restrict__ h,
        const float* __restrict__ wdwT, const float* __restrict__ bdw,
        unsigned short* __restrict__ h2) {
    constexpr int NQ = 4;                     // x-positions per block
    constexpr int nblk = Mrows / NQ;          // 4096
    const int bid = blockIdx.x;
    const int qi = (bid & 7) * (nblk / 8) + (bid >> 3);   // XCD-chunked swizzle (4096 % 8 == 0)
    const int m0 = qi * NQ;                   // quad never crosses a row (Wc % NQ == 0)
    const int b = m0 / NPIX;
    const int pix0 = m0 - b * NPIX;
    const int y = pix0 / Wc, x0 = pix0 - y * Wc;
    const int t = threadIdx.x;
    const int c0 = t * 4;

    float wreg[9][4];
    #pragma unroll
    for (int j = 0; j < 9; ++j) {
        const float4 wv = *reinterpret_cast<const float4*>(wdwT + j * HIDDEN + c0);
        wreg[j][0] = wv.x; wreg[j][1] = wv.y; wreg[j][2] = wv.z; wreg[j][3] = wv.w;
    }

    float acc[NQ][4] = {};
    #pragma unroll
    for (int dy = -1; dy <= 1; ++dy) {
        const int yy = y + dy;
        if (yy < 0 || yy >= Hc) continue;     // zero pad along height (block-uniform branch)
        const size_t rowbase = ((size_t)b * NPIX + (size_t)yy * Wc) * HIDDEN + c0;
        #pragma unroll
        for (int j = 0; j < NQ + 2; ++j) {    // columns x0-1 .. x0+NQ (circular)
            const int xx = (x0 + j - 1 + Wc) & (Wc - 1);
            const ushort4 hv = *reinterpret_cast<const ushort4*>(h + rowbase + (size_t)xx * HIDDEN);
            const float f0 = bf2f(hv.x), f1 = bf2f(hv.y), f2 = bf2f(hv.z), f3 = bf2f(hv.w);
            #pragma unroll
            for (int q = 0; q < NQ; ++q) {
                if (q >= j - 2 && q <= j) {   // folds to constants after unroll
                    const int wj = (dy + 1) * 3 + (j - q);
                    acc[q][0] += f0 * wreg[wj][0];
                    acc[q][1] += f1 * wreg[wj][1];
                    acc[q][2] += f2 * wreg[wj][2];
                    acc[q][3] += f3 * wreg[wj][3];
                }
            }
        }
    }
    const float4 bb = *reinterpret_cast<const float4*>(bdw + c0);
    #pragma unroll
    for (int q = 0; q < NQ; ++q) {
        ushort4 o;
        o.x = f2bf(gelu_exact(acc[q][0] + bb.x));
        o.y = f2bf(gelu_exact(acc[q][1] + bb.y));
        o.z = f2bf(gelu_exact(acc[q][2] + bb.z));
        o.w = f2bf(gelu_exact(acc[q][3] + bb.w));
        *reinterpret_cast<ushort4*>(h2 + (size_t)(m0 + q) * HIDDEN + c0) = o;
    }
}

extern "C" void kernel_launch(void* const* d_in, const int* in_sizes, int n_in,
                              void* d_out, int out_size, void* d_ws, size_t ws_size,
                              hipStream_t stream) {
    const float* x      = (const float*)d_in[0];
    const float* refp   = (const float*)d_in[1];
    const float* ln1_g  = (const float*)d_in[2];
    const float* ln1_b  = (const float*)d_in[3];
    const float* w_v    = (const float*)d_in[4];
    const float* b_v    = (const float*)d_in[5];
    const float* w_off  = (const float*)d_in[6];
    const float* b_off  = (const float*)d_in[7];
    const float* w_attn = (const float*)d_in[8];
    const float* b_attn = (const float*)d_in[9];
    const float* w_out  = (const float*)d_in[10];
    const float* b_out  = (const float*)d_in[11];
    const float* ln2_g  = (const float*)d_in[12];
    const float* ln2_b  = (const float*)d_in[13];
    const float* w1     = (const float*)d_in[14];
    const float* b1     = (const float*)d_in[15];
    const float* w_dw   = (const float*)d_in[16];
    const float* b_dw   = (const float*)d_in[17];
    const float* w2     = (const float*)d_in[18];
    const float* b2     = (const float*)d_in[19];
    float* out = (float*)d_out;

    // Workspace layout (bytes); lifetimes make the overlaps safe:
    //  [0,  8M): xn -> agg -> y          (bf16 [M,256], sequential reuse)
    //  [8, 24M): F fused qkv (bf16 [M,512]) — dead after sample_kernel
    //  [8, 40M): h (bf16 [M,1024])       — written after F is dead
    //  [40,72M): h2 (bf16 [M,1024])
    //  [72M,..): transposed bf16 weights + wdwT + fused qkv bias
    char* wsb = (char*)d_ws;
    unsigned short* xnR = (unsigned short*)(wsb);
    unsigned short* F   = (unsigned short*)(wsb + (8ull  << 20));
    unsigned short* h   = (unsigned short*)(wsb + (8ull  << 20));
    unsigned short* h2  = (unsigned short*)(wsb + (40ull << 20));
    size_t woff = 72ull << 20;
    unsigned short* qkvT = (unsigned short*)(wsb + woff); woff += (size_t)NQKV * 256 * 2;
    unsigned short* woutT= (unsigned short*)(wsb + woff); woff += 256 * 256 * 2;
    unsigned short* w1T  = (unsigned short*)(wsb + woff); woff += 1024 * 256 * 2;
    unsigned short* w2T  = (unsigned short*)(wsb + woff); woff += 256 * 1024 * 2;
    float*          wdwT = (float*)(wsb + woff);          woff += 9 * 1024 * 4;
    float*          qkvB = (float*)(wsb + woff);

    // 0. weight transpose/convert (independent of activations)
    prep_weights<<<NQKV + 256 + 1024 + 256 + 9, 256, 0, stream>>>(
        w_v, b_v, w_off, b_off, w_attn, b_attn, w_out, w1, w2, w_dw,
        qkvT, qkvB, woutT, w1T, w2T, wdwT);
    // 1. LN1 -> xn (bf16)
    ln_kernel<unsigned short><<<Mrows / 4, 256, 0, stream>>>(x, ln1_g, ln1_b, xnR);
    // 2. fused QKV GEMM: F = xn @ [w_v|w_off|w_attn] + bias  (bf16 out)
    mfma_gemm<128, false, false, unsigned short><<<dim3(Mrows / 64, NQKV / 128), 512, 0, stream>>>(
        xnR, qkvT, qkvB, nullptr, F, NQKV, 256);
    // 3. deformable sampling + softmax + aggregation -> agg (reuses xn region)
    sample_kernel<<<Mrows / 4, 256, 0, stream>>>(F, refp, xnR);
    // 4. x2 = x + agg @ w_out + b_out -> d_out (f32)
    mfma_gemm<64, false, true, float><<<dim3(Mrows / 64, 256 / 64), 512, 0, stream>>>(
        xnR, woutT, b_out, x, out, 256, 256);
    // 5. LN2 -> y (bf16, reuses xn region)
    ln_kernel<unsigned short><<<Mrows / 4, 256, 0, stream>>>(out, ln2_g, ln2_b, xnR);
    // 6. h = gelu(y @ w1 + b1) (bf16)
    mfma_gemm<128, true, false, unsigned short><<<dim3(Mrows / 64, 1024 / 128), 512, 0, stream>>>(
        xnR, w1T, b1, nullptr, h, 1024, 256);
    // 7. depthwise conv + gelu -> h2 (bf16)
    dwconv_kernel<<<Mrows / 4, 256, 0, stream>>>(h, wdwT, b_dw, h2);
    // 8. out = x2 + h2 @ w2 + b2 (f32, in-place residual)
    mfma_gemm<64, false, true, float><<<dim3(Mrows / 64, 256 / 64), 512, 0, stream>>>(
        h2, w2T, b2, out, out, 256, 1024);
}

// Round 13
// 127.682 us; speedup vs baseline: 1.0497x; 1.0497x over previous
//
#include <hip/hip_runtime.h>
#include <hip/hip_bf16.h>
#include <type_traits>

// Problem constants
constexpr int Bc = 2, Hc = 64, Wc = 128, Cc = 256;
constexpr int HEADS = 8, KPT = 9, HIDDEN = 1024;
constexpr int HD = Cc / HEADS;           // 32
constexpr int NPIX = Hc * Wc;            // 8192
constexpr int Mrows = Bc * NPIX;         // 16384
constexpr int NQKV = 512;                // 256 (v) + 144 (off) + 72 (attn) padded to 512

typedef __attribute__((ext_vector_type(4))) float f32x4;
typedef __attribute__((ext_vector_type(8))) short bf16x8;

__device__ __forceinline__ float bf2f(unsigned short u) {
    union { unsigned int i; float f; } c; c.i = ((unsigned int)u) << 16; return c.f;
}
__device__ __forceinline__ unsigned short f2bf(float f) {
    __hip_bfloat16 h = __float2bfloat16(f);
    return *reinterpret_cast<unsigned short*>(&h);
}
__device__ __forceinline__ float gelu_exact(float x) {
    return 0.5f * x * (1.0f + erff(x * 0.70710678118654752f));
}
__device__ __forceinline__ void gl2lds16(const void* g, void* l) {
    __builtin_amdgcn_global_load_lds(
        (const __attribute__((address_space(1))) unsigned int*)g,
        (__attribute__((address_space(3))) unsigned int*)l, 16, 0, 0);
}

// ---------------- Merged: LN1 (wave per row) + weight prep, one launch ----------------
// blocks [0, Mrows/4): LN1; blocks [Mrows/4, +2057): weight transpose/convert.
__global__ __launch_bounds__(256) void prepln_kernel(
        const float* __restrict__ x, const float* __restrict__ ln1_g,
        const float* __restrict__ ln1_b, unsigned short* __restrict__ xn,
        const float* __restrict__ w_v, const float* __restrict__ b_v,
        const float* __restrict__ w_off, const float* __restrict__ b_off,
        const float* __restrict__ w_attn, const float* __restrict__ b_attn,
        const float* __restrict__ w_out, const float* __restrict__ w1,
        const float* __restrict__ w2, const float* __restrict__ w_dw,
        unsigned short* __restrict__ qkvT, float* __restrict__ qkvB,
        unsigned short* __restrict__ woutT, unsigned short* __restrict__ w1T,
        unsigned short* __restrict__ w2T, float* __restrict__ wdwT) {
    const int t = threadIdx.x;
    if (blockIdx.x < Mrows / 4) {              // ---- LN1: 4 rows per block, wave/row ----
        const int r = blockIdx.x * 4 + (t >> 6);
        const int l = t & 63;
        const size_t base = (size_t)r * Cc + l * 4;
        const float4 v = *reinterpret_cast<const float4*>(x + base);
        float s  = v.x + v.y + v.z + v.w;
        float s2 = v.x * v.x + v.y * v.y + v.z * v.z + v.w * v.w;
        #pragma unroll
        for (int o = 32; o > 0; o >>= 1) { s += __shfl_down(s, o); s2 += __shfl_down(s2, o); }
        s = __shfl(s, 0); s2 = __shfl(s2, 0);
        const float mean = s * (1.0f / Cc);
        const float rstd = rsqrtf(s2 * (1.0f / Cc) - mean * mean + 1e-5f);
        const float4 gv = *reinterpret_cast<const float4*>(ln1_g + l * 4);
        const float4 bv = *reinterpret_cast<const float4*>(ln1_b + l * 4);
        ushort4 o;
        o.x = f2bf((v.x - mean) * rstd * gv.x + bv.x);
        o.y = f2bf((v.y - mean) * rstd * gv.y + bv.y);
        o.z = f2bf((v.z - mean) * rstd * gv.z + bv.z);
        o.w = f2bf((v.w - mean) * rstd * gv.w + bv.w);
        *reinterpret_cast<ushort4*>(xn + base) = o;
        return;
    }
    const int blk = blockIdx.x - Mrows / 4;    // ---- weight prep ----
    if (blk < NQKV) {                      // qkvT row n, K=256
        const int n = blk;
        float val = 0.0f;
        if (n < 256)       val = w_v[t * 256 + n];
        else if (n < 400)  val = w_off[t * 144 + (n - 256)];
        else if (n < 472)  val = w_attn[t * 72 + (n - 400)];
        qkvT[n * 256 + t] = f2bf(val);
        if (t == 0) {
            float bv = 0.0f;
            if (n < 256)      bv = b_v[n];
            else if (n < 400) bv = b_off[n - 256];
            else if (n < 472) bv = b_attn[n - 400];
            qkvB[n] = bv;
        }
    } else if (blk < NQKV + 256) {         // woutT row n, K=256
        const int n = blk - NQKV;
        woutT[n * 256 + t] = f2bf(w_out[t * 256 + n]);
    } else if (blk < NQKV + 256 + 1024) {  // w1T row n, K=256
        const int n = blk - (NQKV + 256);
        w1T[n * 256 + t] = f2bf(w1[t * 1024 + n]);
    } else if (blk < NQKV + 256 + 1024 + 256) { // w2T row n, K=1024
        const int n = blk - (NQKV + 256 + 1024);
        #pragma unroll
        for (int k = t; k < 1024; k += 256)
            w2T[n * 1024 + k] = f2bf(w2[k * 256 + n]);
    } else {                               // wdwT row j (9 rows)
        const int j = blk - (NQKV + 256 + 1024 + 256);
        #pragma unroll
        for (int c = t; c < HIDDEN; c += 256)
            wdwT[j * HIDDEN + c] = w_dw[c * 9 + j];
    }
}

// ---------------- bf16 MFMA GEMM (R10 geometry): Out[M,N] = A @ BT^T + bias ----------------
// Tile 128 x BN, BK=64, 512 threads (8 waves) — best measured config (R10: 132.4 us).
// K-loop: counted-vmcnt 2-tile-ahead pipeline (T4). Epilogue: C-tile staged in dead
// LDS, full-sector write-back (R9: removed 2-4x WRITE amplification).
template<int BN, bool GELU, bool RESID, typename TO>
__global__ __launch_bounds__(512) void mfma_gemm(
        const unsigned short* __restrict__ A,   // [M,K] bf16
        const unsigned short* __restrict__ BT,  // [N,K] bf16
        const float* __restrict__ bias,         // [N]
        const float* __restrict__ resid,        // [M,N] f32 (if RESID)
        TO* __restrict__ Out,                   // [M,N]
        int N, int K) {
    constexpr int WCOLS = (BN == 128) ? 4 : 2;  // waves along N
    constexpr int WROWS = 8 / WCOLS;            // waves along M
    constexpr int MI = 128 / (WROWS * 16);      // 16-row fragments per wave
    constexpr int NI = BN / (WCOLS * 16);       // 16-col fragments per wave
    constexpr int ACH = 2;                      // A chunks staged per wave (16 total)
    constexpr int BCH = (BN / 8) / 8;           // B chunks per wave (2 or 1)
    constexpr int LA = ACH + BCH;               // per-wave loads per stage
    constexpr int BUFB = 16384 + BN * 128;      // A tile 16 KB + B tile
    __shared__ __align__(16) char lds[2 * BUFB];
    const int t = threadIdx.x;
    const int w = t >> 6;
    const int l = t & 63;
    const int row0 = blockIdx.x * 128;
    const int col0 = blockIdx.y * BN;
    const int wr = (w / WCOLS) * (MI * 16);     // wave row offset in tile
    const int wc = (w % WCOLS) * (NI * 16);     // wave col offset in tile

    const int srow = l >> 3;
    const int selem = ((l & 7) ^ srow) * 8;     // XOR-swizzled source slot

    auto stage = [&](char* buf, int k0) {
        unsigned short* As_ = (unsigned short*)buf;
        unsigned short* Bs_ = (unsigned short*)(buf + 16384);
        #pragma unroll
        for (int i = 0; i < ACH; ++i) {         // A tile: 16 chunks, 2 per wave
            const int c = w + i * 8;
            const int row = c * 8 + srow;
            gl2lds16(A + (size_t)(row0 + row) * K + k0 + selem, As_ + c * 512);
        }
        #pragma unroll
        for (int i = 0; i < BCH; ++i) {         // B tile: BN/8 chunks
            const int c = w + i * 8;
            const int row = c * 8 + srow;
            gl2lds16(BT + (size_t)(col0 + row) * K + k0 + selem, Bs_ + c * 512);
        }
    };

    f32x4 acc[MI][NI] = {};
    const int nt = K / 64;

    stage(lds, 0);
    stage(lds + BUFB, 64);

    for (int tt = 0; tt < nt; ++tt) {
        if (tt + 1 < nt) {
            if constexpr (LA == 4) asm volatile("s_waitcnt vmcnt(4)" ::: "memory");
            else                   asm volatile("s_waitcnt vmcnt(3)" ::: "memory");
        } else {
            asm volatile("s_waitcnt vmcnt(0)" ::: "memory");
        }
        __builtin_amdgcn_s_barrier();
        __builtin_amdgcn_sched_barrier(0);

        const char* Ab = lds + (size_t)(tt & 1) * BUFB;
        const char* Bb = Ab + 16384;
        #pragma unroll
        for (int ks = 0; ks < 2; ++ks) {
            const int kb = ks * 64 + (l >> 4) * 16;
            bf16x8 af[MI], bfr[NI];
            #pragma unroll
            for (int mi = 0; mi < MI; ++mi) {
                const int row = wr + mi * 16 + (l & 15);
                af[mi] = *(const bf16x8*)(Ab + row * 128 + (kb ^ ((row & 7) << 4)));
            }
            #pragma unroll
            for (int ni = 0; ni < NI; ++ni) {
                const int row = wc + ni * 16 + (l & 15);
                bfr[ni] = *(const bf16x8*)(Bb + row * 128 + (kb ^ ((row & 7) << 4)));
            }
            #pragma unroll
            for (int mi = 0; mi < MI; ++mi)
                #pragma unroll
                for (int ni = 0; ni < NI; ++ni)
                    acc[mi][ni] = __builtin_amdgcn_mfma_f32_16x16x32_bf16(
                        af[mi], bfr[ni], acc[mi][ni], 0, 0, 0);
        }
        __builtin_amdgcn_s_barrier();
        __builtin_amdgcn_sched_barrier(0);
        if (tt + 2 < nt) stage(lds + (size_t)(tt & 1) * BUFB, (tt + 2) * 64);
    }

    // epilogue 1: C-tile to LDS (256 B/row, row-XOR swizzle); C/D layout per guide §3
    const int lrow = (l >> 4) * 4;
    const int lcol = l & 15;
    #pragma unroll
    for (int ni = 0; ni < NI; ++ni) {
        const int col = wc + ni * 16 + lcol;
        const float bb = bias[col0 + col];
        #pragma unroll
        for (int mi = 0; mi < MI; ++mi) {
            #pragma unroll
            for (int r = 0; r < 4; ++r) {
                const int row = wr + mi * 16 + lrow + r;
                float v = acc[mi][ni][r] + bb;
                if constexpr (GELU) v = gelu_exact(v);
                if constexpr (std::is_same<TO, unsigned short>::value) {
                    *(unsigned short*)(lds + row * 256 + ((col * 2) ^ ((row & 7) << 4))) = f2bf(v);
                } else {
                    *(float*)(lds + row * 256 + ((col * 4) ^ ((row & 7) << 4))) = v;
                }
            }
        }
    }
    __syncthreads();
    // epilogue 2: full-sector write-back (16 lanes = one complete 256 B row)
    const int ck = t & 15;
    #pragma unroll
    for (int it = 0; it < 4; ++it) {
        const int row = (t >> 4) + it * 32;
        const int bo = ck * 16;
        if constexpr (std::is_same<TO, unsigned short>::value) {
            const int4 val = *(const int4*)(lds + row * 256 + (bo ^ ((row & 7) << 4)));
            *(int4*)(Out + (size_t)(row0 + row) * N + col0 + bo / 2) = val;
        } else {
            float4 val = *(const float4*)(lds + row * 256 + (bo ^ ((row & 7) << 4)));
            if constexpr (RESID) {
                const float4 rv = *(const float4*)(resid + (size_t)(row0 + row) * N + col0 + bo / 4);
                val.x += rv.x; val.y += rv.y; val.z += rv.z; val.w += rv.w;
            }
            *(float4*)((float*)Out + (size_t)(row0 + row) * N + col0 + bo / 4) = val;
        }
    }
}

// ---------------- Fused w_out GEMM + residual + LN2 ----------------
// Tile 64 x 256 (full output row per block), K=256, 512 threads (8 waves, 2x4).
// Epilogue: C-tile (64 rows x 1024 B f32) in dead LDS; one WAVE per row adds the
// x residual, shfl-reduces mean/var over the 256-col row, writes out (f32) AND
// y = LN2(out) (bf16). R12 lesson: Y must NOT alias A (intra-kernel read/write of
// one buffer raced under graph replay despite row-disjointness on paper) — Y now
// points at a separate workspace region (F's front half, dead after sample_kernel).
__global__ __launch_bounds__(512) void wout_ln2_kernel(
        const unsigned short* __restrict__ A,   // agg [M,256] bf16
        const unsigned short* __restrict__ BT,  // woutT [256,256] bf16
        const float* __restrict__ bias,         // b_out
        const float* __restrict__ resid,        // x [M,256] f32
        const float* __restrict__ g2, const float* __restrict__ b2,
        float* __restrict__ Out,                // d_out [M,256] f32
        unsigned short* __restrict__ Y) {       // y [M,256] bf16 (disjoint from A)
    constexpr int BM = 64, K = 256;
    constexpr int ABYTES = BM * 128;            // 8 KB
    constexpr int BUFB = ABYTES + 256 * 128;    // 40 KB
    __shared__ __align__(16) char lds[2 * BUFB];// 80 KB (epilogue reuses 64 KB)
    const int t = threadIdx.x;
    const int w = t >> 6;
    const int l = t & 63;
    const int row0 = blockIdx.x * BM;
    const int wr = (w >> 2) * 32;               // wave grid 2x4: MI=2, NI=4
    const int wc = (w & 3) * 64;

    const int srow = l >> 3;
    const int selem = ((l & 7) ^ srow) * 8;

    auto stage = [&](char* buf, int k0) {       // LA = 1 + 4 = 5 per wave
        unsigned short* As_ = (unsigned short*)buf;
        unsigned short* Bs_ = (unsigned short*)(buf + ABYTES);
        {
            const int row = w * 8 + srow;       // A: 8 chunks, 1 per wave
            gl2lds16(A + (size_t)(row0 + row) * K + k0 + selem, As_ + w * 512);
        }
        #pragma unroll
        for (int i = 0; i < 4; ++i) {           // B: 32 chunks, 4 per wave
            const int c = w + i * 8;
            const int row = c * 8 + srow;
            gl2lds16(BT + (size_t)row * K + k0 + selem, Bs_ + c * 512);
        }
    };

    f32x4 acc[2][4] = {};
    stage(lds, 0);
    stage(lds + BUFB, 64);

    for (int tt = 0; tt < 4; ++tt) {
        if (tt + 1 < 4) asm volatile("s_waitcnt vmcnt(5)" ::: "memory");
        else            asm volatile("s_waitcnt vmcnt(0)" ::: "memory");
        __builtin_amdgcn_s_barrier();
        __builtin_amdgcn_sched_barrier(0);

        const char* Ab = lds + (size_t)(tt & 1) * BUFB;
        const char* Bb = Ab + ABYTES;
        #pragma unroll
        for (int ks = 0; ks < 2; ++ks) {
            const int kb = ks * 64 + (l >> 4) * 16;
            bf16x8 af[2], bfr[4];
            #pragma unroll
            for (int mi = 0; mi < 2; ++mi) {
                const int row = wr + mi * 16 + (l & 15);
                af[mi] = *(const bf16x8*)(Ab + row * 128 + (kb ^ ((row & 7) << 4)));
            }
            #pragma unroll
            for (int ni = 0; ni < 4; ++ni) {
                const int row = wc + ni * 16 + (l & 15);
                bfr[ni] = *(const bf16x8*)(Bb + row * 128 + (kb ^ ((row & 7) << 4)));
            }
            #pragma unroll
            for (int mi = 0; mi < 2; ++mi)
                #pragma unroll
                for (int ni = 0; ni < 4; ++ni)
                    acc[mi][ni] = __builtin_amdgcn_mfma_f32_16x16x32_bf16(
                        af[mi], bfr[ni], acc[mi][ni], 0, 0, 0);
        }
        __builtin_amdgcn_s_barrier();
        __builtin_amdgcn_sched_barrier(0);
        if (tt + 2 < 4) stage(lds + (size_t)(tt & 1) * BUFB, (tt + 2) * 64);
    }

    // epilogue 1: f32 C-tile, 64 rows x 1024 B, row-XOR swizzle (2-way max conflict)
    const int lrow = (l >> 4) * 4;
    const int lcol = l & 15;
    #pragma unroll
    for (int ni = 0; ni < 4; ++ni) {
        const int col = wc + ni * 16 + lcol;
        const float bb = bias[col];
        #pragma unroll
        for (int mi = 0; mi < 2; ++mi) {
            #pragma unroll
            for (int r = 0; r < 4; ++r) {
                const int row = wr + mi * 16 + lrow + r;
                *(float*)(lds + row * 1024 + ((col * 4) ^ ((row & 7) << 4))) = acc[mi][ni][r] + bb;
            }
        }
    }
    __syncthreads();
    // epilogue 2: one wave per row: + residual, LN stats over 256 cols, dual write
    const float4 gv = *reinterpret_cast<const float4*>(g2 + l * 4);
    const float4 bv = *reinterpret_cast<const float4*>(b2 + l * 4);
    #pragma unroll
    for (int it = 0; it < 8; ++it) {
        const int r = w + it * 8;
        float4 v = *(const float4*)(lds + r * 1024 + ((l * 16) ^ ((r & 7) << 4)));
        const float4 rv = *(const float4*)(resid + (size_t)(row0 + r) * Cc + l * 4);
        v.x += rv.x; v.y += rv.y; v.z += rv.z; v.w += rv.w;
        float s  = v.x + v.y + v.z + v.w;
        float s2 = v.x * v.x + v.y * v.y + v.z * v.z + v.w * v.w;
        #pragma unroll
        for (int o = 32; o > 0; o >>= 1) { s += __shfl_down(s, o); s2 += __shfl_down(s2, o); }
        s = __shfl(s, 0); s2 = __shfl(s2, 0);
        const float mean = s * (1.0f / Cc);
        const float rstd = rsqrtf(s2 * (1.0f / Cc) - mean * mean + 1e-5f);
        *(float4*)(Out + (size_t)(row0 + r) * Cc + l * 4) = v;
        ushort4 o;
        o.x = f2bf((v.x - mean) * rstd * gv.x + bv.x);
        o.y = f2bf((v.y - mean) * rstd * gv.y + bv.y);
        o.z = f2bf((v.z - mean) * rstd * gv.z + bv.z);
        o.w = f2bf((v.w - mean) * rstd * gv.w + bv.w);
        *(ushort4*)(Y + (size_t)(row0 + r) * Cc + l * 4) = o;
    }
}

// ---------------- Deformable sampling + softmax + aggregation (bf16 in/out) ----------------
__global__ __launch_bounds__(256) void sample_kernel(const unsigned short* __restrict__ F,
        const float* __restrict__ refp, unsigned short* __restrict__ agg) {
    constexpr int PPB = 4;                       // pixels per block
    constexpr int nblk = Mrows / PPB;            // 4096
    const int bid = blockIdx.x;
    const int qi = (bid & 7) * (nblk / 8) + (bid >> 3);   // XCD-chunked swizzle
    const int m0 = qi * PPB;
    const int b = m0 / NPIX;
    const int pix0 = m0 - b * NPIX;
    const int t = threadIdx.x;
    __shared__ int4   s_idx[PPB][72];
    __shared__ float4 s_w[PPB][72];
    __shared__ float  s_lg[PPB][72];

    for (int idx = t; idx < PPB * 72; idx += 256) {
        const int p = idx / 72, hk = idx - p * 72;
        const int head = hk / 9, k = hk - head * 9;
        const int m = m0 + p, pix = pix0 + p;
        const size_t fb = (size_t)m * NQKV;
        const unsigned int ou = *(const unsigned int*)(F + fb + 256 + head * 18 + k * 2);
        const float ox = __uint_as_float(ou << 16);
        const float oy = __uint_as_float(ou & 0xffff0000u);
        const float2 rr = *(const float2*)(refp + ((size_t)pix * KPT + k) * 2);
        const float cx = (rr.x + ox + 1.0f) * 0.5f * (Wc - 1);
        const float cy = (rr.y + oy + 1.0f) * 0.5f * (Hc - 1);
        const float fx = floorf(cx), fy = floorf(cy);
        const float wx = cx - fx, wy = cy - fy;
        const int x0 = min(max((int)fx, 0), Wc - 1);
        const int x1 = min(max((int)fx + 1, 0), Wc - 1);
        const int y0 = min(max((int)fy, 0), Hc - 1);
        const int y1 = min(max((int)fy + 1, 0), Hc - 1);
        s_idx[p][hk] = make_int4(y0 * Wc + x0, y0 * Wc + x1, y1 * Wc + x0, y1 * Wc + x1);
        s_w[p][hk] = make_float4((1.0f - wy) * (1.0f - wx), (1.0f - wy) * wx,
                                 wy * (1.0f - wx), wy * wx);
        s_lg[p][hk] = bf2f(F[fb + 400 + hk]);
    }
    __syncthreads();
    for (int idx = t; idx < PPB * 72; idx += 256) {
        const int p = idx / 72, hk = idx - p * 72;
        const int h9 = (hk / 9) * 9;
        float mx = -1e30f;
        #pragma unroll
        for (int k = 0; k < 9; ++k) mx = fmaxf(mx, s_lg[p][h9 + k]);
        float sm = 0.0f;
        #pragma unroll
        for (int k = 0; k < 9; ++k) sm += __expf(s_lg[p][h9 + k] - mx);
        const float a = __expf(s_lg[p][hk] - mx) / sm;
        float4 w = s_w[p][hk];
        w.x *= a; w.y *= a; w.z *= a; w.w *= a;
        s_w[p][hk] = w;
    }
    __syncthreads();
    const int p = t >> 6, tl = t & 63;
    const int head = tl >> 3, dq = tl & 7;
    const unsigned short* vb = F + (size_t)b * NPIX * NQKV + head * HD + dq * 4;
    float a0 = 0.f, a1 = 0.f, a2 = 0.f, a3 = 0.f;
    #pragma unroll
    for (int k = 0; k < 9; ++k) {
        const int hk = head * 9 + k;
        const int4   ix = s_idx[p][hk];
        const float4 ww = s_w[p][hk];
        {
            const uint2 u = *(const uint2*)(vb + (size_t)ix.x * NQKV);
            a0 += __uint_as_float(u.x << 16) * ww.x;
            a1 += __uint_as_float(u.x & 0xffff0000u) * ww.x;
            a2 += __uint_as_float(u.y << 16) * ww.x;
            a3 += __uint_as_float(u.y & 0xffff0000u) * ww.x;
        }
        {
            const uint2 u = *(const uint2*)(vb + (size_t)ix.y * NQKV);
            a0 += __uint_as_float(u.x << 16) * ww.y;
            a1 += __uint_as_float(u.x & 0xffff0000u) * ww.y;
            a2 += __uint_as_float(u.y << 16) * ww.y;
            a3 += __uint_as_float(u.y & 0xffff0000u) * ww.y;
        }
        {
            const uint2 u = *(const uint2*)(vb + (size_t)ix.z * NQKV);
            a0 += __uint_as_float(u.x << 16) * ww.z;
            a1 += __uint_as_float(u.x & 0xffff0000u) * ww.z;
            a2 += __uint_as_float(u.y << 16) * ww.z;
            a3 += __uint_as_float(u.y & 0xffff0000u) * ww.z;
        }
        {
            const uint2 u = *(const uint2*)(vb + (size_t)ix.w * NQKV);
            a0 += __uint_as_float(u.x << 16) * ww.w;
            a1 += __uint_as_float(u.x & 0xffff0000u) * ww.w;
            a2 += __uint_as_float(u.y << 16) * ww.w;
            a3 += __uint_as_float(u.y & 0xffff0000u) * ww.w;
        }
    }
    ushort4 o;
    o.x = f2bf(a0); o.y = f2bf(a1); o.z = f2bf(a2); o.w = f2bf(a3);
    *reinterpret_cast<ushort4*>(agg + (size_t)(m0 + p) * Cc + tl * 4) = o;
}

// ---------------- Depthwise 3x3 conv (circular W, zero H) + GELU, bf16 in/out ----------------
__global__ __launch_bounds__(256) void dwconv_kernel(const unsigned short* __restrict__ h,
        const float* __restrict__ wdwT, const float* __restrict__ bdw,
        unsigned short* __restrict__ h2) {
    constexpr int NQ = 4;                     // x-positions per block
    constexpr int nblk = Mrows / NQ;          // 4096
    const int bid = blockIdx.x;
    const int qi = (bid & 7) * (nblk / 8) + (bid >> 3);   // XCD-chunked swizzle
    const int m0 = qi * NQ;
    const int b = m0 / NPIX;
    const int pix0 = m0 - b * NPIX;
    const int y = pix0 / Wc, x0 = pix0 - y * Wc;
    const int t = threadIdx.x;
    const int c0 = t * 4;

    float wreg[9][4];
    #pragma unroll
    for (int j = 0; j < 9; ++j) {
        const float4 wv = *reinterpret_cast<const float4*>(wdwT + j * HIDDEN + c0);
        wreg[j][0] = wv.x; wreg[j][1] = wv.y; wreg[j][2] = wv.z; wreg[j][3] = wv.w;
    }

    float acc[NQ][4] = {};
    #pragma unroll
    for (int dy = -1; dy <= 1; ++dy) {
        const int yy = y + dy;
        if (yy < 0 || yy >= Hc) continue;     // zero pad along height
        const size_t rowbase = ((size_t)b * NPIX + (size_t)yy * Wc) * HIDDEN + c0;
        #pragma unroll
        for (int j = 0; j < NQ + 2; ++j) {    // columns x0-1 .. x0+NQ (circular)
            const int xx = (x0 + j - 1 + Wc) & (Wc - 1);
            const ushort4 hv = *reinterpret_cast<const ushort4*>(h + rowbase + (size_t)xx * HIDDEN);
            const float f0 = bf2f(hv.x), f1 = bf2f(hv.y), f2 = bf2f(hv.z), f3 = bf2f(hv.w);
            #pragma unroll
            for (int q = 0; q < NQ; ++q) {
                if (q >= j - 2 && q <= j) {
                    const int wj = (dy + 1) * 3 + (j - q);
                    acc[q][0] += f0 * wreg[wj][0];
                    acc[q][1] += f1 * wreg[wj][1];
                    acc[q][2] += f2 * wreg[wj][2];
                    acc[q][3] += f3 * wreg[wj][3];
                }
            }
        }
    }
    const float4 bb = *reinterpret_cast<const float4*>(bdw + c0);
    #pragma unroll
    for (int q = 0; q < NQ; ++q) {
        ushort4 o;
        o.x = f2bf(gelu_exact(acc[q][0] + bb.x));
        o.y = f2bf(gelu_exact(acc[q][1] + bb.y));
        o.z = f2bf(gelu_exact(acc[q][2] + bb.z));
        o.w = f2bf(gelu_exact(acc[q][3] + bb.w));
        *reinterpret_cast<ushort4*>(h2 + (size_t)(m0 + q) * HIDDEN + c0) = o;
    }
}

extern "C" void kernel_launch(void* const* d_in, const int* in_sizes, int n_in,
                              void* d_out, int out_size, void* d_ws, size_t ws_size,
                              hipStream_t stream) {
    const float* x      = (const float*)d_in[0];
    const float* refp   = (const float*)d_in[1];
    const float* ln1_g  = (const float*)d_in[2];
    const float* ln1_b  = (const float*)d_in[3];
    const float* w_v    = (const float*)d_in[4];
    const float* b_v    = (const float*)d_in[5];
    const float* w_off  = (const float*)d_in[6];
    const float* b_off  = (const float*)d_in[7];
    const float* w_attn = (const float*)d_in[8];
    const float* b_attn = (const float*)d_in[9];
    const float* w_out  = (const float*)d_in[10];
    const float* b_out  = (const float*)d_in[11];
    const float* ln2_g  = (const float*)d_in[12];
    const float* ln2_b  = (const float*)d_in[13];
    const float* w1     = (const float*)d_in[14];
    const float* b1     = (const float*)d_in[15];
    const float* w_dw   = (const float*)d_in[16];
    const float* b_dw   = (const float*)d_in[17];
    const float* w2     = (const float*)d_in[18];
    const float* b2     = (const float*)d_in[19];
    float* out = (float*)d_out;

    // Workspace layout (bytes). Every region is written by one kernel and read by
    // LATER kernels only (stream-ordered); no kernel reads and writes one region.
    //  [0,  8M): A   = xn (s1) -> agg (s3); dead after s4
    //  [8, 24M): F   fused qkv (s2); dead after s3
    //  [8, 16M): y   = LN2 out (s4, reuses dead F); dead after s5
    //  [32,64M): h   (s5); dead after s6
    //  [0, 32M): h2  (s6, reuses dead A/y/F); dead after s7
    //  [64M,..): transposed bf16 weights + wdwT + fused qkv bias
    char* wsb = (char*)d_ws;
    unsigned short* Abuf = (unsigned short*)(wsb);
    unsigned short* F    = (unsigned short*)(wsb + (8ull  << 20));
    unsigned short* ybuf = (unsigned short*)(wsb + (8ull  << 20));
    unsigned short* h    = (unsigned short*)(wsb + (32ull << 20));
    unsigned short* h2   = (unsigned short*)(wsb);
    size_t woff = 64ull << 20;
    unsigned short* qkvT = (unsigned short*)(wsb + woff); woff += (size_t)NQKV * 256 * 2;
    unsigned short* woutT= (unsigned short*)(wsb + woff); woff += 256 * 256 * 2;
    unsigned short* w1T  = (unsigned short*)(wsb + woff); woff += 1024 * 256 * 2;
    unsigned short* w2T  = (unsigned short*)(wsb + woff); woff += 256 * 1024 * 2;
    float*          wdwT = (float*)(wsb + woff);          woff += 9 * 1024 * 4;
    float*          qkvB = (float*)(wsb + woff);

    // 1. merged LN1 + weight prep (one dispatch)
    prepln_kernel<<<Mrows / 4 + NQKV + 256 + 1024 + 256 + 9, 256, 0, stream>>>(
        x, ln1_g, ln1_b, Abuf,
        w_v, b_v, w_off, b_off, w_attn, b_attn, w_out, w1, w2, w_dw,
        qkvT, qkvB, woutT, w1T, w2T, wdwT);
    // 2. fused QKV GEMM: F = xn @ [w_v|w_off|w_attn] + bias  (bf16 out)
    mfma_gemm<128, false, false, unsigned short><<<dim3(Mrows / 128, NQKV / 128), 512, 0, stream>>>(
        Abuf, qkvT, qkvB, nullptr, F, NQKV, 256);
    // 3. deformable sampling + softmax + aggregation -> agg (A region)
    sample_kernel<<<Mrows / 4, 256, 0, stream>>>(F, refp, Abuf);
    // 4. fused: out = x + agg @ w_out + b_out;  y = LN2(out) -> ybuf (disjoint)
    wout_ln2_kernel<<<Mrows / 64, 512, 0, stream>>>(
        Abuf, woutT, b_out, x, ln2_g, ln2_b, out, ybuf);
    // 5. h = gelu(y @ w1 + b1) (bf16)
    mfma_gemm<128, true, false, unsigned short><<<dim3(Mrows / 128, 1024 / 128), 512, 0, stream>>>(
        ybuf, w1T, b1, nullptr, h, 1024, 256);
    // 6. depthwise conv + gelu -> h2 (bf16)
    dwconv_kernel<<<Mrows / 4, 256, 0, stream>>>(h, wdwT, b_dw, h2);
    // 7. out += h2 @ w2 + b2 (f32, in-place residual)
    mfma_gemm<64, false, true, float><<<dim3(Mrows / 128, 256 / 64), 512, 0, stream>>>(
        h2, w2T, b2, out, out, 256, 1024);
}

// Round 14
// 124.200 us; speedup vs baseline: 1.0792x; 1.0280x over previous
//
#include <hip/hip_runtime.h>
#include <hip/hip_bf16.h>
#include <hip/hip_fp8.h>
#include <type_traits>

// Problem constants
constexpr int Bc = 2, Hc = 64, Wc = 128, Cc = 256;
constexpr int HEADS = 8, KPT = 9, HIDDEN = 1024;
constexpr int HD = Cc / HEADS;           // 32
constexpr int NPIX = Hc * Wc;            // 8192
constexpr int Mrows = Bc * NPIX;         // 16384
constexpr int NQKV = 512;                // 256 (v) + 144 (off) + 72 (attn) padded to 512

typedef __attribute__((ext_vector_type(4))) float f32x4;
typedef __attribute__((ext_vector_type(8))) short bf16x8;

__device__ __forceinline__ float bf2f(unsigned short u) {
    union { unsigned int i; float f; } c; c.i = ((unsigned int)u) << 16; return c.f;
}
__device__ __forceinline__ unsigned short f2bf(float f) {
    __hip_bfloat16 h = __float2bfloat16(f);
    return *reinterpret_cast<unsigned short*>(&h);
}
__device__ __forceinline__ unsigned char f2fp8(float f) {
    return __hip_fp8_e4m3(f).__x;        // OCP e4m3 (gfx950)
}
__device__ __forceinline__ float fp82f(unsigned char u) {
    __hip_fp8_e4m3 v; v.__x = u; return (float)v;
}
__device__ __forceinline__ float gelu_exact(float x) {
    return 0.5f * x * (1.0f + erff(x * 0.70710678118654752f));
}
__device__ __forceinline__ void gl2lds16(const void* g, void* l) {
    __builtin_amdgcn_global_load_lds(
        (const __attribute__((address_space(1))) unsigned int*)g,
        (__attribute__((address_space(3))) unsigned int*)l, 16, 0, 0);
}

// ---------------- Merged: LN1 (wave per row) + weight prep, one launch ----------------
__global__ __launch_bounds__(256) void prepln_kernel(
        const float* __restrict__ x, const float* __restrict__ ln1_g,
        const float* __restrict__ ln1_b, unsigned short* __restrict__ xn,
        const float* __restrict__ w_v, const float* __restrict__ b_v,
        const float* __restrict__ w_off, const float* __restrict__ b_off,
        const float* __restrict__ w_attn, const float* __restrict__ b_attn,
        const float* __restrict__ w_out, const float* __restrict__ w1,
        const float* __restrict__ w2, const float* __restrict__ w_dw,
        unsigned short* __restrict__ qkvT, float* __restrict__ qkvB,
        unsigned short* __restrict__ woutT, unsigned short* __restrict__ w1T,
        unsigned short* __restrict__ w2T, float* __restrict__ wdwT) {
    const int t = threadIdx.x;
    if (blockIdx.x < Mrows / 4) {              // ---- LN1: 4 rows per block, wave/row ----
        const int r = blockIdx.x * 4 + (t >> 6);
        const int l = t & 63;
        const size_t base = (size_t)r * Cc + l * 4;
        const float4 v = *reinterpret_cast<const float4*>(x + base);
        float s  = v.x + v.y + v.z + v.w;
        float s2 = v.x * v.x + v.y * v.y + v.z * v.z + v.w * v.w;
        #pragma unroll
        for (int o = 32; o > 0; o >>= 1) { s += __shfl_down(s, o); s2 += __shfl_down(s2, o); }
        s = __shfl(s, 0); s2 = __shfl(s2, 0);
        const float mean = s * (1.0f / Cc);
        const float rstd = rsqrtf(s2 * (1.0f / Cc) - mean * mean + 1e-5f);
        const float4 gv = *reinterpret_cast<const float4*>(ln1_g + l * 4);
        const float4 bv = *reinterpret_cast<const float4*>(ln1_b + l * 4);
        ushort4 o;
        o.x = f2bf((v.x - mean) * rstd * gv.x + bv.x);
        o.y = f2bf((v.y - mean) * rstd * gv.y + bv.y);
        o.z = f2bf((v.z - mean) * rstd * gv.z + bv.z);
        o.w = f2bf((v.w - mean) * rstd * gv.w + bv.w);
        *reinterpret_cast<ushort4*>(xn + base) = o;
        return;
    }
    const int blk = blockIdx.x - Mrows / 4;    // ---- weight prep ----
    if (blk < NQKV) {                      // qkvT row n, K=256
        const int n = blk;
        float val = 0.0f;
        if (n < 256)       val = w_v[t * 256 + n];
        else if (n < 400)  val = w_off[t * 144 + (n - 256)];
        else if (n < 472)  val = w_attn[t * 72 + (n - 400)];
        qkvT[n * 256 + t] = f2bf(val);
        if (t == 0) {
            float bv = 0.0f;
            if (n < 256)      bv = b_v[n];
            else if (n < 400) bv = b_off[n - 256];
            else if (n < 472) bv = b_attn[n - 400];
            qkvB[n] = bv;
        }
    } else if (blk < NQKV + 256) {         // woutT row n, K=256
        const int n = blk - NQKV;
        woutT[n * 256 + t] = f2bf(w_out[t * 256 + n]);
    } else if (blk < NQKV + 256 + 1024) {  // w1T row n, K=256
        const int n = blk - (NQKV + 256);
        w1T[n * 256 + t] = f2bf(w1[t * 1024 + n]);
    } else if (blk < NQKV + 256 + 1024 + 256) { // w2T row n, K=1024
        const int n = blk - (NQKV + 256 + 1024);
        #pragma unroll
        for (int k = t; k < 1024; k += 256)
            w2T[n * 1024 + k] = f2bf(w2[k * 256 + n]);
    } else {                               // wdwT row j (9 rows)
        const int j = blk - (NQKV + 256 + 1024 + 256);
        #pragma unroll
        for (int c = t; c < HIDDEN; c += 256)
            wdwT[j * HIDDEN + c] = w_dw[c * 9 + j];
    }
}

// ---------------- bf16 MFMA GEMM: Out[M,N] = A @ BT^T + bias ----------------
// Tile 128 x BN, BK=64, 512 threads (8 waves) — best measured config (R10).
// K-loop: counted-vmcnt 2-tile-ahead pipeline. Epilogue: C-tile staged in dead LDS,
// full-sector write-back (R9). TO = float / bf16(ushort) / fp8(uchar, e4m3).
template<int BN, bool GELU, bool RESID, typename TO>
__global__ __launch_bounds__(512) void mfma_gemm(
        const unsigned short* __restrict__ A,   // [M,K] bf16
        const unsigned short* __restrict__ BT,  // [N,K] bf16
        const float* __restrict__ bias,         // [N]
        const float* __restrict__ resid,        // [M,N] f32 (if RESID)
        TO* __restrict__ Out,                   // [M,N]
        int N, int K) {
    constexpr int WCOLS = (BN == 128) ? 4 : 2;  // waves along N
    constexpr int WROWS = 8 / WCOLS;            // waves along M
    constexpr int MI = 128 / (WROWS * 16);      // 16-row fragments per wave
    constexpr int NI = BN / (WCOLS * 16);       // 16-col fragments per wave
    constexpr int ACH = 2;                      // A chunks staged per wave (16 total)
    constexpr int BCH = (BN / 8) / 8;           // B chunks per wave (2 or 1)
    constexpr int LA = ACH + BCH;               // per-wave loads per stage
    constexpr int BUFB = 16384 + BN * 128;      // A tile 16 KB + B tile
    __shared__ __align__(16) char lds[2 * BUFB];
    const int t = threadIdx.x;
    const int w = t >> 6;
    const int l = t & 63;
    const int row0 = blockIdx.x * 128;
    const int col0 = blockIdx.y * BN;
    const int wr = (w / WCOLS) * (MI * 16);     // wave row offset in tile
    const int wc = (w % WCOLS) * (NI * 16);     // wave col offset in tile

    const int srow = l >> 3;
    const int selem = ((l & 7) ^ srow) * 8;     // XOR-swizzled source slot

    auto stage = [&](char* buf, int k0) {
        unsigned short* As_ = (unsigned short*)buf;
        unsigned short* Bs_ = (unsigned short*)(buf + 16384);
        #pragma unroll
        for (int i = 0; i < ACH; ++i) {         // A tile: 16 chunks, 2 per wave
            const int c = w + i * 8;
            const int row = c * 8 + srow;
            gl2lds16(A + (size_t)(row0 + row) * K + k0 + selem, As_ + c * 512);
        }
        #pragma unroll
        for (int i = 0; i < BCH; ++i) {         // B tile: BN/8 chunks
            const int c = w + i * 8;
            const int row = c * 8 + srow;
            gl2lds16(BT + (size_t)(col0 + row) * K + k0 + selem, Bs_ + c * 512);
        }
    };

    f32x4 acc[MI][NI] = {};
    const int nt = K / 64;

    stage(lds, 0);
    stage(lds + BUFB, 64);

    for (int tt = 0; tt < nt; ++tt) {
        if (tt + 1 < nt) {
            if constexpr (LA == 4) asm volatile("s_waitcnt vmcnt(4)" ::: "memory");
            else                   asm volatile("s_waitcnt vmcnt(3)" ::: "memory");
        } else {
            asm volatile("s_waitcnt vmcnt(0)" ::: "memory");
        }
        __builtin_amdgcn_s_barrier();
        __builtin_amdgcn_sched_barrier(0);

        const char* Ab = lds + (size_t)(tt & 1) * BUFB;
        const char* Bb = Ab + 16384;
        #pragma unroll
        for (int ks = 0; ks < 2; ++ks) {
            const int kb = ks * 64 + (l >> 4) * 16;
            bf16x8 af[MI], bfr[NI];
            #pragma unroll
            for (int mi = 0; mi < MI; ++mi) {
                const int row = wr + mi * 16 + (l & 15);
                af[mi] = *(const bf16x8*)(Ab + row * 128 + (kb ^ ((row & 7) << 4)));
            }
            #pragma unroll
            for (int ni = 0; ni < NI; ++ni) {
                const int row = wc + ni * 16 + (l & 15);
                bfr[ni] = *(const bf16x8*)(Bb + row * 128 + (kb ^ ((row & 7) << 4)));
            }
            #pragma unroll
            for (int mi = 0; mi < MI; ++mi)
                #pragma unroll
                for (int ni = 0; ni < NI; ++ni)
                    acc[mi][ni] = __builtin_amdgcn_mfma_f32_16x16x32_bf16(
                        af[mi], bfr[ni], acc[mi][ni], 0, 0, 0);
        }
        __builtin_amdgcn_s_barrier();
        __builtin_amdgcn_sched_barrier(0);
        if (tt + 2 < nt) stage(lds + (size_t)(tt & 1) * BUFB, (tt + 2) * 64);
    }

    // epilogue 1: C-tile to LDS, row stride ROWB = BN*sizeof(TO), row-XOR swizzle.
    // MFMA C/D layout: col=l&15, row=(l>>4)*4+reg (guide §3, m89-verified)
    constexpr int ROWB = BN * (int)sizeof(TO);  // 128 (fp8) / 256 (bf16, f32-BN64)
    const int lrow = (l >> 4) * 4;
    const int lcol = l & 15;
    #pragma unroll
    for (int ni = 0; ni < NI; ++ni) {
        const int col = wc + ni * 16 + lcol;
        const float bb = bias[col0 + col];
        #pragma unroll
        for (int mi = 0; mi < MI; ++mi) {
            #pragma unroll
            for (int r = 0; r < 4; ++r) {
                const int row = wr + mi * 16 + lrow + r;
                float v = acc[mi][ni][r] + bb;
                if constexpr (GELU) v = gelu_exact(v);
                if constexpr (std::is_same<TO, unsigned short>::value) {
                    *(unsigned short*)(lds + row * ROWB + ((col * 2) ^ ((row & 7) << 4))) = f2bf(v);
                } else if constexpr (std::is_same<TO, unsigned char>::value) {
                    *(unsigned char*)(lds + row * ROWB + ((col) ^ ((row & 7) << 4))) = f2fp8(v);
                } else {
                    *(float*)(lds + row * ROWB + ((col * 4) ^ ((row & 7) << 4))) = v;
                }
            }
        }
    }
    __syncthreads();
    // epilogue 2: full-sector write-back (ROWB/16 lanes cover one complete row)
    constexpr int CPR = ROWB / 16;            // 16B chunks per row (8 or 16)
    constexpr int RPI = 512 / CPR;            // rows per iteration (64 or 32)
    const int ck = t % CPR;
    #pragma unroll
    for (int it = 0; it < 128 / RPI; ++it) {
        const int row = (t / CPR) + it * RPI;
        const int bo = ck * 16;
        const char* src = lds + row * ROWB + (bo ^ ((row & 7) << 4));
        if constexpr (std::is_same<TO, unsigned short>::value) {
            *(int4*)(Out + (size_t)(row0 + row) * N + col0 + bo / 2) = *(const int4*)src;
        } else if constexpr (std::is_same<TO, unsigned char>::value) {
            *(int4*)(Out + (size_t)(row0 + row) * N + col0 + bo) = *(const int4*)src;
        } else {
            float4 val = *(const float4*)src;
            if constexpr (RESID) {
                const float4 rv = *(const float4*)(resid + (size_t)(row0 + row) * N + col0 + bo / 4);
                val.x += rv.x; val.y += rv.y; val.z += rv.z; val.w += rv.w;
            }
            *(float4*)((float*)Out + (size_t)(row0 + row) * N + col0 + bo / 4) = val;
        }
    }
}

// ---------------- Fused w_out GEMM + residual + LN2 ----------------
// Tile 64 x 256 (full output row per block), K=256, 512 threads (8 waves, 2x4).
// Epilogue: C-tile in dead LDS; one WAVE per row adds x residual, shfl-reduces
// mean/var, writes out (f32) AND y = LN2(out) (bf16, region disjoint from A — R12).
__global__ __launch_bounds__(512) void wout_ln2_kernel(
        const unsigned short* __restrict__ A,   // agg [M,256] bf16
        const unsigned short* __restrict__ BT,  // woutT [256,256] bf16
        const float* __restrict__ bias,         // b_out
        const float* __restrict__ resid,        // x [M,256] f32
        const float* __restrict__ g2, const float* __restrict__ b2,
        float* __restrict__ Out,                // d_out [M,256] f32
        unsigned short* __restrict__ Y) {       // y [M,256] bf16 (disjoint from A)
    constexpr int BM = 64, K = 256;
    constexpr int ABYTES = BM * 128;            // 8 KB
    constexpr int BUFB = ABYTES + 256 * 128;    // 40 KB
    __shared__ __align__(16) char lds[2 * BUFB];// 80 KB (epilogue reuses 64 KB)
    const int t = threadIdx.x;
    const int w = t >> 6;
    const int l = t & 63;
    const int row0 = blockIdx.x * BM;
    const int wr = (w >> 2) * 32;               // wave grid 2x4: MI=2, NI=4
    const int wc = (w & 3) * 64;

    const int srow = l >> 3;
    const int selem = ((l & 7) ^ srow) * 8;

    auto stage = [&](char* buf, int k0) {       // LA = 1 + 4 = 5 per wave
        unsigned short* As_ = (unsigned short*)buf;
        unsigned short* Bs_ = (unsigned short*)(buf + ABYTES);
        {
            const int row = w * 8 + srow;       // A: 8 chunks, 1 per wave
            gl2lds16(A + (size_t)(row0 + row) * K + k0 + selem, As_ + w * 512);
        }
        #pragma unroll
        for (int i = 0; i < 4; ++i) {           // B: 32 chunks, 4 per wave
            const int c = w + i * 8;
            const int row = c * 8 + srow;
            gl2lds16(BT + (size_t)row * K + k0 + selem, Bs_ + c * 512);
        }
    };

    f32x4 acc[2][4] = {};
    stage(lds, 0);
    stage(lds + BUFB, 64);

    for (int tt = 0; tt < 4; ++tt) {
        if (tt + 1 < 4) asm volatile("s_waitcnt vmcnt(5)" ::: "memory");
        else            asm volatile("s_waitcnt vmcnt(0)" ::: "memory");
        __builtin_amdgcn_s_barrier();
        __builtin_amdgcn_sched_barrier(0);

        const char* Ab = lds + (size_t)(tt & 1) * BUFB;
        const char* Bb = Ab + ABYTES;
        #pragma unroll
        for (int ks = 0; ks < 2; ++ks) {
            const int kb = ks * 64 + (l >> 4) * 16;
            bf16x8 af[2], bfr[4];
            #pragma unroll
            for (int mi = 0; mi < 2; ++mi) {
                const int row = wr + mi * 16 + (l & 15);
                af[mi] = *(const bf16x8*)(Ab + row * 128 + (kb ^ ((row & 7) << 4)));
            }
            #pragma unroll
            for (int ni = 0; ni < 4; ++ni) {
                const int row = wc + ni * 16 + (l & 15);
                bfr[ni] = *(const bf16x8*)(Bb + row * 128 + (kb ^ ((row & 7) << 4)));
            }
            #pragma unroll
            for (int mi = 0; mi < 2; ++mi)
                #pragma unroll
                for (int ni = 0; ni < 4; ++ni)
                    acc[mi][ni] = __builtin_amdgcn_mfma_f32_16x16x32_bf16(
                        af[mi], bfr[ni], acc[mi][ni], 0, 0, 0);
        }
        __builtin_amdgcn_s_barrier();
        __builtin_amdgcn_sched_barrier(0);
        if (tt + 2 < 4) stage(lds + (size_t)(tt & 1) * BUFB, (tt + 2) * 64);
    }

    // epilogue 1: f32 C-tile, 64 rows x 1024 B, row-XOR swizzle
    const int lrow = (l >> 4) * 4;
    const int lcol = l & 15;
    #pragma unroll
    for (int ni = 0; ni < 4; ++ni) {
        const int col = wc + ni * 16 + lcol;
        const float bb = bias[col];
        #pragma unroll
        for (int mi = 0; mi < 2; ++mi) {
            #pragma unroll
            for (int r = 0; r < 4; ++r) {
                const int row = wr + mi * 16 + lrow + r;
                *(float*)(lds + row * 1024 + ((col * 4) ^ ((row & 7) << 4))) = acc[mi][ni][r] + bb;
            }
        }
    }
    __syncthreads();
    // epilogue 2: one wave per row: + residual, LN stats over 256 cols, dual write
    const float4 gv = *reinterpret_cast<const float4*>(g2 + l * 4);
    const float4 bv = *reinterpret_cast<const float4*>(b2 + l * 4);
    #pragma unroll
    for (int it = 0; it < 8; ++it) {
        const int r = w + it * 8;
        float4 v = *(const float4*)(lds + r * 1024 + ((l * 16) ^ ((r & 7) << 4)));
        const float4 rv = *(const float4*)(resid + (size_t)(row0 + r) * Cc + l * 4);
        v.x += rv.x; v.y += rv.y; v.z += rv.z; v.w += rv.w;
        float s  = v.x + v.y + v.z + v.w;
        float s2 = v.x * v.x + v.y * v.y + v.z * v.z + v.w * v.w;
        #pragma unroll
        for (int o = 32; o > 0; o >>= 1) { s += __shfl_down(s, o); s2 += __shfl_down(s2, o); }
        s = __shfl(s, 0); s2 = __shfl(s2, 0);
        const float mean = s * (1.0f / Cc);
        const float rstd = rsqrtf(s2 * (1.0f / Cc) - mean * mean + 1e-5f);
        *(float4*)(Out + (size_t)(row0 + r) * Cc + l * 4) = v;
        ushort4 o;
        o.x = f2bf((v.x - mean) * rstd * gv.x + bv.x);
        o.y = f2bf((v.y - mean) * rstd * gv.y + bv.y);
        o.z = f2bf((v.z - mean) * rstd * gv.z + bv.z);
        o.w = f2bf((v.w - mean) * rstd * gv.w + bv.w);
        *(ushort4*)(Y + (size_t)(row0 + r) * Cc + l * 4) = o;
    }
}

// ---------------- Deformable sampling + softmax + aggregation (bf16 in/out) ----------------
__global__ __launch_bounds__(256) void sample_kernel(const unsigned short* __restrict__ F,
        const float* __restrict__ refp, unsigned short* __restrict__ agg) {
    constexpr int PPB = 4;                       // pixels per block
    constexpr int nblk = Mrows / PPB;            // 4096
    const int bid = blockIdx.x;
    const int qi = (bid & 7) * (nblk / 8) + (bid >> 3);   // XCD-chunked swizzle
    const int m0 = qi * PPB;
    const int b = m0 / NPIX;
    const int pix0 = m0 - b * NPIX;
    const int t = threadIdx.x;
    __shared__ int4   s_idx[PPB][72];
    __shared__ float4 s_w[PPB][72];
    __shared__ float  s_lg[PPB][72];

    for (int idx = t; idx < PPB * 72; idx += 256) {
        const int p = idx / 72, hk = idx - p * 72;
        const int head = hk / 9, k = hk - head * 9;
        const int m = m0 + p, pix = pix0 + p;
        const size_t fb = (size_t)m * NQKV;
        const unsigned int ou = *(const unsigned int*)(F + fb + 256 + head * 18 + k * 2);
        const float ox = __uint_as_float(ou << 16);
        const float oy = __uint_as_float(ou & 0xffff0000u);
        const float2 rr = *(const float2*)(refp + ((size_t)pix * KPT + k) * 2);
        const float cx = (rr.x + ox + 1.0f) * 0.5f * (Wc - 1);
        const float cy = (rr.y + oy + 1.0f) * 0.5f * (Hc - 1);
        const float fx = floorf(cx), fy = floorf(cy);
        const float wx = cx - fx, wy = cy - fy;
        const int x0 = min(max((int)fx, 0), Wc - 1);
        const int x1 = min(max((int)fx + 1, 0), Wc - 1);
        const int y0 = min(max((int)fy, 0), Hc - 1);
        const int y1 = min(max((int)fy + 1, 0), Hc - 1);
        s_idx[p][hk] = make_int4(y0 * Wc + x0, y0 * Wc + x1, y1 * Wc + x0, y1 * Wc + x1);
        s_w[p][hk] = make_float4((1.0f - wy) * (1.0f - wx), (1.0f - wy) * wx,
                                 wy * (1.0f - wx), wy * wx);
        s_lg[p][hk] = bf2f(F[fb + 400 + hk]);
    }
    __syncthreads();
    for (int idx = t; idx < PPB * 72; idx += 256) {
        const int p = idx / 72, hk = idx - p * 72;
        const int h9 = (hk / 9) * 9;
        float mx = -1e30f;
        #pragma unroll
        for (int k = 0; k < 9; ++k) mx = fmaxf(mx, s_lg[p][h9 + k]);
        float sm = 0.0f;
        #pragma unroll
        for (int k = 0; k < 9; ++k) sm += __expf(s_lg[p][h9 + k] - mx);
        const float a = __expf(s_lg[p][hk] - mx) / sm;
        float4 w = s_w[p][hk];
        w.x *= a; w.y *= a; w.z *= a; w.w *= a;
        s_w[p][hk] = w;
    }
    __syncthreads();
    const int p = t >> 6, tl = t & 63;
    const int head = tl >> 3, dq = tl & 7;
    const unsigned short* vb = F + (size_t)b * NPIX * NQKV + head * HD + dq * 4;
    float a0 = 0.f, a1 = 0.f, a2 = 0.f, a3 = 0.f;
    #pragma unroll
    for (int k = 0; k < 9; ++k) {
        const int hk = head * 9 + k;
        const int4   ix = s_idx[p][hk];
        const float4 ww = s_w[p][hk];
        {
            const uint2 u = *(const uint2*)(vb + (size_t)ix.x * NQKV);
            a0 += __uint_as_float(u.x << 16) * ww.x;
            a1 += __uint_as_float(u.x & 0xffff0000u) * ww.x;
            a2 += __uint_as_float(u.y << 16) * ww.x;
            a3 += __uint_as_float(u.y & 0xffff0000u) * ww.x;
        }
        {
            const uint2 u = *(const uint2*)(vb + (size_t)ix.y * NQKV);
            a0 += __uint_as_float(u.x << 16) * ww.y;
            a1 += __uint_as_float(u.x & 0xffff0000u) * ww.y;
            a2 += __uint_as_float(u.y << 16) * ww.y;
            a3 += __uint_as_float(u.y & 0xffff0000u) * ww.y;
        }
        {
            const uint2 u = *(const uint2*)(vb + (size_t)ix.z * NQKV);
            a0 += __uint_as_float(u.x << 16) * ww.z;
            a1 += __uint_as_float(u.x & 0xffff0000u) * ww.z;
            a2 += __uint_as_float(u.y << 16) * ww.z;
            a3 += __uint_as_float(u.y & 0xffff0000u) * ww.z;
        }
        {
            const uint2 u = *(const uint2*)(vb + (size_t)ix.w * NQKV);
            a0 += __uint_as_float(u.x << 16) * ww.w;
            a1 += __uint_as_float(u.x & 0xffff0000u) * ww.w;
            a2 += __uint_as_float(u.y << 16) * ww.w;
            a3 += __uint_as_float(u.y & 0xffff0000u) * ww.w;
        }
    }
    ushort4 o;
    o.x = f2bf(a0); o.y = f2bf(a1); o.z = f2bf(a2); o.w = f2bf(a3);
    *reinterpret_cast<ushort4*>(agg + (size_t)(m0 + p) * Cc + tl * 4) = o;
}

// ---------------- Depthwise 3x3 conv (circular W, zero H) + GELU, fp8 in / bf16 out ----
// 8 consecutive x-positions per block (2048 blocks); thread t owns channels [4t,4t+4).
// h is fp8 e4m3 (quantized once by w1's epilogue): halves load bytes, HW cvt decode.
__global__ __launch_bounds__(256) void dwconv_kernel(const unsigned char* __restrict__ h,
        const float* __restrict__ wdwT, const float* __restrict__ bdw,
        unsigned short* __restrict__ h2) {
    constexpr int NQ = 8;                     // x-positions per block
    constexpr int nblk = Mrows / NQ;          // 2048
    const int bid = blockIdx.x;
    const int qi = (bid & 7) * (nblk / 8) + (bid >> 3);   // XCD-chunked swizzle (2048%8==0)
    const int m0 = qi * NQ;                   // octet never crosses a row (Wc % NQ == 0)
    const int b = m0 / NPIX;
    const int pix0 = m0 - b * NPIX;
    const int y = pix0 / Wc, x0 = pix0 - y * Wc;
    const int t = threadIdx.x;
    const int c0 = t * 4;

    float wreg[9][4];
    #pragma unroll
    for (int j = 0; j < 9; ++j) {
        const float4 wv = *reinterpret_cast<const float4*>(wdwT + j * HIDDEN + c0);
        wreg[j][0] = wv.x; wreg[j][1] = wv.y; wreg[j][2] = wv.z; wreg[j][3] = wv.w;
    }

    float acc[NQ][4] = {};
    #pragma unroll
    for (int dy = -1; dy <= 1; ++dy) {
        const int yy = y + dy;
        if (yy < 0 || yy >= Hc) continue;     // zero pad along height
        const size_t rowbase = ((size_t)b * NPIX + (size_t)yy * Wc) * HIDDEN + c0;
        #pragma unroll
        for (int j = 0; j < NQ + 2; ++j) {    // columns x0-1 .. x0+NQ (circular)
            const int xx = (x0 + j - 1 + Wc) & (Wc - 1);
            const uchar4 hv = *reinterpret_cast<const uchar4*>(h + rowbase + (size_t)xx * HIDDEN);
            const float f0 = fp82f(hv.x), f1 = fp82f(hv.y), f2 = fp82f(hv.z), f3 = fp82f(hv.w);
            #pragma unroll
            for (int q = 0; q < NQ; ++q) {
                if (q >= j - 2 && q <= j) {   // folds to constants after unroll
                    const int wj = (dy + 1) * 3 + (j - q);
                    acc[q][0] += f0 * wreg[wj][0];
                    acc[q][1] += f1 * wreg[wj][1];
                    acc[q][2] += f2 * wreg[wj][2];
                    acc[q][3] += f3 * wreg[wj][3];
                }
            }
        }
    }
    const float4 bb = *reinterpret_cast<const float4*>(bdw + c0);
    #pragma unroll
    for (int q = 0; q < NQ; ++q) {
        ushort4 o;
        o.x = f2bf(gelu_exact(acc[q][0] + bb.x));
        o.y = f2bf(gelu_exact(acc[q][1] + bb.y));
        o.z = f2bf(gelu_exact(acc[q][2] + bb.z));
        o.w = f2bf(gelu_exact(acc[q][3] + bb.w));
        *reinterpret_cast<ushort4*>(h2 + (size_t)(m0 + q) * HIDDEN + c0) = o;
    }
}

extern "C" void kernel_launch(void* const* d_in, const int* in_sizes, int n_in,
                              void* d_out, int out_size, void* d_ws, size_t ws_size,
                              hipStream_t stream) {
    const float* x      = (const float*)d_in[0];
    const float* refp   = (const float*)d_in[1];
    const float* ln1_g  = (const float*)d_in[2];
    const float* ln1_b  = (const float*)d_in[3];
    const float* w_v    = (const float*)d_in[4];
    const float* b_v    = (const float*)d_in[5];
    const float* w_off  = (const float*)d_in[6];
    const float* b_off  = (const float*)d_in[7];
    const float* w_attn = (const float*)d_in[8];
    const float* b_attn = (const float*)d_in[9];
    const float* w_out  = (const float*)d_in[10];
    const float* b_out  = (const float*)d_in[11];
    const float* ln2_g  = (const float*)d_in[12];
    const float* ln2_b  = (const float*)d_in[13];
    const float* w1     = (const float*)d_in[14];
    const float* b1     = (const float*)d_in[15];
    const float* w_dw   = (const float*)d_in[16];
    const float* b_dw   = (const float*)d_in[17];
    const float* w2     = (const float*)d_in[18];
    const float* b2     = (const float*)d_in[19];
    float* out = (float*)d_out;

    // Workspace layout (bytes). Every region is written by one kernel and read by
    // LATER kernels only (stream-ordered); no kernel reads and writes one region.
    //  [0,  8M): A   = xn (s1) -> agg (s3); dead after s4
    //  [8, 24M): F   fused qkv (s2); dead after s3
    //  [8, 16M): y   = LN2 out (s4, reuses dead F); dead after s5
    //  [32,48M): h   fp8 (s5); dead after s6
    //  [0, 32M): h2  bf16 (s6, reuses dead A/y/F); dead after s7
    //  [64M,..): transposed bf16 weights + wdwT + fused qkv bias
    char* wsb = (char*)d_ws;
    unsigned short* Abuf = (unsigned short*)(wsb);
    unsigned short* F    = (unsigned short*)(wsb + (8ull  << 20));
    unsigned short* ybuf = (unsigned short*)(wsb + (8ull  << 20));
    unsigned char*  hbuf = (unsigned char*)(wsb + (32ull << 20));
    unsigned short* h2   = (unsigned short*)(wsb);
    size_t woff = 64ull << 20;
    unsigned short* qkvT = (unsigned short*)(wsb + woff); woff += (size_t)NQKV * 256 * 2;
    unsigned short* woutT= (unsigned short*)(wsb + woff); woff += 256 * 256 * 2;
    unsigned short* w1T  = (unsigned short*)(wsb + woff); woff += 1024 * 256 * 2;
    unsigned short* w2T  = (unsigned short*)(wsb + woff); woff += 256 * 1024 * 2;
    float*          wdwT = (float*)(wsb + woff);          woff += 9 * 1024 * 4;
    float*          qkvB = (float*)(wsb + woff);

    // 1. merged LN1 + weight prep (one dispatch)
    prepln_kernel<<<Mrows / 4 + NQKV + 256 + 1024 + 256 + 9, 256, 0, stream>>>(
        x, ln1_g, ln1_b, Abuf,
        w_v, b_v, w_off, b_off, w_attn, b_attn, w_out, w1, w2, w_dw,
        qkvT, qkvB, woutT, w1T, w2T, wdwT);
    // 2. fused QKV GEMM: F = xn @ [w_v|w_off|w_attn] + bias  (bf16 out)
    mfma_gemm<128, false, false, unsigned short><<<dim3(Mrows / 128, NQKV / 128), 512, 0, stream>>>(
        Abuf, qkvT, qkvB, nullptr, F, NQKV, 256);
    // 3. deformable sampling + softmax + aggregation -> agg (A region)
    sample_kernel<<<Mrows / 4, 256, 0, stream>>>(F, refp, Abuf);
    // 4. fused: out = x + agg @ w_out + b_out;  y = LN2(out) -> ybuf (disjoint)
    wout_ln2_kernel<<<Mrows / 64, 512, 0, stream>>>(
        Abuf, woutT, b_out, x, ln2_g, ln2_b, out, ybuf);
    // 5. h = gelu(y @ w1 + b1) -> fp8 e4m3 (single FFN quantization point)
    mfma_gemm<128, true, false, unsigned char><<<dim3(Mrows / 128, 1024 / 128), 512, 0, stream>>>(
        ybuf, w1T, b1, nullptr, hbuf, 1024, 256);
    // 6. depthwise conv + gelu: fp8 in -> bf16 h2
    dwconv_kernel<<<Mrows / 8, 256, 0, stream>>>(hbuf, wdwT, b_dw, h2);
    // 7. out += h2 @ w2 + b2 (f32, in-place residual)
    mfma_gemm<64, false, true, float><<<dim3(Mrows / 128, 256 / 64), 512, 0, stream>>>(
        h2, w2T, b2, out, out, 256, 1024);
}

// Round 15
// 117.513 us; speedup vs baseline: 1.1406x; 1.0569x over previous
//
#include <hip/hip_runtime.h>
#include <hip/hip_bf16.h>
#include <hip/hip_fp8.h>
#include <type_traits>

// Problem constants
constexpr int Bc = 2, Hc = 64, Wc = 128, Cc = 256;
constexpr int HEADS = 8, KPT = 9, HIDDEN = 1024;
constexpr int HD = Cc / HEADS;           // 32
constexpr int NPIX = Hc * Wc;            // 8192
constexpr int Mrows = Bc * NPIX;         // 16384
constexpr int NQKV = 512;                // 256 (v) + 144 (off) + 72 (attn) padded to 512

typedef __attribute__((ext_vector_type(4))) float f32x4;
typedef __attribute__((ext_vector_type(8))) short bf16x8;

__device__ __forceinline__ float bf2f(unsigned short u) {
    union { unsigned int i; float f; } c; c.i = ((unsigned int)u) << 16; return c.f;
}
__device__ __forceinline__ unsigned short f2bf(float f) {
    __hip_bfloat16 h = __float2bfloat16(f);
    return *reinterpret_cast<unsigned short*>(&h);
}
__device__ __forceinline__ unsigned char f2fp8(float f) {
    return __hip_fp8_e4m3(f).__x;        // OCP e4m3 (gfx950)
}
__device__ __forceinline__ float fp82f(unsigned char u) {
    __hip_fp8_e4m3 v; v.__x = u; return (float)v;
}
__device__ __forceinline__ float gelu_exact(float x) {
    return 0.5f * x * (1.0f + erff(x * 0.70710678118654752f));
}
__device__ __forceinline__ void gl2lds16(const void* g, void* l) {
    __builtin_amdgcn_global_load_lds(
        (const __attribute__((address_space(1))) unsigned int*)g,
        (__attribute__((address_space(3))) unsigned int*)l, 16, 0, 0);
}

// ---------------- Merged: LN1 (wave per row) + weight prep, one launch ----------------
__global__ __launch_bounds__(256) void prepln_kernel(
        const float* __restrict__ x, const float* __restrict__ ln1_g,
        const float* __restrict__ ln1_b, unsigned short* __restrict__ xn,
        const float* __restrict__ w_v, const float* __restrict__ b_v,
        const float* __restrict__ w_off, const float* __restrict__ b_off,
        const float* __restrict__ w_attn, const float* __restrict__ b_attn,
        const float* __restrict__ w_out, const float* __restrict__ w1,
        const float* __restrict__ w2, const float* __restrict__ w_dw,
        unsigned short* __restrict__ qkvT, float* __restrict__ qkvB,
        unsigned short* __restrict__ woutT, unsigned short* __restrict__ w1T,
        unsigned char* __restrict__ w2T8, float* __restrict__ wdwT) {
    const int t = threadIdx.x;
    if (blockIdx.x < Mrows / 4) {              // ---- LN1: 4 rows per block, wave/row ----
        const int r = blockIdx.x * 4 + (t >> 6);
        const int l = t & 63;
        const size_t base = (size_t)r * Cc + l * 4;
        const float4 v = *reinterpret_cast<const float4*>(x + base);
        float s  = v.x + v.y + v.z + v.w;
        float s2 = v.x * v.x + v.y * v.y + v.z * v.z + v.w * v.w;
        #pragma unroll
        for (int o = 32; o > 0; o >>= 1) { s += __shfl_down(s, o); s2 += __shfl_down(s2, o); }
        s = __shfl(s, 0); s2 = __shfl(s2, 0);
        const float mean = s * (1.0f / Cc);
        const float rstd = rsqrtf(s2 * (1.0f / Cc) - mean * mean + 1e-5f);
        const float4 gv = *reinterpret_cast<const float4*>(ln1_g + l * 4);
        const float4 bv = *reinterpret_cast<const float4*>(ln1_b + l * 4);
        ushort4 o;
        o.x = f2bf((v.x - mean) * rstd * gv.x + bv.x);
        o.y = f2bf((v.y - mean) * rstd * gv.y + bv.y);
        o.z = f2bf((v.z - mean) * rstd * gv.z + bv.z);
        o.w = f2bf((v.w - mean) * rstd * gv.w + bv.w);
        *reinterpret_cast<ushort4*>(xn + base) = o;
        return;
    }
    const int blk = blockIdx.x - Mrows / 4;    // ---- weight prep ----
    if (blk < NQKV) {                      // qkvT row n, K=256
        const int n = blk;
        float val = 0.0f;
        if (n < 256)       val = w_v[t * 256 + n];
        else if (n < 400)  val = w_off[t * 144 + (n - 256)];
        else if (n < 472)  val = w_attn[t * 72 + (n - 400)];
        qkvT[n * 256 + t] = f2bf(val);
        if (t == 0) {
            float bv = 0.0f;
            if (n < 256)      bv = b_v[n];
            else if (n < 400) bv = b_off[n - 256];
            else if (n < 472) bv = b_attn[n - 400];
            qkvB[n] = bv;
        }
    } else if (blk < NQKV + 256) {         // woutT row n, K=256
        const int n = blk - NQKV;
        woutT[n * 256 + t] = f2bf(w_out[t * 256 + n]);
    } else if (blk < NQKV + 256 + 1024) {  // w1T row n, K=256
        const int n = blk - (NQKV + 256);
        w1T[n * 256 + t] = f2bf(w1[t * 1024 + n]);
    } else if (blk < NQKV + 256 + 1024 + 256) { // w2T8 row n, K=1024, fp8 x32 scale
        const int n = blk - (NQKV + 256 + 1024);
        #pragma unroll
        for (int k = t; k < 1024; k += 256)
            w2T8[n * 1024 + k] = f2fp8(w2[k * 256 + n] * 32.0f);
    } else {                               // wdwT row j (9 rows)
        const int j = blk - (NQKV + 256 + 1024 + 256);
        #pragma unroll
        for (int c = t; c < HIDDEN; c += 256)
            wdwT[j * HIDDEN + c] = w_dw[c * 9 + j];
    }
}

// ---------------- bf16 MFMA GEMM: Out[M,N] = A @ BT^T + bias ----------------
// Tile 128 x BN, BK=64, 512 threads (8 waves) — best measured config (R10).
// K-loop: counted-vmcnt 2-tile-ahead pipeline. Epilogue: C-tile staged in dead LDS,
// full-sector write-back (R9). TO = float / bf16(ushort) / fp8(uchar, e4m3).
template<int BN, bool GELU, bool RESID, typename TO>
__global__ __launch_bounds__(512) void mfma_gemm(
        const unsigned short* __restrict__ A,   // [M,K] bf16
        const unsigned short* __restrict__ BT,  // [N,K] bf16
        const float* __restrict__ bias,         // [N]
        const float* __restrict__ resid,        // [M,N] f32 (if RESID)
        TO* __restrict__ Out,                   // [M,N]
        int N, int K) {
    constexpr int WCOLS = (BN == 128) ? 4 : 2;  // waves along N
    constexpr int WROWS = 8 / WCOLS;            // waves along M
    constexpr int MI = 128 / (WROWS * 16);      // 16-row fragments per wave
    constexpr int NI = BN / (WCOLS * 16);       // 16-col fragments per wave
    constexpr int ACH = 2;                      // A chunks staged per wave (16 total)
    constexpr int BCH = (BN / 8) / 8;           // B chunks per wave (2 or 1)
    constexpr int LA = ACH + BCH;               // per-wave loads per stage
    constexpr int BUFB = 16384 + BN * 128;      // A tile 16 KB + B tile
    __shared__ __align__(16) char lds[2 * BUFB];
    const int t = threadIdx.x;
    const int w = t >> 6;
    const int l = t & 63;
    const int row0 = blockIdx.x * 128;
    const int col0 = blockIdx.y * BN;
    const int wr = (w / WCOLS) * (MI * 16);     // wave row offset in tile
    const int wc = (w % WCOLS) * (NI * 16);     // wave col offset in tile

    const int srow = l >> 3;
    const int selem = ((l & 7) ^ srow) * 8;     // XOR-swizzled source slot

    auto stage = [&](char* buf, int k0) {
        unsigned short* As_ = (unsigned short*)buf;
        unsigned short* Bs_ = (unsigned short*)(buf + 16384);
        #pragma unroll
        for (int i = 0; i < ACH; ++i) {         // A tile: 16 chunks, 2 per wave
            const int c = w + i * 8;
            const int row = c * 8 + srow;
            gl2lds16(A + (size_t)(row0 + row) * K + k0 + selem, As_ + c * 512);
        }
        #pragma unroll
        for (int i = 0; i < BCH; ++i) {         // B tile: BN/8 chunks
            const int c = w + i * 8;
            const int row = c * 8 + srow;
            gl2lds16(BT + (size_t)(col0 + row) * K + k0 + selem, Bs_ + c * 512);
        }
    };

    f32x4 acc[MI][NI] = {};
    const int nt = K / 64;

    stage(lds, 0);
    stage(lds + BUFB, 64);

    for (int tt = 0; tt < nt; ++tt) {
        if (tt + 1 < nt) {
            if constexpr (LA == 4) asm volatile("s_waitcnt vmcnt(4)" ::: "memory");
            else                   asm volatile("s_waitcnt vmcnt(3)" ::: "memory");
        } else {
            asm volatile("s_waitcnt vmcnt(0)" ::: "memory");
        }
        __builtin_amdgcn_s_barrier();
        __builtin_amdgcn_sched_barrier(0);

        const char* Ab = lds + (size_t)(tt & 1) * BUFB;
        const char* Bb = Ab + 16384;
        #pragma unroll
        for (int ks = 0; ks < 2; ++ks) {
            const int kb = ks * 64 + (l >> 4) * 16;
            bf16x8 af[MI], bfr[NI];
            #pragma unroll
            for (int mi = 0; mi < MI; ++mi) {
                const int row = wr + mi * 16 + (l & 15);
                af[mi] = *(const bf16x8*)(Ab + row * 128 + (kb ^ ((row & 7) << 4)));
            }
            #pragma unroll
            for (int ni = 0; ni < NI; ++ni) {
                const int row = wc + ni * 16 + (l & 15);
                bfr[ni] = *(const bf16x8*)(Bb + row * 128 + (kb ^ ((row & 7) << 4)));
            }
            #pragma unroll
            for (int mi = 0; mi < MI; ++mi)
                #pragma unroll
                for (int ni = 0; ni < NI; ++ni)
                    acc[mi][ni] = __builtin_amdgcn_mfma_f32_16x16x32_bf16(
                        af[mi], bfr[ni], acc[mi][ni], 0, 0, 0);
        }
        __builtin_amdgcn_s_barrier();
        __builtin_amdgcn_sched_barrier(0);
        if (tt + 2 < nt) stage(lds + (size_t)(tt & 1) * BUFB, (tt + 2) * 64);
    }

    // epilogue 1: C-tile to LDS, row stride ROWB = BN*sizeof(TO), row-XOR swizzle.
    constexpr int ROWB = BN * (int)sizeof(TO);
    const int lrow = (l >> 4) * 4;
    const int lcol = l & 15;
    #pragma unroll
    for (int ni = 0; ni < NI; ++ni) {
        const int col = wc + ni * 16 + lcol;
        const float bb = bias[col0 + col];
        #pragma unroll
        for (int mi = 0; mi < MI; ++mi) {
            #pragma unroll
            for (int r = 0; r < 4; ++r) {
                const int row = wr + mi * 16 + lrow + r;
                float v = acc[mi][ni][r] + bb;
                if constexpr (GELU) v = gelu_exact(v);
                if constexpr (std::is_same<TO, unsigned short>::value) {
                    *(unsigned short*)(lds + row * ROWB + ((col * 2) ^ ((row & 7) << 4))) = f2bf(v);
                } else if constexpr (std::is_same<TO, unsigned char>::value) {
                    *(unsigned char*)(lds + row * ROWB + ((col) ^ ((row & 7) << 4))) = f2fp8(v);
                } else {
                    *(float*)(lds + row * ROWB + ((col * 4) ^ ((row & 7) << 4))) = v;
                }
            }
        }
    }
    __syncthreads();
    // epilogue 2: full-sector write-back (ROWB/16 lanes cover one complete row)
    constexpr int CPR = ROWB / 16;
    constexpr int RPI = 512 / CPR;
    const int ck = t % CPR;
    #pragma unroll
    for (int it = 0; it < 128 / RPI; ++it) {
        const int row = (t / CPR) + it * RPI;
        const int bo = ck * 16;
        const char* src = lds + row * ROWB + (bo ^ ((row & 7) << 4));
        if constexpr (std::is_same<TO, unsigned short>::value) {
            *(int4*)(Out + (size_t)(row0 + row) * N + col0 + bo / 2) = *(const int4*)src;
        } else if constexpr (std::is_same<TO, unsigned char>::value) {
            *(int4*)(Out + (size_t)(row0 + row) * N + col0 + bo) = *(const int4*)src;
        } else {
            float4 val = *(const float4*)src;
            if constexpr (RESID) {
                const float4 rv = *(const float4*)(resid + (size_t)(row0 + row) * N + col0 + bo / 4);
                val.x += rv.x; val.y += rv.y; val.z += rv.z; val.w += rv.w;
            }
            *(float4*)((float*)Out + (size_t)(row0 + row) * N + col0 + bo / 4) = val;
        }
    }
}

// ---------------- fp8 MFMA GEMM for w2: out += h2(fp8) @ w2T8(fp8 x32)^T / 32 + b2 ----
// Tile 128 x 64, BK=128 fp8 elements (128 B/row — same staging geometry as bf16 BK=64),
// 512 threads (8 waves, 4x2), mfma_f32_16x16x32_fp8_fp8 (i64 operands, 4 K-substeps).
__global__ __launch_bounds__(512) void w2_gemm_fp8(
        const unsigned char* __restrict__ A,   // h2 [M,1024] fp8 e4m3
        const unsigned char* __restrict__ BT,  // w2T8 [256,1024] fp8 (x32 scaled)
        const float* __restrict__ bias,        // b2
        const float* __restrict__ resid,       // out (read)
        float* __restrict__ Out,               // out (write)
        int N, int K) {                        // 256, 1024
    constexpr int ABYTES = 128 * 128;          // 16 KB
    constexpr int BUFB = ABYTES + 64 * 128;    // 24 KB
    __shared__ __align__(16) char lds[2 * BUFB];
    const int t = threadIdx.x;
    const int w = t >> 6;
    const int l = t & 63;
    const int row0 = blockIdx.x * 128;
    const int col0 = blockIdx.y * 64;
    const int wr = (w >> 1) * 32;              // wave grid 4x2: MI=2
    const int wc = (w & 1) * 32;               // NI=2

    const int srow = l >> 3;
    const int sbyte = ((l & 7) ^ srow) * 16;   // byte offset (fp8: byte == element)

    auto stage = [&](char* buf, int k0) {      // LA = 3 per wave
        unsigned char* As_ = (unsigned char*)buf;
        unsigned char* Bs_ = (unsigned char*)(buf + ABYTES);
        #pragma unroll
        for (int i = 0; i < 2; ++i) {          // A: 16 chunks (8 rows x 128 B), 2/wave
            const int c = w + i * 8;
            const int row = c * 8 + srow;
            gl2lds16(A + (size_t)(row0 + row) * K + k0 + sbyte, As_ + c * 1024);
        }
        {                                       // B: 8 chunks, 1/wave
            const int row = w * 8 + srow;
            gl2lds16(BT + (size_t)(col0 + row) * K + k0 + sbyte, Bs_ + w * 1024);
        }
    };

    f32x4 acc[2][2] = {};
    const int nt = K / 128;                    // 8

    stage(lds, 0);
    stage(lds + BUFB, 128);

    for (int tt = 0; tt < nt; ++tt) {
        if (tt + 1 < nt) asm volatile("s_waitcnt vmcnt(3)" ::: "memory");
        else             asm volatile("s_waitcnt vmcnt(0)" ::: "memory");
        __builtin_amdgcn_s_barrier();
        __builtin_amdgcn_sched_barrier(0);

        const char* Ab = lds + (size_t)(tt & 1) * BUFB;
        const char* Bb = Ab + ABYTES;
        #pragma unroll
        for (int ks = 0; ks < 4; ++ks) {       // 4 x K=32 substeps per 128-elem tile
            const int kb = ks * 32 + (l >> 4) * 8;   // byte offset within 128 B row
            long af[2], bfr[2];
            #pragma unroll
            for (int mi = 0; mi < 2; ++mi) {
                const int row = wr + mi * 16 + (l & 15);
                af[mi] = *(const long*)(Ab + row * 128 + (kb ^ ((row & 7) << 4)));
            }
            #pragma unroll
            for (int ni = 0; ni < 2; ++ni) {
                const int row = wc + ni * 16 + (l & 15);
                bfr[ni] = *(const long*)(Bb + row * 128 + (kb ^ ((row & 7) << 4)));
            }
            #pragma unroll
            for (int mi = 0; mi < 2; ++mi)
                #pragma unroll
                for (int ni = 0; ni < 2; ++ni)
                    acc[mi][ni] = __builtin_amdgcn_mfma_f32_16x16x32_fp8_fp8(
                        af[mi], bfr[ni], acc[mi][ni], 0, 0, 0);
        }
        __builtin_amdgcn_s_barrier();
        __builtin_amdgcn_sched_barrier(0);
        if (tt + 2 < nt) stage(lds + (size_t)(tt & 1) * BUFB, (tt + 2) * 128);
    }

    // epilogue 1: f32 C-tile (128 rows x 256 B), row-XOR swizzle; undo x32 weight scale
    const int lrow = (l >> 4) * 4;
    const int lcol = l & 15;
    #pragma unroll
    for (int ni = 0; ni < 2; ++ni) {
        const int col = wc + ni * 16 + lcol;
        const float bb = bias[col0 + col];
        #pragma unroll
        for (int mi = 0; mi < 2; ++mi) {
            #pragma unroll
            for (int r = 0; r < 4; ++r) {
                const int row = wr + mi * 16 + lrow + r;
                *(float*)(lds + row * 256 + ((col * 4) ^ ((row & 7) << 4)))
                    = acc[mi][ni][r] * 0.03125f + bb;
            }
        }
    }
    __syncthreads();
    // epilogue 2: full-sector write-back + residual (16 lanes per 256 B row)
    const int ck = t & 15;
    #pragma unroll
    for (int it = 0; it < 4; ++it) {
        const int row = (t >> 4) + it * 32;
        const int bo = ck * 16;
        float4 val = *(const float4*)(lds + row * 256 + (bo ^ ((row & 7) << 4)));
        const float4 rv = *(const float4*)(resid + (size_t)(row0 + row) * N + col0 + bo / 4);
        val.x += rv.x; val.y += rv.y; val.z += rv.z; val.w += rv.w;
        *(float4*)(Out + (size_t)(row0 + row) * N + col0 + bo / 4) = val;
    }
}

// ---------------- Fused w_out GEMM + residual + LN2 ----------------
__global__ __launch_bounds__(512) void wout_ln2_kernel(
        const unsigned short* __restrict__ A,   // agg [M,256] bf16
        const unsigned short* __restrict__ BT,  // woutT [256,256] bf16
        const float* __restrict__ bias,         // b_out
        const float* __restrict__ resid,        // x [M,256] f32
        const float* __restrict__ g2, const float* __restrict__ b2,
        float* __restrict__ Out,                // d_out [M,256] f32
        unsigned short* __restrict__ Y) {       // y [M,256] bf16 (disjoint from A)
    constexpr int BM = 64, K = 256;
    constexpr int ABYTES = BM * 128;            // 8 KB
    constexpr int BUFB = ABYTES + 256 * 128;    // 40 KB
    __shared__ __align__(16) char lds[2 * BUFB];// 80 KB (epilogue reuses 64 KB)
    const int t = threadIdx.x;
    const int w = t >> 6;
    const int l = t & 63;
    const int row0 = blockIdx.x * BM;
    const int wr = (w >> 2) * 32;               // wave grid 2x4: MI=2, NI=4
    const int wc = (w & 3) * 64;

    const int srow = l >> 3;
    const int selem = ((l & 7) ^ srow) * 8;

    auto stage = [&](char* buf, int k0) {       // LA = 5 per wave
        unsigned short* As_ = (unsigned short*)buf;
        unsigned short* Bs_ = (unsigned short*)(buf + ABYTES);
        {
            const int row = w * 8 + srow;       // A: 8 chunks, 1 per wave
            gl2lds16(A + (size_t)(row0 + row) * K + k0 + selem, As_ + w * 512);
        }
        #pragma unroll
        for (int i = 0; i < 4; ++i) {           // B: 32 chunks, 4 per wave
            const int c = w + i * 8;
            const int row = c * 8 + srow;
            gl2lds16(BT + (size_t)row * K + k0 + selem, Bs_ + c * 512);
        }
    };

    f32x4 acc[2][4] = {};
    stage(lds, 0);
    stage(lds + BUFB, 64);

    for (int tt = 0; tt < 4; ++tt) {
        if (tt + 1 < 4) asm volatile("s_waitcnt vmcnt(5)" ::: "memory");
        else            asm volatile("s_waitcnt vmcnt(0)" ::: "memory");
        __builtin_amdgcn_s_barrier();
        __builtin_amdgcn_sched_barrier(0);

        const char* Ab = lds + (size_t)(tt & 1) * BUFB;
        const char* Bb = Ab + ABYTES;
        #pragma unroll
        for (int ks = 0; ks < 2; ++ks) {
            const int kb = ks * 64 + (l >> 4) * 16;
            bf16x8 af[2], bfr[4];
            #pragma unroll
            for (int mi = 0; mi < 2; ++mi) {
                const int row = wr + mi * 16 + (l & 15);
                af[mi] = *(const bf16x8*)(Ab + row * 128 + (kb ^ ((row & 7) << 4)));
            }
            #pragma unroll
            for (int ni = 0; ni < 4; ++ni) {
                const int row = wc + ni * 16 + (l & 15);
                bfr[ni] = *(const bf16x8*)(Bb + row * 128 + (kb ^ ((row & 7) << 4)));
            }
            #pragma unroll
            for (int mi = 0; mi < 2; ++mi)
                #pragma unroll
                for (int ni = 0; ni < 4; ++ni)
                    acc[mi][ni] = __builtin_amdgcn_mfma_f32_16x16x32_bf16(
                        af[mi], bfr[ni], acc[mi][ni], 0, 0, 0);
        }
        __builtin_amdgcn_s_barrier();
        __builtin_amdgcn_sched_barrier(0);
        if (tt + 2 < 4) stage(lds + (size_t)(tt & 1) * BUFB, (tt + 2) * 64);
    }

    // epilogue 1: f32 C-tile, 64 rows x 1024 B, row-XOR swizzle
    const int lrow = (l >> 4) * 4;
    const int lcol = l & 15;
    #pragma unroll
    for (int ni = 0; ni < 4; ++ni) {
        const int col = wc + ni * 16 + lcol;
        const float bb = bias[col];
        #pragma unroll
        for (int mi = 0; mi < 2; ++mi) {
            #pragma unroll
            for (int r = 0; r < 4; ++r) {
                const int row = wr + mi * 16 + lrow + r;
                *(float*)(lds + row * 1024 + ((col * 4) ^ ((row & 7) << 4))) = acc[mi][ni][r] + bb;
            }
        }
    }
    __syncthreads();
    // epilogue 2: one wave per row: + residual, LN stats over 256 cols, dual write
    const float4 gv = *reinterpret_cast<const float4*>(g2 + l * 4);
    const float4 bv = *reinterpret_cast<const float4*>(b2 + l * 4);
    #pragma unroll
    for (int it = 0; it < 8; ++it) {
        const int r = w + it * 8;
        float4 v = *(const float4*)(lds + r * 1024 + ((l * 16) ^ ((r & 7) << 4)));
        const float4 rv = *(const float4*)(resid + (size_t)(row0 + r) * Cc + l * 4);
        v.x += rv.x; v.y += rv.y; v.z += rv.z; v.w += rv.w;
        float s  = v.x + v.y + v.z + v.w;
        float s2 = v.x * v.x + v.y * v.y + v.z * v.z + v.w * v.w;
        #pragma unroll
        for (int o = 32; o > 0; o >>= 1) { s += __shfl_down(s, o); s2 += __shfl_down(s2, o); }
        s = __shfl(s, 0); s2 = __shfl(s2, 0);
        const float mean = s * (1.0f / Cc);
        const float rstd = rsqrtf(s2 * (1.0f / Cc) - mean * mean + 1e-5f);
        *(float4*)(Out + (size_t)(row0 + r) * Cc + l * 4) = v;
        ushort4 o;
        o.x = f2bf((v.x - mean) * rstd * gv.x + bv.x);
        o.y = f2bf((v.y - mean) * rstd * gv.y + bv.y);
        o.z = f2bf((v.z - mean) * rstd * gv.z + bv.z);
        o.w = f2bf((v.w - mean) * rstd * gv.w + bv.w);
        *(ushort4*)(Y + (size_t)(row0 + r) * Cc + l * 4) = o;
    }
}

// ---------------- Deformable sampling + softmax + aggregation (bf16 in/out) ----------------
__global__ __launch_bounds__(256) void sample_kernel(const unsigned short* __restrict__ F,
        const float* __restrict__ refp, unsigned short* __restrict__ agg) {
    constexpr int PPB = 4;                       // pixels per block
    constexpr int nblk = Mrows / PPB;            // 4096
    const int bid = blockIdx.x;
    const int qi = (bid & 7) * (nblk / 8) + (bid >> 3);   // XCD-chunked swizzle
    const int m0 = qi * PPB;
    const int b = m0 / NPIX;
    const int pix0 = m0 - b * NPIX;
    const int t = threadIdx.x;
    __shared__ int4   s_idx[PPB][72];
    __shared__ float4 s_w[PPB][72];
    __shared__ float  s_lg[PPB][72];

    for (int idx = t; idx < PPB * 72; idx += 256) {
        const int p = idx / 72, hk = idx - p * 72;
        const int head = hk / 9, k = hk - head * 9;
        const int m = m0 + p, pix = pix0 + p;
        const size_t fb = (size_t)m * NQKV;
        const unsigned int ou = *(const unsigned int*)(F + fb + 256 + head * 18 + k * 2);
        const float ox = __uint_as_float(ou << 16);
        const float oy = __uint_as_float(ou & 0xffff0000u);
        const float2 rr = *(const float2*)(refp + ((size_t)pix * KPT + k) * 2);
        const float cx = (rr.x + ox + 1.0f) * 0.5f * (Wc - 1);
        const float cy = (rr.y + oy + 1.0f) * 0.5f * (Hc - 1);
        const float fx = floorf(cx), fy = floorf(cy);
        const float wx = cx - fx, wy = cy - fy;
        const int x0 = min(max((int)fx, 0), Wc - 1);
        const int x1 = min(max((int)fx + 1, 0), Wc - 1);
        const int y0 = min(max((int)fy, 0), Hc - 1);
        const int y1 = min(max((int)fy + 1, 0), Hc - 1);
        s_idx[p][hk] = make_int4(y0 * Wc + x0, y0 * Wc + x1, y1 * Wc + x0, y1 * Wc + x1);
        s_w[p][hk] = make_float4((1.0f - wy) * (1.0f - wx), (1.0f - wy) * wx,
                                 wy * (1.0f - wx), wy * wx);
        s_lg[p][hk] = bf2f(F[fb + 400 + hk]);
    }
    __syncthreads();
    for (int idx = t; idx < PPB * 72; idx += 256) {
        const int p = idx / 72, hk = idx - p * 72;
        const int h9 = (hk / 9) * 9;
        float mx = -1e30f;
        #pragma unroll
        for (int k = 0; k < 9; ++k) mx = fmaxf(mx, s_lg[p][h9 + k]);
        float sm = 0.0f;
        #pragma unroll
        for (int k = 0; k < 9; ++k) sm += __expf(s_lg[p][h9 + k] - mx);
        const float a = __expf(s_lg[p][hk] - mx) / sm;
        float4 w = s_w[p][hk];
        w.x *= a; w.y *= a; w.z *= a; w.w *= a;
        s_w[p][hk] = w;
    }
    __syncthreads();
    const int p = t >> 6, tl = t & 63;
    const int head = tl >> 3, dq = tl & 7;
    const unsigned short* vb = F + (size_t)b * NPIX * NQKV + head * HD + dq * 4;
    float a0 = 0.f, a1 = 0.f, a2 = 0.f, a3 = 0.f;
    #pragma unroll
    for (int k = 0; k < 9; ++k) {
        const int hk = head * 9 + k;
        const int4   ix = s_idx[p][hk];
        const float4 ww = s_w[p][hk];
        {
            const uint2 u = *(const uint2*)(vb + (size_t)ix.x * NQKV);
            a0 += __uint_as_float(u.x << 16) * ww.x;
            a1 += __uint_as_float(u.x & 0xffff0000u) * ww.x;
            a2 += __uint_as_float(u.y << 16) * ww.x;
            a3 += __uint_as_float(u.y & 0xffff0000u) * ww.x;
        }
        {
            const uint2 u = *(const uint2*)(vb + (size_t)ix.y * NQKV);
            a0 += __uint_as_float(u.x << 16) * ww.y;
            a1 += __uint_as_float(u.x & 0xffff0000u) * ww.y;
            a2 += __uint_as_float(u.y << 16) * ww.y;
            a3 += __uint_as_float(u.y & 0xffff0000u) * ww.y;
        }
        {
            const uint2 u = *(const uint2*)(vb + (size_t)ix.z * NQKV);
            a0 += __uint_as_float(u.x << 16) * ww.z;
            a1 += __uint_as_float(u.x & 0xffff0000u) * ww.z;
            a2 += __uint_as_float(u.y << 16) * ww.z;
            a3 += __uint_as_float(u.y & 0xffff0000u) * ww.z;
        }
        {
            const uint2 u = *(const uint2*)(vb + (size_t)ix.w * NQKV);
            a0 += __uint_as_float(u.x << 16) * ww.w;
            a1 += __uint_as_float(u.x & 0xffff0000u) * ww.w;
            a2 += __uint_as_float(u.y << 16) * ww.w;
            a3 += __uint_as_float(u.y & 0xffff0000u) * ww.w;
        }
    }
    ushort4 o;
    o.x = f2bf(a0); o.y = f2bf(a1); o.z = f2bf(a2); o.w = f2bf(a3);
    *reinterpret_cast<ushort4*>(agg + (size_t)(m0 + p) * Cc + tl * 4) = o;
}

// ---------------- Depthwise 3x3 conv (circular W, zero H) + GELU, fp8 in / fp8 out ----
__global__ __launch_bounds__(256) void dwconv_kernel(const unsigned char* __restrict__ h,
        const float* __restrict__ wdwT, const float* __restrict__ bdw,
        unsigned char* __restrict__ h2) {
    constexpr int NQ = 8;                     // x-positions per block
    constexpr int nblk = Mrows / NQ;          // 2048
    const int bid = blockIdx.x;
    const int qi = (bid & 7) * (nblk / 8) + (bid >> 3);   // XCD-chunked swizzle
    const int m0 = qi * NQ;
    const int b = m0 / NPIX;
    const int pix0 = m0 - b * NPIX;
    const int y = pix0 / Wc, x0 = pix0 - y * Wc;
    const int t = threadIdx.x;
    const int c0 = t * 4;

    float wreg[9][4];
    #pragma unroll
    for (int j = 0; j < 9; ++j) {
        const float4 wv = *reinterpret_cast<const float4*>(wdwT + j * HIDDEN + c0);
        wreg[j][0] = wv.x; wreg[j][1] = wv.y; wreg[j][2] = wv.z; wreg[j][3] = wv.w;
    }

    float acc[NQ][4] = {};
    #pragma unroll
    for (int dy = -1; dy <= 1; ++dy) {
        const int yy = y + dy;
        if (yy < 0 || yy >= Hc) continue;     // zero pad along height
        const size_t rowbase = ((size_t)b * NPIX + (size_t)yy * Wc) * HIDDEN + c0;
        #pragma unroll
        for (int j = 0; j < NQ + 2; ++j) {    // columns x0-1 .. x0+NQ (circular)
            const int xx = (x0 + j - 1 + Wc) & (Wc - 1);
            const uchar4 hv = *reinterpret_cast<const uchar4*>(h + rowbase + (size_t)xx * HIDDEN);
            const float f0 = fp82f(hv.x), f1 = fp82f(hv.y), f2 = fp82f(hv.z), f3 = fp82f(hv.w);
            #pragma unroll
            for (int q = 0; q < NQ; ++q) {
                if (q >= j - 2 && q <= j) {
                    const int wj = (dy + 1) * 3 + (j - q);
                    acc[q][0] += f0 * wreg[wj][0];
                    acc[q][1] += f1 * wreg[wj][1];
                    acc[q][2] += f2 * wreg[wj][2];
                    acc[q][3] += f3 * wreg[wj][3];
                }
            }
        }
    }
    const float4 bb = *reinterpret_cast<const float4*>(bdw + c0);
    #pragma unroll
    for (int q = 0; q < NQ; ++q) {
        uchar4 o;
        o.x = f2fp8(gelu_exact(acc[q][0] + bb.x));
        o.y = f2fp8(gelu_exact(acc[q][1] + bb.y));
        o.z = f2fp8(gelu_exact(acc[q][2] + bb.z));
        o.w = f2fp8(gelu_exact(acc[q][3] + bb.w));
        *reinterpret_cast<uchar4*>(h2 + (size_t)(m0 + q) * HIDDEN + c0) = o;
    }
}

extern "C" void kernel_launch(void* const* d_in, const int* in_sizes, int n_in,
                              void* d_out, int out_size, void* d_ws, size_t ws_size,
                              hipStream_t stream) {
    const float* x      = (const float*)d_in[0];
    const float* refp   = (const float*)d_in[1];
    const float* ln1_g  = (const float*)d_in[2];
    const float* ln1_b  = (const float*)d_in[3];
    const float* w_v    = (const float*)d_in[4];
    const float* b_v    = (const float*)d_in[5];
    const float* w_off  = (const float*)d_in[6];
    const float* b_off  = (const float*)d_in[7];
    const float* w_attn = (const float*)d_in[8];
    const float* b_attn = (const float*)d_in[9];
    const float* w_out  = (const float*)d_in[10];
    const float* b_out  = (const float*)d_in[11];
    const float* ln2_g  = (const float*)d_in[12];
    const float* ln2_b  = (const float*)d_in[13];
    const float* w1     = (const float*)d_in[14];
    const float* b1     = (const float*)d_in[15];
    const float* w_dw   = (const float*)d_in[16];
    const float* b_dw   = (const float*)d_in[17];
    const float* w2     = (const float*)d_in[18];
    const float* b2     = (const float*)d_in[19];
    float* out = (float*)d_out;

    // Workspace layout (bytes). Each region written by one kernel, read by LATER
    // kernels only; no intra-kernel read/write aliasing (R12 lesson).
    //  [0,  8M): A    = xn (s1) -> agg (s3); dead after s4
    //  [8, 24M): F    fused qkv (s2); dead after s3
    //  [8, 16M): y    = LN2 out (s4, reuses dead F); dead after s5
    //  [32,48M): h    fp8 (s5); dead after s6
    //  [16,32M): h2   fp8 (s6, fresh region); dead after s7
    //  [64M,..): weights: qkvT/woutT/w1T bf16, w2T8 fp8(x32), wdwT f32, qkvB
    char* wsb = (char*)d_ws;
    unsigned short* Abuf = (unsigned short*)(wsb);
    unsigned short* F    = (unsigned short*)(wsb + (8ull  << 20));
    unsigned short* ybuf = (unsigned short*)(wsb + (8ull  << 20));
    unsigned char*  hbuf = (unsigned char*)(wsb + (32ull << 20));
    unsigned char*  h2   = (unsigned char*)(wsb + (16ull << 20));
    size_t woff = 64ull << 20;
    unsigned short* qkvT = (unsigned short*)(wsb + woff); woff += (size_t)NQKV * 256 * 2;
    unsigned short* woutT= (unsigned short*)(wsb + woff); woff += 256 * 256 * 2;
    unsigned short* w1T  = (unsigned short*)(wsb + woff); woff += 1024 * 256 * 2;
    unsigned char*  w2T8 = (unsigned char*)(wsb + woff);  woff += 256 * 1024;
    float*          wdwT = (float*)(wsb + woff);          woff += 9 * 1024 * 4;
    float*          qkvB = (float*)(wsb + woff);

    // 1. merged LN1 + weight prep (one dispatch)
    prepln_kernel<<<Mrows / 4 + NQKV + 256 + 1024 + 256 + 9, 256, 0, stream>>>(
        x, ln1_g, ln1_b, Abuf,
        w_v, b_v, w_off, b_off, w_attn, b_attn, w_out, w1, w2, w_dw,
        qkvT, qkvB, woutT, w1T, w2T8, wdwT);
    // 2. fused QKV GEMM: F = xn @ [w_v|w_off|w_attn] + bias  (bf16 out)
    mfma_gemm<128, false, false, unsigned short><<<dim3(Mrows / 128, NQKV / 128), 512, 0, stream>>>(
        Abuf, qkvT, qkvB, nullptr, F, NQKV, 256);
    // 3. deformable sampling + softmax + aggregation -> agg (A region)
    sample_kernel<<<Mrows / 4, 256, 0, stream>>>(F, refp, Abuf);
    // 4. fused: out = x + agg @ w_out + b_out;  y = LN2(out) -> ybuf (disjoint)
    wout_ln2_kernel<<<Mrows / 64, 512, 0, stream>>>(
        Abuf, woutT, b_out, x, ln2_g, ln2_b, out, ybuf);
    // 5. h = gelu(y @ w1 + b1) -> fp8 e4m3
    mfma_gemm<128, true, false, unsigned char><<<dim3(Mrows / 128, 1024 / 128), 512, 0, stream>>>(
        ybuf, w1T, b1, nullptr, hbuf, 1024, 256);
    // 6. depthwise conv + gelu: fp8 in -> fp8 h2
    dwconv_kernel<<<Mrows / 8, 256, 0, stream>>>(hbuf, wdwT, b_dw, h2);
    // 7. out += (h2 @ w2T8^T)/32 + b2  (fp8 x fp8 MFMA, f32 accum)
    w2_gemm_fp8<<<dim3(Mrows / 128, 256 / 64), 512, 0, stream>>>(
        h2, w2T8, b2, out, out, 256, 1024);
}

// Round 17
// 113.309 us; speedup vs baseline: 1.1829x; 1.0371x over previous
//
#include <hip/hip_runtime.h>
#include <hip/hip_bf16.h>
#include <hip/hip_fp8.h>
#include <type_traits>

// Problem constants
constexpr int Bc = 2, Hc = 64, Wc = 128, Cc = 256;
constexpr int HEADS = 8, KPT = 9, HIDDEN = 1024;
constexpr int HD = Cc / HEADS;           // 32
constexpr int NPIX = Hc * Wc;            // 8192
constexpr int Mrows = Bc * NPIX;         // 16384
constexpr int NQKV = 512;                // 256 (v) + 144 (off) + 72 (attn) padded to 512

typedef __attribute__((ext_vector_type(4))) float f32x4;
typedef __attribute__((ext_vector_type(8))) short bf16x8;

__device__ __forceinline__ float bf2f(unsigned short u) {
    union { unsigned int i; float f; } c; c.i = ((unsigned int)u) << 16; return c.f;
}
__device__ __forceinline__ unsigned short f2bf(float f) {
    __hip_bfloat16 h = __float2bfloat16(f);
    return *reinterpret_cast<unsigned short*>(&h);
}
__device__ __forceinline__ unsigned char f2fp8(float f) {
    return __hip_fp8_e4m3(f).__x;        // OCP e4m3 (gfx950)
}
__device__ __forceinline__ float fp82f(unsigned char u) {
    __hip_fp8_e4m3 v; v.__x = u; return (float)v;
}
__device__ __forceinline__ float gelu_exact(float x) {
    return 0.5f * x * (1.0f + erff(x * 0.70710678118654752f));
}
__device__ __forceinline__ void gl2lds16(const void* g, void* l) {
    __builtin_amdgcn_global_load_lds(
        (const __attribute__((address_space(1))) unsigned int*)g,
        (__attribute__((address_space(3))) unsigned int*)l, 16, 0, 0);
}

// ---------------- Merged: LN1 (wave per row) + weight prep, one launch ----------------
__global__ __launch_bounds__(256) void prepln_kernel(
        const float* __restrict__ x, const float* __restrict__ ln1_g,
        const float* __restrict__ ln1_b, unsigned short* __restrict__ xn,
        const float* __restrict__ w_v, const float* __restrict__ b_v,
        const float* __restrict__ w_off, const float* __restrict__ b_off,
        const float* __restrict__ w_attn, const float* __restrict__ b_attn,
        const float* __restrict__ w_out, const float* __restrict__ w1,
        const float* __restrict__ w2, const float* __restrict__ w_dw,
        unsigned short* __restrict__ qkvT, float* __restrict__ qkvB,
        unsigned short* __restrict__ woutT, unsigned short* __restrict__ w1T,
        unsigned char* __restrict__ w2T8, float* __restrict__ wdwT) {
    const int t = threadIdx.x;
    if (blockIdx.x < Mrows / 4) {              // ---- LN1: 4 rows per block, wave/row ----
        const int r = blockIdx.x * 4 + (t >> 6);
        const int l = t & 63;
        const size_t base = (size_t)r * Cc + l * 4;
        const float4 v = *reinterpret_cast<const float4*>(x + base);
        float s  = v.x + v.y + v.z + v.w;
        float s2 = v.x * v.x + v.y * v.y + v.z * v.z + v.w * v.w;
        #pragma unroll
        for (int o = 32; o > 0; o >>= 1) { s += __shfl_down(s, o); s2 += __shfl_down(s2, o); }
        s = __shfl(s, 0); s2 = __shfl(s2, 0);
        const float mean = s * (1.0f / Cc);
        const float rstd = rsqrtf(s2 * (1.0f / Cc) - mean * mean + 1e-5f);
        const float4 gv = *reinterpret_cast<const float4*>(ln1_g + l * 4);
        const float4 bv = *reinterpret_cast<const float4*>(ln1_b + l * 4);
        ushort4 o;
        o.x = f2bf((v.x - mean) * rstd * gv.x + bv.x);
        o.y = f2bf((v.y - mean) * rstd * gv.y + bv.y);
        o.z = f2bf((v.z - mean) * rstd * gv.z + bv.z);
        o.w = f2bf((v.w - mean) * rstd * gv.w + bv.w);
        *reinterpret_cast<ushort4*>(xn + base) = o;
        return;
    }
    const int blk = blockIdx.x - Mrows / 4;    // ---- weight prep ----
    if (blk < NQKV) {                      // qkvT row n, K=256
        const int n = blk;
        float val = 0.0f;
        if (n < 256)       val = w_v[t * 256 + n];
        else if (n < 400)  val = w_off[t * 144 + (n - 256)];
        else if (n < 472)  val = w_attn[t * 72 + (n - 400)];
        qkvT[n * 256 + t] = f2bf(val);
        if (t == 0) {
            float bv = 0.0f;
            if (n < 256)      bv = b_v[n];
            else if (n < 400) bv = b_off[n - 256];
            else if (n < 472) bv = b_attn[n - 400];
            qkvB[n] = bv;
        }
    } else if (blk < NQKV + 256) {         // woutT row n, K=256
        const int n = blk - NQKV;
        woutT[n * 256 + t] = f2bf(w_out[t * 256 + n]);
    } else if (blk < NQKV + 256 + 1024) {  // w1T row n, K=256
        const int n = blk - (NQKV + 256);
        w1T[n * 256 + t] = f2bf(w1[t * 1024 + n]);
    } else if (blk < NQKV + 256 + 1024 + 256) { // w2T8 row n, K=1024, fp8 x32 scale
        const int n = blk - (NQKV + 256 + 1024);
        #pragma unroll
        for (int k = t; k < 1024; k += 256)
            w2T8[n * 1024 + k] = f2fp8(w2[k * 256 + n] * 32.0f);
    } else {                               // wdwT row j (9 rows)
        const int j = blk - (NQKV + 256 + 1024 + 256);
        #pragma unroll
        for (int c = t; c < HIDDEN; c += 256)
            wdwT[j * HIDDEN + c] = w_dw[c * 9 + j];
    }
}

// ---------------- bf16 MFMA GEMM: Out[M,N] = A @ BT^T + bias ----------------
// Tile 128 x BN, BK=64, 512 threads (8 waves) — best measured config (R10).
// K-loop: counted-vmcnt 2-tile-ahead pipeline. Epilogue: C-tile staged in dead LDS,
// full-sector write-back (R9). TO = float / bf16(ushort) / fp8(uchar, e4m3).
template<int BN, bool GELU, bool RESID, typename TO>
__global__ __launch_bounds__(512) void mfma_gemm(
        const unsigned short* __restrict__ A,   // [M,K] bf16
        const unsigned short* __restrict__ BT,  // [N,K] bf16
        const float* __restrict__ bias,         // [N]
        const float* __restrict__ resid,        // [M,N] f32 (if RESID)
        TO* __restrict__ Out,                   // [M,N]
        int N, int K) {
    constexpr int WCOLS = (BN == 128) ? 4 : 2;  // waves along N
    constexpr int WROWS = 8 / WCOLS;            // waves along M
    constexpr int MI = 128 / (WROWS * 16);      // 16-row fragments per wave
    constexpr int NI = BN / (WCOLS * 16);       // 16-col fragments per wave
    constexpr int ACH = 2;                      // A chunks staged per wave (16 total)
    constexpr int BCH = (BN / 8) / 8;           // B chunks per wave (2 or 1)
    constexpr int LA = ACH + BCH;               // per-wave loads per stage
    constexpr int BUFB = 16384 + BN * 128;      // A tile 16 KB + B tile
    __shared__ __align__(16) char lds[2 * BUFB];
    const int t = threadIdx.x;
    const int w = t >> 6;
    const int l = t & 63;
    const int row0 = blockIdx.x * 128;
    const int col0 = blockIdx.y * BN;
    const int wr = (w / WCOLS) * (MI * 16);     // wave row offset in tile
    const int wc = (w % WCOLS) * (NI * 16);     // wave col offset in tile

    const int srow = l >> 3;
    const int selem = ((l & 7) ^ srow) * 8;     // XOR-swizzled source slot

    auto stage = [&](char* buf, int k0) {
        unsigned short* As_ = (unsigned short*)buf;
        unsigned short* Bs_ = (unsigned short*)(buf + 16384);
        #pragma unroll
        for (int i = 0; i < ACH; ++i) {         // A tile: 16 chunks, 2 per wave
            const int c = w + i * 8;
            const int row = c * 8 + srow;
            gl2lds16(A + (size_t)(row0 + row) * K + k0 + selem, As_ + c * 512);
        }
        #pragma unroll
        for (int i = 0; i < BCH; ++i) {         // B tile: BN/8 chunks
            const int c = w + i * 8;
            const int row = c * 8 + srow;
            gl2lds16(BT + (size_t)(col0 + row) * K + k0 + selem, Bs_ + c * 512);
        }
    };

    f32x4 acc[MI][NI] = {};
    const int nt = K / 64;

    stage(lds, 0);
    stage(lds + BUFB, 64);

    for (int tt = 0; tt < nt; ++tt) {
        if (tt + 1 < nt) {
            if constexpr (LA == 4) asm volatile("s_waitcnt vmcnt(4)" ::: "memory");
            else                   asm volatile("s_waitcnt vmcnt(3)" ::: "memory");
        } else {
            asm volatile("s_waitcnt vmcnt(0)" ::: "memory");
        }
        __builtin_amdgcn_s_barrier();
        __builtin_amdgcn_sched_barrier(0);

        const char* Ab = lds + (size_t)(tt & 1) * BUFB;
        const char* Bb = Ab + 16384;
        #pragma unroll
        for (int ks = 0; ks < 2; ++ks) {
            const int kb = ks * 64 + (l >> 4) * 16;
            bf16x8 af[MI], bfr[NI];
            #pragma unroll
            for (int mi = 0; mi < MI; ++mi) {
                const int row = wr + mi * 16 + (l & 15);
                af[mi] = *(const bf16x8*)(Ab + row * 128 + (kb ^ ((row & 7) << 4)));
            }
            #pragma unroll
            for (int ni = 0; ni < NI; ++ni) {
                const int row = wc + ni * 16 + (l & 15);
                bfr[ni] = *(const bf16x8*)(Bb + row * 128 + (kb ^ ((row & 7) << 4)));
            }
            #pragma unroll
            for (int mi = 0; mi < MI; ++mi)
                #pragma unroll
                for (int ni = 0; ni < NI; ++ni)
                    acc[mi][ni] = __builtin_amdgcn_mfma_f32_16x16x32_bf16(
                        af[mi], bfr[ni], acc[mi][ni], 0, 0, 0);
        }
        __builtin_amdgcn_s_barrier();
        __builtin_amdgcn_sched_barrier(0);
        if (tt + 2 < nt) stage(lds + (size_t)(tt & 1) * BUFB, (tt + 2) * 64);
    }

    // epilogue 1: C-tile to LDS, row stride ROWB = BN*sizeof(TO), row-XOR swizzle.
    constexpr int ROWB = BN * (int)sizeof(TO);
    const int lrow = (l >> 4) * 4;
    const int lcol = l & 15;
    #pragma unroll
    for (int ni = 0; ni < NI; ++ni) {
        const int col = wc + ni * 16 + lcol;
        const float bb = bias[col0 + col];
        #pragma unroll
        for (int mi = 0; mi < MI; ++mi) {
            #pragma unroll
            for (int r = 0; r < 4; ++r) {
                const int row = wr + mi * 16 + lrow + r;
                float v = acc[mi][ni][r] + bb;
                if constexpr (GELU) v = gelu_exact(v);
                if constexpr (std::is_same<TO, unsigned short>::value) {
                    *(unsigned short*)(lds + row * ROWB + ((col * 2) ^ ((row & 7) << 4))) = f2bf(v);
                } else if constexpr (std::is_same<TO, unsigned char>::value) {
                    *(unsigned char*)(lds + row * ROWB + ((col) ^ ((row & 7) << 4))) = f2fp8(v);
                } else {
                    *(float*)(lds + row * ROWB + ((col * 4) ^ ((row & 7) << 4))) = v;
                }
            }
        }
    }
    __syncthreads();
    // epilogue 2: full-sector write-back (ROWB/16 lanes cover one complete row)
    constexpr int CPR = ROWB / 16;
    constexpr int RPI = 512 / CPR;
    const int ck = t % CPR;
    #pragma unroll
    for (int it = 0; it < 128 / RPI; ++it) {
        const int row = (t / CPR) + it * RPI;
        const int bo = ck * 16;
        const char* src = lds + row * ROWB + (bo ^ ((row & 7) << 4));
        if constexpr (std::is_same<TO, unsigned short>::value) {
            *(int4*)(Out + (size_t)(row0 + row) * N + col0 + bo / 2) = *(const int4*)src;
        } else if constexpr (std::is_same<TO, unsigned char>::value) {
            *(int4*)(Out + (size_t)(row0 + row) * N + col0 + bo) = *(const int4*)src;
        } else {
            float4 val = *(const float4*)src;
            if constexpr (RESID) {
                const float4 rv = *(const float4*)(resid + (size_t)(row0 + row) * N + col0 + bo / 4);
                val.x += rv.x; val.y += rv.y; val.z += rv.z; val.w += rv.w;
            }
            *(float4*)((float*)Out + (size_t)(row0 + row) * N + col0 + bo / 4) = val;
        }
    }
}

// ---------------- QKV GEMM with dual-dtype epilogue ----------------
// K-loop IDENTICAL to mfma_gemm<128> (MI=4, NI=2, ACH=2, BCH=2, LA=4 — R16's NaN was
// a hand-specialized copy with MI=2 and half the B staging; do not diverge again).
// Epilogue: cols 0-255 (v) -> Fv fp8; cols 256-511 (off/attn) -> Foa bf16.
__global__ __launch_bounds__(512) void qkv_gemm(
        const unsigned short* __restrict__ A,   // xn [M,256] bf16
        const unsigned short* __restrict__ BT,  // qkvT [512,256] bf16
        const float* __restrict__ bias,         // qkvB [512]
        unsigned char* __restrict__ Fv,         // [M,256] fp8 e4m3
        unsigned short* __restrict__ Foa,       // [M,256] bf16 (off 0-143, attn 144-215)
        int K) {                                // 256
    constexpr int BN = 128;
    constexpr int MI = 4, NI = 2;
    constexpr int BUFB = 16384 + BN * 128;
    __shared__ __align__(16) char lds[2 * BUFB];
    const int t = threadIdx.x;
    const int w = t >> 6;
    const int l = t & 63;
    const int row0 = blockIdx.x * 128;
    const int col0 = blockIdx.y * BN;
    const int wr = (w / 4) * 64;                // wave grid 2x4: 64 rows x 32 cols each
    const int wc = (w % 4) * 32;

    const int srow = l >> 3;
    const int selem = ((l & 7) ^ srow) * 8;

    auto stage = [&](char* buf, int k0) {       // LA = 4 per wave (2 A + 2 B)
        unsigned short* As_ = (unsigned short*)buf;
        unsigned short* Bs_ = (unsigned short*)(buf + 16384);
        #pragma unroll
        for (int i = 0; i < 2; ++i) {           // A: 16 chunks, 2 per wave
            const int c = w + i * 8;
            const int row = c * 8 + srow;
            gl2lds16(A + (size_t)(row0 + row) * K + k0 + selem, As_ + c * 512);
        }
        #pragma unroll
        for (int i = 0; i < 2; ++i) {           // B: 16 chunks, 2 per wave
            const int c = w + i * 8;
            const int row = c * 8 + srow;
            gl2lds16(BT + (size_t)(col0 + row) * K + k0 + selem, Bs_ + c * 512);
        }
    };

    f32x4 acc[MI][NI] = {};
    stage(lds, 0);
    stage(lds + BUFB, 64);

    for (int tt = 0; tt < 4; ++tt) {
        if (tt + 1 < 4) asm volatile("s_waitcnt vmcnt(4)" ::: "memory");
        else            asm volatile("s_waitcnt vmcnt(0)" ::: "memory");
        __builtin_amdgcn_s_barrier();
        __builtin_amdgcn_sched_barrier(0);

        const char* Ab = lds + (size_t)(tt & 1) * BUFB;
        const char* Bb = Ab + 16384;
        #pragma unroll
        for (int ks = 0; ks < 2; ++ks) {
            const int kb = ks * 64 + (l >> 4) * 16;
            bf16x8 af[MI], bfr[NI];
            #pragma unroll
            for (int mi = 0; mi < MI; ++mi) {
                const int row = wr + mi * 16 + (l & 15);
                af[mi] = *(const bf16x8*)(Ab + row * 128 + (kb ^ ((row & 7) << 4)));
            }
            #pragma unroll
            for (int ni = 0; ni < NI; ++ni) {
                const int row = wc + ni * 16 + (l & 15);
                bfr[ni] = *(const bf16x8*)(Bb + row * 128 + (kb ^ ((row & 7) << 4)));
            }
            #pragma unroll
            for (int mi = 0; mi < MI; ++mi)
                #pragma unroll
                for (int ni = 0; ni < NI; ++ni)
                    acc[mi][ni] = __builtin_amdgcn_mfma_f32_16x16x32_bf16(
                        af[mi], bfr[ni], acc[mi][ni], 0, 0, 0);
        }
        __builtin_amdgcn_s_barrier();
        __builtin_amdgcn_sched_barrier(0);
        if (tt + 2 < 4) stage(lds + (size_t)(tt & 1) * BUFB, (tt + 2) * 64);
    }

    const int lrow = (l >> 4) * 4;
    const int lcol = l & 15;
    if (col0 < 256) {
        // ---- fp8 v epilogue: ROWB = 128 B ----
        #pragma unroll
        for (int ni = 0; ni < NI; ++ni) {
            const int col = wc + ni * 16 + lcol;
            const float bb = bias[col0 + col];
            #pragma unroll
            for (int mi = 0; mi < MI; ++mi) {
                #pragma unroll
                for (int r = 0; r < 4; ++r) {
                    const int row = wr + mi * 16 + lrow + r;
                    *(unsigned char*)(lds + row * 128 + (col ^ ((row & 7) << 4)))
                        = f2fp8(acc[mi][ni][r] + bb);
                }
            }
        }
        __syncthreads();
        const int ck = t & 7;                 // 8 chunks x 16 B = 128 B row
        #pragma unroll
        for (int it = 0; it < 2; ++it) {
            const int row = (t >> 3) + it * 64;
            const int bo = ck * 16;
            *(int4*)(Fv + (size_t)(row0 + row) * 256 + col0 + bo)
                = *(const int4*)(lds + row * 128 + (bo ^ ((row & 7) << 4)));
        }
    } else {
        // ---- bf16 off/attn epilogue: ROWB = 256 B, local col = col0-256 ----
        #pragma unroll
        for (int ni = 0; ni < NI; ++ni) {
            const int col = wc + ni * 16 + lcol;
            const float bb = bias[col0 + col];
            #pragma unroll
            for (int mi = 0; mi < MI; ++mi) {
                #pragma unroll
                for (int r = 0; r < 4; ++r) {
                    const int row = wr + mi * 16 + lrow + r;
                    *(unsigned short*)(lds + row * 256 + ((col * 2) ^ ((row & 7) << 4)))
                        = f2bf(acc[mi][ni][r] + bb);
                }
            }
        }
        __syncthreads();
        const int ck = t & 15;                // 16 chunks x 16 B = 256 B row
        #pragma unroll
        for (int it = 0; it < 4; ++it) {
            const int row = (t >> 4) + it * 32;
            const int bo = ck * 16;
            *(int4*)(Foa + (size_t)(row0 + row) * 256 + (col0 - 256) + bo / 2)
                = *(const int4*)(lds + row * 256 + (bo ^ ((row & 7) << 4)));
        }
    }
}

// ---------------- fp8 MFMA GEMM for w2: out += h2(fp8) @ w2T8(fp8 x32)^T / 32 + b2 ----
__global__ __launch_bounds__(512) void w2_gemm_fp8(
        const unsigned char* __restrict__ A,   // h2 [M,1024] fp8 e4m3
        const unsigned char* __restrict__ BT,  // w2T8 [256,1024] fp8 (x32 scaled)
        const float* __restrict__ bias,        // b2
        const float* __restrict__ resid,       // out (read)
        float* __restrict__ Out,               // out (write)
        int N, int K) {                        // 256, 1024
    constexpr int ABYTES = 128 * 128;          // 16 KB
    constexpr int BUFB = ABYTES + 64 * 128;    // 24 KB
    __shared__ __align__(16) char lds[2 * BUFB];
    const int t = threadIdx.x;
    const int w = t >> 6;
    const int l = t & 63;
    const int row0 = blockIdx.x * 128;
    const int col0 = blockIdx.y * 64;
    const int wr = (w >> 1) * 32;              // wave grid 4x2: MI=2
    const int wc = (w & 1) * 32;               // NI=2

    const int srow = l >> 3;
    const int sbyte = ((l & 7) ^ srow) * 16;   // byte offset (fp8: byte == element)

    auto stage = [&](char* buf, int k0) {      // LA = 3 per wave
        unsigned char* As_ = (unsigned char*)buf;
        unsigned char* Bs_ = (unsigned char*)(buf + ABYTES);
        #pragma unroll
        for (int i = 0; i < 2; ++i) {
            const int c = w + i * 8;
            const int row = c * 8 + srow;
            gl2lds16(A + (size_t)(row0 + row) * K + k0 + sbyte, As_ + c * 1024);
        }
        {
            const int row = w * 8 + srow;
            gl2lds16(BT + (size_t)(col0 + row) * K + k0 + sbyte, Bs_ + w * 1024);
        }
    };

    f32x4 acc[2][2] = {};
    const int nt = K / 128;                    // 8

    stage(lds, 0);
    stage(lds + BUFB, 128);

    for (int tt = 0; tt < nt; ++tt) {
        if (tt + 1 < nt) asm volatile("s_waitcnt vmcnt(3)" ::: "memory");
        else             asm volatile("s_waitcnt vmcnt(0)" ::: "memory");
        __builtin_amdgcn_s_barrier();
        __builtin_amdgcn_sched_barrier(0);

        const char* Ab = lds + (size_t)(tt & 1) * BUFB;
        const char* Bb = Ab + ABYTES;
        #pragma unroll
        for (int ks = 0; ks < 4; ++ks) {
            const int kb = ks * 32 + (l >> 4) * 8;
            long af[2], bfr[2];
            #pragma unroll
            for (int mi = 0; mi < 2; ++mi) {
                const int row = wr + mi * 16 + (l & 15);
                af[mi] = *(const long*)(Ab + row * 128 + (kb ^ ((row & 7) << 4)));
            }
            #pragma unroll
            for (int ni = 0; ni < 2; ++ni) {
                const int row = wc + ni * 16 + (l & 15);
                bfr[ni] = *(const long*)(Bb + row * 128 + (kb ^ ((row & 7) << 4)));
            }
            #pragma unroll
            for (int mi = 0; mi < 2; ++mi)
                #pragma unroll
                for (int ni = 0; ni < 2; ++ni)
                    acc[mi][ni] = __builtin_amdgcn_mfma_f32_16x16x32_fp8_fp8(
                        af[mi], bfr[ni], acc[mi][ni], 0, 0, 0);
        }
        __builtin_amdgcn_s_barrier();
        __builtin_amdgcn_sched_barrier(0);
        if (tt + 2 < nt) stage(lds + (size_t)(tt & 1) * BUFB, (tt + 2) * 128);
    }

    const int lrow = (l >> 4) * 4;
    const int lcol = l & 15;
    #pragma unroll
    for (int ni = 0; ni < 2; ++ni) {
        const int col = wc + ni * 16 + lcol;
        const float bb = bias[col0 + col];
        #pragma unroll
        for (int mi = 0; mi < 2; ++mi) {
            #pragma unroll
            for (int r = 0; r < 4; ++r) {
                const int row = wr + mi * 16 + lrow + r;
                *(float*)(lds + row * 256 + ((col * 4) ^ ((row & 7) << 4)))
                    = acc[mi][ni][r] * 0.03125f + bb;
            }
        }
    }
    __syncthreads();
    const int ck = t & 15;
    #pragma unroll
    for (int it = 0; it < 4; ++it) {
        const int row = (t >> 4) + it * 32;
        const int bo = ck * 16;
        float4 val = *(const float4*)(lds + row * 256 + (bo ^ ((row & 7) << 4)));
        const float4 rv = *(const float4*)(resid + (size_t)(row0 + row) * N + col0 + bo / 4);
        val.x += rv.x; val.y += rv.y; val.z += rv.z; val.w += rv.w;
        *(float4*)(Out + (size_t)(row0 + row) * N + col0 + bo / 4) = val;
    }
}

// ---------------- Fused w_out GEMM + residual + LN2 (BM=32: 512 blocks, 2/CU) ----------
__global__ __launch_bounds__(512) void wout_ln2_kernel(
        const unsigned short* __restrict__ A,   // agg [M,256] bf16
        const unsigned short* __restrict__ BT,  // woutT [256,256] bf16
        const float* __restrict__ bias,         // b_out
        const float* __restrict__ resid,        // x [M,256] f32
        const float* __restrict__ g2, const float* __restrict__ b2,
        float* __restrict__ Out,                // d_out [M,256] f32
        unsigned short* __restrict__ Y) {       // y [M,256] bf16 (disjoint from A)
    constexpr int BM = 32, K = 256;
    constexpr int ABYTES = BM * 128;            // 4 KB
    constexpr int BUFB = ABYTES + 256 * 128;    // 36 KB
    __shared__ __align__(16) char lds[2 * BUFB];// 72 KB (epilogue reuses 32 KB)
    const int t = threadIdx.x;
    const int w = t >> 6;
    const int l = t & 63;
    const int row0 = blockIdx.x * BM;
    const int wr = (w >> 2) * 16;               // wave grid 2x4: MI=1, NI=4
    const int wc = (w & 3) * 64;

    const int srow = l >> 3;
    const int selem = ((l & 7) ^ srow) * 8;

    auto stage = [&](char* buf, int k0) {       // LA: waves 0-3 = 5, waves 4-7 = 4
        unsigned short* As_ = (unsigned short*)buf;
        unsigned short* Bs_ = (unsigned short*)(buf + ABYTES);
        if (w < 4) {                            // A: 4 chunks, waves 0-3
            const int row = w * 8 + srow;
            gl2lds16(A + (size_t)(row0 + row) * K + k0 + selem, As_ + w * 512);
        }
        #pragma unroll
        for (int i = 0; i < 4; ++i) {           // B: 32 chunks, 4 per wave
            const int c = w + i * 8;
            const int row = c * 8 + srow;
            gl2lds16(BT + (size_t)row * K + k0 + selem, Bs_ + c * 512);
        }
    };

    f32x4 acc[1][4] = {};
    stage(lds, 0);
    stage(lds + BUFB, 64);

    for (int tt = 0; tt < 4; ++tt) {
        if (tt + 1 < 4) {                       // per-wave counted wait (uniform branch)
            if (w < 4) asm volatile("s_waitcnt vmcnt(5)" ::: "memory");
            else       asm volatile("s_waitcnt vmcnt(4)" ::: "memory");
        } else {
            asm volatile("s_waitcnt vmcnt(0)" ::: "memory");
        }
        __builtin_amdgcn_s_barrier();
        __builtin_amdgcn_sched_barrier(0);

        const char* Ab = lds + (size_t)(tt & 1) * BUFB;
        const char* Bb = Ab + ABYTES;
        #pragma unroll
        for (int ks = 0; ks < 2; ++ks) {
            const int kb = ks * 64 + (l >> 4) * 16;
            bf16x8 af, bfr[4];
            {
                const int row = wr + (l & 15);
                af = *(const bf16x8*)(Ab + row * 128 + (kb ^ ((row & 7) << 4)));
            }
            #pragma unroll
            for (int ni = 0; ni < 4; ++ni) {
                const int row = wc + ni * 16 + (l & 15);
                bfr[ni] = *(const bf16x8*)(Bb + row * 128 + (kb ^ ((row & 7) << 4)));
            }
            #pragma unroll
            for (int ni = 0; ni < 4; ++ni)
                acc[0][ni] = __builtin_amdgcn_mfma_f32_16x16x32_bf16(
                    af, bfr[ni], acc[0][ni], 0, 0, 0);
        }
        __builtin_amdgcn_s_barrier();
        __builtin_amdgcn_sched_barrier(0);
        if (tt + 2 < 4) stage(lds + (size_t)(tt & 1) * BUFB, (tt + 2) * 64);
    }

    // epilogue 1: f32 C-tile, 32 rows x 1024 B, row-XOR swizzle
    const int lrow = (l >> 4) * 4;
    const int lcol = l & 15;
    #pragma unroll
    for (int ni = 0; ni < 4; ++ni) {
        const int col = wc + ni * 16 + lcol;
        const float bb = bias[col];
        #pragma unroll
        for (int r = 0; r < 4; ++r) {
            const int row = wr + lrow + r;
            *(float*)(lds + row * 1024 + ((col * 4) ^ ((row & 7) << 4))) = acc[0][ni][r] + bb;
        }
    }
    __syncthreads();
    // epilogue 2: one wave per row: + residual, LN stats over 256 cols, dual write
    const float4 gv = *reinterpret_cast<const float4*>(g2 + l * 4);
    const float4 bv = *reinterpret_cast<const float4*>(b2 + l * 4);
    #pragma unroll
    for (int it = 0; it < 4; ++it) {
        const int r = w + it * 8;
        float4 v = *(const float4*)(lds + r * 1024 + ((l * 16) ^ ((r & 7) << 4)));
        const float4 rv = *(const float4*)(resid + (size_t)(row0 + r) * Cc + l * 4);
        v.x += rv.x; v.y += rv.y; v.z += rv.z; v.w += rv.w;
        float s  = v.x + v.y + v.z + v.w;
        float s2 = v.x * v.x + v.y * v.y + v.z * v.z + v.w * v.w;
        #pragma unroll
        for (int o = 32; o > 0; o >>= 1) { s += __shfl_down(s, o); s2 += __shfl_down(s2, o); }
        s = __shfl(s, 0); s2 = __shfl(s2, 0);
        const float mean = s * (1.0f / Cc);
        const float rstd = rsqrtf(s2 * (1.0f / Cc) - mean * mean + 1e-5f);
        *(float4*)(Out + (size_t)(row0 + r) * Cc + l * 4) = v;
        ushort4 o;
        o.x = f2bf((v.x - mean) * rstd * gv.x + bv.x);
        o.y = f2bf((v.y - mean) * rstd * gv.y + bv.y);
        o.z = f2bf((v.z - mean) * rstd * gv.z + bv.z);
        o.w = f2bf((v.w - mean) * rstd * gv.w + bv.w);
        *(ushort4*)(Y + (size_t)(row0 + r) * Cc + l * 4) = o;
    }
}

// ---------------- Deformable sampling: fp8 v gather + bf16 off/attn ----------------
__global__ __launch_bounds__(256) void sample_kernel(const unsigned char* __restrict__ Fv,
        const unsigned short* __restrict__ Foa,
        const float* __restrict__ refp, unsigned short* __restrict__ agg) {
    constexpr int PPB = 4;                       // pixels per block
    constexpr int nblk = Mrows / PPB;            // 4096
    const int bid = blockIdx.x;
    const int qi = (bid & 7) * (nblk / 8) + (bid >> 3);   // XCD-chunked swizzle
    const int m0 = qi * PPB;
    const int b = m0 / NPIX;
    const int pix0 = m0 - b * NPIX;
    const int t = threadIdx.x;
    __shared__ int4   s_idx[PPB][72];
    __shared__ float4 s_w[PPB][72];
    __shared__ float  s_lg[PPB][72];

    for (int idx = t; idx < PPB * 72; idx += 256) {
        const int p = idx / 72, hk = idx - p * 72;
        const int head = hk / 9, k = hk - head * 9;
        const int m = m0 + p, pix = pix0 + p;
        const size_t fb = (size_t)m * 256;
        const unsigned int ou = *(const unsigned int*)(Foa + fb + head * 18 + k * 2);
        const float ox = __uint_as_float(ou << 16);
        const float oy = __uint_as_float(ou & 0xffff0000u);
        const float2 rr = *(const float2*)(refp + ((size_t)pix * KPT + k) * 2);
        const float cx = (rr.x + ox + 1.0f) * 0.5f * (Wc - 1);
        const float cy = (rr.y + oy + 1.0f) * 0.5f * (Hc - 1);
        const float fx = floorf(cx), fy = floorf(cy);
        const float wx = cx - fx, wy = cy - fy;
        const int x0 = min(max((int)fx, 0), Wc - 1);
        const int x1 = min(max((int)fx + 1, 0), Wc - 1);
        const int y0 = min(max((int)fy, 0), Hc - 1);
        const int y1 = min(max((int)fy + 1, 0), Hc - 1);
        s_idx[p][hk] = make_int4(y0 * Wc + x0, y0 * Wc + x1, y1 * Wc + x0, y1 * Wc + x1);
        s_w[p][hk] = make_float4((1.0f - wy) * (1.0f - wx), (1.0f - wy) * wx,
                                 wy * (1.0f - wx), wy * wx);
        s_lg[p][hk] = bf2f(Foa[fb + 144 + hk]);
    }
    __syncthreads();
    for (int idx = t; idx < PPB * 72; idx += 256) {
        const int p = idx / 72, hk = idx - p * 72;
        const int h9 = (hk / 9) * 9;
        float mx = -1e30f;
        #pragma unroll
        for (int k = 0; k < 9; ++k) mx = fmaxf(mx, s_lg[p][h9 + k]);
        float sm = 0.0f;
        #pragma unroll
        for (int k = 0; k < 9; ++k) sm += __expf(s_lg[p][h9 + k] - mx);
        const float a = __expf(s_lg[p][hk] - mx) / sm;
        float4 w = s_w[p][hk];
        w.x *= a; w.y *= a; w.z *= a; w.w *= a;
        s_w[p][hk] = w;
    }
    __syncthreads();
    const int p = t >> 6, tl = t & 63;
    const int head = tl >> 3, dq = tl & 7;
    const unsigned char* vb = Fv + (size_t)b * NPIX * 256 + head * HD + dq * 4;
    float a0 = 0.f, a1 = 0.f, a2 = 0.f, a3 = 0.f;
    #pragma unroll
    for (int k = 0; k < 9; ++k) {
        const int hk = head * 9 + k;
        const int4   ix = s_idx[p][hk];
        const float4 ww = s_w[p][hk];
        {
            const uchar4 u = *(const uchar4*)(vb + (size_t)ix.x * 256);
            a0 += fp82f(u.x) * ww.x; a1 += fp82f(u.y) * ww.x;
            a2 += fp82f(u.z) * ww.x; a3 += fp82f(u.w) * ww.x;
        }
        {
            const uchar4 u = *(const uchar4*)(vb + (size_t)ix.y * 256);
            a0 += fp82f(u.x) * ww.y; a1 += fp82f(u.y) * ww.y;
            a2 += fp82f(u.z) * ww.y; a3 += fp82f(u.w) * ww.y;
        }
        {
            const uchar4 u = *(const uchar4*)(vb + (size_t)ix.z * 256);
            a0 += fp82f(u.x) * ww.z; a1 += fp82f(u.y) * ww.z;
            a2 += fp82f(u.z) * ww.z; a3 += fp82f(u.w) * ww.z;
        }
        {
            const uchar4 u = *(const uchar4*)(vb + (size_t)ix.w * 256);
            a0 += fp82f(u.x) * ww.w; a1 += fp82f(u.y) * ww.w;
            a2 += fp82f(u.z) * ww.w; a3 += fp82f(u.w) * ww.w;
        }
    }
    ushort4 o;
    o.x = f2bf(a0); o.y = f2bf(a1); o.z = f2bf(a2); o.w = f2bf(a3);
    *reinterpret_cast<ushort4*>(agg + (size_t)(m0 + p) * Cc + tl * 4) = o;
}

// ---------------- Depthwise 3x3 conv (circular W, zero H) + GELU, fp8 in / fp8 out ----
__global__ __launch_bounds__(256) void dwconv_kernel(const unsigned char* __restrict__ h,
        const float* __restrict__ wdwT, const float* __restrict__ bdw,
        unsigned char* __restrict__ h2) {
    constexpr int NQ = 8;                     // x-positions per block
    constexpr int nblk = Mrows / NQ;          // 2048
    const int bid = blockIdx.x;
    const int qi = (bid & 7) * (nblk / 8) + (bid >> 3);   // XCD-chunked swizzle
    const int m0 = qi * NQ;
    const int b = m0 / NPIX;
    const int pix0 = m0 - b * NPIX;
    const int y = pix0 / Wc, x0 = pix0 - y * Wc;
    const int t = threadIdx.x;
    const int c0 = t * 4;

    float wreg[9][4];
    #pragma unroll
    for (int j = 0; j < 9; ++j) {
        const float4 wv = *reinterpret_cast<const float4*>(wdwT + j * HIDDEN + c0);
        wreg[j][0] = wv.x; wreg[j][1] = wv.y; wreg[j][2] = wv.z; wreg[j][3] = wv.w;
    }

    float acc[NQ][4] = {};
    #pragma unroll
    for (int dy = -1; dy <= 1; ++dy) {
        const int yy = y + dy;
        if (yy < 0 || yy >= Hc) continue;     // zero pad along height
        const size_t rowbase = ((size_t)b * NPIX + (size_t)yy * Wc) * HIDDEN + c0;
        #pragma unroll
        for (int j = 0; j < NQ + 2; ++j) {    // columns x0-1 .. x0+NQ (circular)
            const int xx = (x0 + j - 1 + Wc) & (Wc - 1);
            const uchar4 hv = *reinterpret_cast<const uchar4*>(h + rowbase + (size_t)xx * HIDDEN);
            const float f0 = fp82f(hv.x), f1 = fp82f(hv.y), f2 = fp82f(hv.z), f3 = fp82f(hv.w);
            #pragma unroll
            for (int q = 0; q < NQ; ++q) {
                if (q >= j - 2 && q <= j) {
                    const int wj = (dy + 1) * 3 + (j - q);
                    acc[q][0] += f0 * wreg[wj][0];
                    acc[q][1] += f1 * wreg[wj][1];
                    acc[q][2] += f2 * wreg[wj][2];
                    acc[q][3] += f3 * wreg[wj][3];
                }
            }
        }
    }
    const float4 bb = *reinterpret_cast<const float4*>(bdw + c0);
    #pragma unroll
    for (int q = 0; q < NQ; ++q) {
        uchar4 o;
        o.x = f2fp8(gelu_exact(acc[q][0] + bb.x));
        o.y = f2fp8(gelu_exact(acc[q][1] + bb.y));
        o.z = f2fp8(gelu_exact(acc[q][2] + bb.z));
        o.w = f2fp8(gelu_exact(acc[q][3] + bb.w));
        *reinterpret_cast<uchar4*>(h2 + (size_t)(m0 + q) * HIDDEN + c0) = o;
    }
}

extern "C" void kernel_launch(void* const* d_in, const int* in_sizes, int n_in,
                              void* d_out, int out_size, void* d_ws, size_t ws_size,
                              hipStream_t stream) {
    const float* x      = (const float*)d_in[0];
    const float* refp   = (const float*)d_in[1];
    const float* ln1_g  = (const float*)d_in[2];
    const float* ln1_b  = (const float*)d_in[3];
    const float* w_v    = (const float*)d_in[4];
    const float* b_v    = (const float*)d_in[5];
    const float* w_off  = (const float*)d_in[6];
    const float* b_off  = (const float*)d_in[7];
    const float* w_attn = (const float*)d_in[8];
    const float* b_attn = (const float*)d_in[9];
    const float* w_out  = (const float*)d_in[10];
    const float* b_out  = (const float*)d_in[11];
    const float* ln2_g  = (const float*)d_in[12];
    const float* ln2_b  = (const float*)d_in[13];
    const float* w1     = (const float*)d_in[14];
    const float* b1     = (const float*)d_in[15];
    const float* w_dw   = (const float*)d_in[16];
    const float* b_dw   = (const float*)d_in[17];
    const float* w2     = (const float*)d_in[18];
    const float* b2     = (const float*)d_in[19];
    float* out = (float*)d_out;

    // Workspace layout (bytes). Each region written by one kernel, read by LATER
    // kernels only; no intra-kernel read/write aliasing (R12 lesson).
    //  [0,  8M): A    = xn (s1) -> agg (s3); dead after s4
    //  [8, 16M): Foa  bf16 off/attn (s2); dead after s3
    //  [16,20M): Fv   fp8 v (s2); dead after s3
    //  [8, 16M)  y    = LN2 out (s4, reuses dead Foa); dead after s5
    //  [32,48M): h    fp8 (s5); dead after s6
    //  [16,32M): h2   fp8 (s6, reuses dead Fv + fresh); dead after s7
    //  [64M,..): weights: qkvT/woutT/w1T bf16, w2T8 fp8(x32), wdwT f32, qkvB
    char* wsb = (char*)d_ws;
    unsigned short* Abuf = (unsigned short*)(wsb);
    unsigned short* Foa  = (unsigned short*)(wsb + (8ull  << 20));
    unsigned char*  Fv   = (unsigned char*)(wsb + (16ull << 20));
    unsigned short* ybuf = (unsigned short*)(wsb + (8ull  << 20));
    unsigned char*  hbuf = (unsigned char*)(wsb + (32ull << 20));
    unsigned char*  h2   = (unsigned char*)(wsb + (16ull << 20));
    size_t woff = 64ull << 20;
    unsigned short* qkvT = (unsigned short*)(wsb + woff); woff += (size_t)NQKV * 256 * 2;
    unsigned short* woutT= (unsigned short*)(wsb + woff); woff += 256 * 256 * 2;
    unsigned short* w1T  = (unsigned short*)(wsb + woff); woff += 1024 * 256 * 2;
    unsigned char*  w2T8 = (unsigned char*)(wsb + woff);  woff += 256 * 1024;
    float*          wdwT = (float*)(wsb + woff);          woff += 9 * 1024 * 4;
    float*          qkvB = (float*)(wsb + woff);

    // 1. merged LN1 + weight prep (one dispatch)
    prepln_kernel<<<Mrows / 4 + NQKV + 256 + 1024 + 256 + 9, 256, 0, stream>>>(
        x, ln1_g, ln1_b, Abuf,
        w_v, b_v, w_off, b_off, w_attn, b_attn, w_out, w1, w2, w_dw,
        qkvT, qkvB, woutT, w1T, w2T8, wdwT);
    // 2. QKV GEMM, dual epilogue: v -> Fv fp8, off/attn -> Foa bf16
    qkv_gemm<<<dim3(Mrows / 128, NQKV / 128), 512, 0, stream>>>(
        Abuf, qkvT, qkvB, Fv, Foa, 256);
    // 3. deformable sampling (fp8 v gather) -> agg (A region)
    sample_kernel<<<Mrows / 4, 256, 0, stream>>>(Fv, Foa, refp, Abuf);
    // 4. fused: out = x + agg @ w_out + b_out;  y = LN2(out) -> ybuf (disjoint)
    wout_ln2_kernel<<<Mrows / 32, 512, 0, stream>>>(
        Abuf, woutT, b_out, x, ln2_g, ln2_b, out, ybuf);
    // 5. h = gelu(y @ w1 + b1) -> fp8 e4m3
    mfma_gemm<128, true, false, unsigned char><<<dim3(Mrows / 128, 1024 / 128), 512, 0, stream>>>(
        ybuf, w1T, b1, nullptr, hbuf, 1024, 256);
    // 6. depthwise conv + gelu: fp8 in -> fp8 h2
    dwconv_kernel<<<Mrows / 8, 256, 0, stream>>>(hbuf, wdwT, b_dw, h2);
    // 7. out += (h2 @ w2T8^T)/32 + b2  (fp8 x fp8 MFMA, f32 accum)
    w2_gemm_fp8<<<dim3(Mrows / 128, 256 / 64), 512, 0, stream>>>(
        h2, w2T8, b2, out, out, 256, 1024);
}

// Round 18
// 110.959 us; speedup vs baseline: 1.2079x; 1.0212x over previous
//
#include <hip/hip_runtime.h>
#include <hip/hip_bf16.h>
#include <hip/hip_fp8.h>
#include <type_traits>

// Problem constants
constexpr int Bc = 2, Hc = 64, Wc = 128, Cc = 256;
constexpr int HEADS = 8, KPT = 9, HIDDEN = 1024;
constexpr int HD = Cc / HEADS;           // 32
constexpr int NPIX = Hc * Wc;            // 8192
constexpr int Mrows = Bc * NPIX;         // 16384
constexpr int NQKV = 512;                // 256 (v) + 144 (off) + 72 (attn) padded to 512

typedef __attribute__((ext_vector_type(4))) float f32x4;
typedef __attribute__((ext_vector_type(8))) short bf16x8;

__device__ __forceinline__ float bf2f(unsigned short u) {
    union { unsigned int i; float f; } c; c.i = ((unsigned int)u) << 16; return c.f;
}
__device__ __forceinline__ unsigned short f2bf(float f) {
    __hip_bfloat16 h = __float2bfloat16(f);
    return *reinterpret_cast<unsigned short*>(&h);
}
__device__ __forceinline__ unsigned char f2fp8(float f) {
    return __hip_fp8_e4m3(f).__x;        // OCP e4m3 (gfx950)
}
__device__ __forceinline__ float fp82f(unsigned char u) {
    __hip_fp8_e4m3 v; v.__x = u; return (float)v;
}
__device__ __forceinline__ float gelu_exact(float x) {
    return 0.5f * x * (1.0f + erff(x * 0.70710678118654752f));
}
__device__ __forceinline__ void gl2lds16(const void* g, void* l) {
    __builtin_amdgcn_global_load_lds(
        (const __attribute__((address_space(1))) unsigned int*)g,
        (__attribute__((address_space(3))) unsigned int*)l, 16, 0, 0);
}

// ---------------- Merged: LN1 (wave per row) + weight prep, one launch ----------------
__global__ __launch_bounds__(256) void prepln_kernel(
        const float* __restrict__ x, const float* __restrict__ ln1_g,
        const float* __restrict__ ln1_b, unsigned short* __restrict__ xn,
        const float* __restrict__ w_v, const float* __restrict__ b_v,
        const float* __restrict__ w_off, const float* __restrict__ b_off,
        const float* __restrict__ w_attn, const float* __restrict__ b_attn,
        const float* __restrict__ w_out, const float* __restrict__ w1,
        const float* __restrict__ w2, const float* __restrict__ w_dw,
        unsigned short* __restrict__ qkvT, float* __restrict__ qkvB,
        unsigned short* __restrict__ woutT, unsigned short* __restrict__ w1T,
        unsigned char* __restrict__ w2T8, float* __restrict__ wdwT) {
    const int t = threadIdx.x;
    if (blockIdx.x < Mrows / 4) {              // ---- LN1: 4 rows per block, wave/row ----
        const int r = blockIdx.x * 4 + (t >> 6);
        const int l = t & 63;
        const size_t base = (size_t)r * Cc + l * 4;
        const float4 v = *reinterpret_cast<const float4*>(x + base);
        float s  = v.x + v.y + v.z + v.w;
        float s2 = v.x * v.x + v.y * v.y + v.z * v.z + v.w * v.w;
        #pragma unroll
        for (int o = 32; o > 0; o >>= 1) { s += __shfl_down(s, o); s2 += __shfl_down(s2, o); }
        s = __shfl(s, 0); s2 = __shfl(s2, 0);
        const float mean = s * (1.0f / Cc);
        const float rstd = rsqrtf(s2 * (1.0f / Cc) - mean * mean + 1e-5f);
        const float4 gv = *reinterpret_cast<const float4*>(ln1_g + l * 4);
        const float4 bv = *reinterpret_cast<const float4*>(ln1_b + l * 4);
        ushort4 o;
        o.x = f2bf((v.x - mean) * rstd * gv.x + bv.x);
        o.y = f2bf((v.y - mean) * rstd * gv.y + bv.y);
        o.z = f2bf((v.z - mean) * rstd * gv.z + bv.z);
        o.w = f2bf((v.w - mean) * rstd * gv.w + bv.w);
        *reinterpret_cast<ushort4*>(xn + base) = o;
        return;
    }
    const int blk = blockIdx.x - Mrows / 4;    // ---- weight prep ----
    if (blk < NQKV) {                      // qkvT row n, K=256
        const int n = blk;
        float val = 0.0f;
        if (n < 256)       val = w_v[t * 256 + n];
        else if (n < 400)  val = w_off[t * 144 + (n - 256)];
        else if (n < 472)  val = w_attn[t * 72 + (n - 400)];
        qkvT[n * 256 + t] = f2bf(val);
        if (t == 0) {
            float bv = 0.0f;
            if (n < 256)      bv = b_v[n];
            else if (n < 400) bv = b_off[n - 256];
            else if (n < 472) bv = b_attn[n - 400];
            qkvB[n] = bv;
        }
    } else if (blk < NQKV + 256) {         // woutT row n, K=256
        const int n = blk - NQKV;
        woutT[n * 256 + t] = f2bf(w_out[t * 256 + n]);
    } else if (blk < NQKV + 256 + 1024) {  // w1T row n, K=256
        const int n = blk - (NQKV + 256);
        w1T[n * 256 + t] = f2bf(w1[t * 1024 + n]);
    } else if (blk < NQKV + 256 + 1024 + 256) { // w2T8 row n, K=1024, fp8 x32 scale
        const int n = blk - (NQKV + 256 + 1024);
        #pragma unroll
        for (int k = t; k < 1024; k += 256)
            w2T8[n * 1024 + k] = f2fp8(w2[k * 256 + n] * 32.0f);
    } else {                               // wdwT row j (9 rows)
        const int j = blk - (NQKV + 256 + 1024 + 256);
        #pragma unroll
        for (int c = t; c < HIDDEN; c += 256)
            wdwT[j * HIDDEN + c] = w_dw[c * 9 + j];
    }
}

// ---------------- bf16 MFMA GEMM: Out[M,N] = A @ BT^T + bias ----------------
// Tile 128 x BN, BK=64, 512 threads (8 waves) — best measured config (R10).
// K-loop: counted-vmcnt 2-tile-ahead pipeline. Epilogue: C-tile staged in dead LDS,
// full-sector write-back (R9). TO = float / bf16(ushort) / fp8(uchar, e4m3).
template<int BN, bool GELU, bool RESID, typename TO>
__global__ __launch_bounds__(512) void mfma_gemm(
        const unsigned short* __restrict__ A,   // [M,K] bf16
        const unsigned short* __restrict__ BT,  // [N,K] bf16
        const float* __restrict__ bias,         // [N]
        const float* __restrict__ resid,        // [M,N] f32 (if RESID)
        TO* __restrict__ Out,                   // [M,N]
        int N, int K) {
    constexpr int WCOLS = (BN == 128) ? 4 : 2;  // waves along N
    constexpr int WROWS = 8 / WCOLS;            // waves along M
    constexpr int MI = 128 / (WROWS * 16);      // 16-row fragments per wave
    constexpr int NI = BN / (WCOLS * 16);       // 16-col fragments per wave
    constexpr int ACH = 2;                      // A chunks staged per wave (16 total)
    constexpr int BCH = (BN / 8) / 8;           // B chunks per wave (2 or 1)
    constexpr int LA = ACH + BCH;               // per-wave loads per stage
    constexpr int BUFB = 16384 + BN * 128;      // A tile 16 KB + B tile
    __shared__ __align__(16) char lds[2 * BUFB];
    const int t = threadIdx.x;
    const int w = t >> 6;
    const int l = t & 63;
    const int row0 = blockIdx.x * 128;
    const int col0 = blockIdx.y * BN;
    const int wr = (w / WCOLS) * (MI * 16);     // wave row offset in tile
    const int wc = (w % WCOLS) * (NI * 16);     // wave col offset in tile

    const int srow = l >> 3;
    const int selem = ((l & 7) ^ srow) * 8;     // XOR-swizzled source slot

    auto stage = [&](char* buf, int k0) {
        unsigned short* As_ = (unsigned short*)buf;
        unsigned short* Bs_ = (unsigned short*)(buf + 16384);
        #pragma unroll
        for (int i = 0; i < ACH; ++i) {         // A tile: 16 chunks, 2 per wave
            const int c = w + i * 8;
            const int row = c * 8 + srow;
            gl2lds16(A + (size_t)(row0 + row) * K + k0 + selem, As_ + c * 512);
        }
        #pragma unroll
        for (int i = 0; i < BCH; ++i) {         // B tile: BN/8 chunks
            const int c = w + i * 8;
            const int row = c * 8 + srow;
            gl2lds16(BT + (size_t)(col0 + row) * K + k0 + selem, Bs_ + c * 512);
        }
    };

    f32x4 acc[MI][NI] = {};
    const int nt = K / 64;

    stage(lds, 0);
    stage(lds + BUFB, 64);

    for (int tt = 0; tt < nt; ++tt) {
        if (tt + 1 < nt) {
            if constexpr (LA == 4) asm volatile("s_waitcnt vmcnt(4)" ::: "memory");
            else                   asm volatile("s_waitcnt vmcnt(3)" ::: "memory");
        } else {
            asm volatile("s_waitcnt vmcnt(0)" ::: "memory");
        }
        __builtin_amdgcn_s_barrier();
        __builtin_amdgcn_sched_barrier(0);

        const char* Ab = lds + (size_t)(tt & 1) * BUFB;
        const char* Bb = Ab + 16384;
        #pragma unroll
        for (int ks = 0; ks < 2; ++ks) {
            const int kb = ks * 64 + (l >> 4) * 16;
            bf16x8 af[MI], bfr[NI];
            #pragma unroll
            for (int mi = 0; mi < MI; ++mi) {
                const int row = wr + mi * 16 + (l & 15);
                af[mi] = *(const bf16x8*)(Ab + row * 128 + (kb ^ ((row & 7) << 4)));
            }
            #pragma unroll
            for (int ni = 0; ni < NI; ++ni) {
                const int row = wc + ni * 16 + (l & 15);
                bfr[ni] = *(const bf16x8*)(Bb + row * 128 + (kb ^ ((row & 7) << 4)));
            }
            #pragma unroll
            for (int mi = 0; mi < MI; ++mi)
                #pragma unroll
                for (int ni = 0; ni < NI; ++ni)
                    acc[mi][ni] = __builtin_amdgcn_mfma_f32_16x16x32_bf16(
                        af[mi], bfr[ni], acc[mi][ni], 0, 0, 0);
        }
        __builtin_amdgcn_s_barrier();
        __builtin_amdgcn_sched_barrier(0);
        if (tt + 2 < nt) stage(lds + (size_t)(tt & 1) * BUFB, (tt + 2) * 64);
    }

    // epilogue 1: C-tile to LDS, row stride ROWB = BN*sizeof(TO), row-XOR swizzle.
    constexpr int ROWB = BN * (int)sizeof(TO);
    const int lrow = (l >> 4) * 4;
    const int lcol = l & 15;
    #pragma unroll
    for (int ni = 0; ni < NI; ++ni) {
        const int col = wc + ni * 16 + lcol;
        const float bb = bias[col0 + col];
        #pragma unroll
        for (int mi = 0; mi < MI; ++mi) {
            #pragma unroll
            for (int r = 0; r < 4; ++r) {
                const int row = wr + mi * 16 + lrow + r;
                float v = acc[mi][ni][r] + bb;
                if constexpr (GELU) v = gelu_exact(v);
                if constexpr (std::is_same<TO, unsigned short>::value) {
                    *(unsigned short*)(lds + row * ROWB + ((col * 2) ^ ((row & 7) << 4))) = f2bf(v);
                } else if constexpr (std::is_same<TO, unsigned char>::value) {
                    *(unsigned char*)(lds + row * ROWB + ((col) ^ ((row & 7) << 4))) = f2fp8(v);
                } else {
                    *(float*)(lds + row * ROWB + ((col * 4) ^ ((row & 7) << 4))) = v;
                }
            }
        }
    }
    __syncthreads();
    // epilogue 2: full-sector write-back (ROWB/16 lanes cover one complete row)
    constexpr int CPR = ROWB / 16;
    constexpr int RPI = 512 / CPR;
    const int ck = t % CPR;
    #pragma unroll
    for (int it = 0; it < 128 / RPI; ++it) {
        const int row = (t / CPR) + it * RPI;
        const int bo = ck * 16;
        const char* src = lds + row * ROWB + (bo ^ ((row & 7) << 4));
        if constexpr (std::is_same<TO, unsigned short>::value) {
            *(int4*)(Out + (size_t)(row0 + row) * N + col0 + bo / 2) = *(const int4*)src;
        } else if constexpr (std::is_same<TO, unsigned char>::value) {
            *(int4*)(Out + (size_t)(row0 + row) * N + col0 + bo) = *(const int4*)src;
        } else {
            float4 val = *(const float4*)src;
            if constexpr (RESID) {
                const float4 rv = *(const float4*)(resid + (size_t)(row0 + row) * N + col0 + bo / 4);
                val.x += rv.x; val.y += rv.y; val.z += rv.z; val.w += rv.w;
            }
            *(float4*)((float*)Out + (size_t)(row0 + row) * N + col0 + bo / 4) = val;
        }
    }
}

// ---------------- QKV GEMM with dual-dtype epilogue ----------------
// K-loop IDENTICAL to mfma_gemm<128> (MI=4, NI=2, ACH=2, BCH=2, LA=4).
// Epilogue: cols 0-255 (v) -> Fv fp8; cols 256-511 (off/attn) -> Foa bf16.
__global__ __launch_bounds__(512) void qkv_gemm(
        const unsigned short* __restrict__ A,   // xn [M,256] bf16
        const unsigned short* __restrict__ BT,  // qkvT [512,256] bf16
        const float* __restrict__ bias,         // qkvB [512]
        unsigned char* __restrict__ Fv,         // [M,256] fp8 e4m3
        unsigned short* __restrict__ Foa,       // [M,256] bf16 (off 0-143, attn 144-215)
        int K) {                                // 256
    constexpr int BN = 128;
    constexpr int MI = 4, NI = 2;
    constexpr int BUFB = 16384 + BN * 128;
    __shared__ __align__(16) char lds[2 * BUFB];
    const int t = threadIdx.x;
    const int w = t >> 6;
    const int l = t & 63;
    const int row0 = blockIdx.x * 128;
    const int col0 = blockIdx.y * BN;
    const int wr = (w / 4) * 64;                // wave grid 2x4: 64 rows x 32 cols each
    const int wc = (w % 4) * 32;

    const int srow = l >> 3;
    const int selem = ((l & 7) ^ srow) * 8;

    auto stage = [&](char* buf, int k0) {       // LA = 4 per wave (2 A + 2 B)
        unsigned short* As_ = (unsigned short*)buf;
        unsigned short* Bs_ = (unsigned short*)(buf + 16384);
        #pragma unroll
        for (int i = 0; i < 2; ++i) {           // A: 16 chunks, 2 per wave
            const int c = w + i * 8;
            const int row = c * 8 + srow;
            gl2lds16(A + (size_t)(row0 + row) * K + k0 + selem, As_ + c * 512);
        }
        #pragma unroll
        for (int i = 0; i < 2; ++i) {           // B: 16 chunks, 2 per wave
            const int c = w + i * 8;
            const int row = c * 8 + srow;
            gl2lds16(BT + (size_t)(col0 + row) * K + k0 + selem, Bs_ + c * 512);
        }
    };

    f32x4 acc[MI][NI] = {};
    stage(lds, 0);
    stage(lds + BUFB, 64);

    for (int tt = 0; tt < 4; ++tt) {
        if (tt + 1 < 4) asm volatile("s_waitcnt vmcnt(4)" ::: "memory");
        else            asm volatile("s_waitcnt vmcnt(0)" ::: "memory");
        __builtin_amdgcn_s_barrier();
        __builtin_amdgcn_sched_barrier(0);

        const char* Ab = lds + (size_t)(tt & 1) * BUFB;
        const char* Bb = Ab + 16384;
        #pragma unroll
        for (int ks = 0; ks < 2; ++ks) {
            const int kb = ks * 64 + (l >> 4) * 16;
            bf16x8 af[MI], bfr[NI];
            #pragma unroll
            for (int mi = 0; mi < MI; ++mi) {
                const int row = wr + mi * 16 + (l & 15);
                af[mi] = *(const bf16x8*)(Ab + row * 128 + (kb ^ ((row & 7) << 4)));
            }
            #pragma unroll
            for (int ni = 0; ni < NI; ++ni) {
                const int row = wc + ni * 16 + (l & 15);
                bfr[ni] = *(const bf16x8*)(Bb + row * 128 + (kb ^ ((row & 7) << 4)));
            }
            #pragma unroll
            for (int mi = 0; mi < MI; ++mi)
                #pragma unroll
                for (int ni = 0; ni < NI; ++ni)
                    acc[mi][ni] = __builtin_amdgcn_mfma_f32_16x16x32_bf16(
                        af[mi], bfr[ni], acc[mi][ni], 0, 0, 0);
        }
        __builtin_amdgcn_s_barrier();
        __builtin_amdgcn_sched_barrier(0);
        if (tt + 2 < 4) stage(lds + (size_t)(tt & 1) * BUFB, (tt + 2) * 64);
    }

    const int lrow = (l >> 4) * 4;
    const int lcol = l & 15;
    if (col0 < 256) {
        // ---- fp8 v epilogue: ROWB = 128 B ----
        #pragma unroll
        for (int ni = 0; ni < NI; ++ni) {
            const int col = wc + ni * 16 + lcol;
            const float bb = bias[col0 + col];
            #pragma unroll
            for (int mi = 0; mi < MI; ++mi) {
                #pragma unroll
                for (int r = 0; r < 4; ++r) {
                    const int row = wr + mi * 16 + lrow + r;
                    *(unsigned char*)(lds + row * 128 + (col ^ ((row & 7) << 4)))
                        = f2fp8(acc[mi][ni][r] + bb);
                }
            }
        }
        __syncthreads();
        const int ck = t & 7;                 // 8 chunks x 16 B = 128 B row
        #pragma unroll
        for (int it = 0; it < 2; ++it) {
            const int row = (t >> 3) + it * 64;
            const int bo = ck * 16;
            *(int4*)(Fv + (size_t)(row0 + row) * 256 + col0 + bo)
                = *(const int4*)(lds + row * 128 + (bo ^ ((row & 7) << 4)));
        }
    } else {
        // ---- bf16 off/attn epilogue: ROWB = 256 B, local col = col0-256 ----
        #pragma unroll
        for (int ni = 0; ni < NI; ++ni) {
            const int col = wc + ni * 16 + lcol;
            const float bb = bias[col0 + col];
            #pragma unroll
            for (int mi = 0; mi < MI; ++mi) {
                #pragma unroll
                for (int r = 0; r < 4; ++r) {
                    const int row = wr + mi * 16 + lrow + r;
                    *(unsigned short*)(lds + row * 256 + ((col * 2) ^ ((row & 7) << 4)))
                        = f2bf(acc[mi][ni][r] + bb);
                }
            }
        }
        __syncthreads();
        const int ck = t & 15;                // 16 chunks x 16 B = 256 B row
        #pragma unroll
        for (int it = 0; it < 4; ++it) {
            const int row = (t >> 4) + it * 32;
            const int bo = ck * 16;
            *(int4*)(Foa + (size_t)(row0 + row) * 256 + (col0 - 256) + bo / 2)
                = *(const int4*)(lds + row * 256 + (bo ^ ((row & 7) << 4)));
        }
    }
}

// ---------------- fp8 MFMA GEMM for w2: out = x2(bf16) + (h2 @ w2T8^T)/32 + b2 ----
// R18: residual handoff is bf16 x2 (written by wout_ln2); this kernel is the sole
// writer of d_out. Saves the f32 out round-trip (16+16 -> 8+8 MB).
__global__ __launch_bounds__(512) void w2_gemm_fp8(
        const unsigned char* __restrict__ A,   // h2 [M,1024] fp8 e4m3
        const unsigned char* __restrict__ BT,  // w2T8 [256,1024] fp8 (x32 scaled)
        const float* __restrict__ bias,        // b2
        const unsigned short* __restrict__ x2b,// x2 [M,256] bf16 (residual)
        float* __restrict__ Out,               // d_out [M,256] f32
        int N, int K) {                        // 256, 1024
    constexpr int ABYTES = 128 * 128;          // 16 KB
    constexpr int BUFB = ABYTES + 64 * 128;    // 24 KB
    __shared__ __align__(16) char lds[2 * BUFB];
    const int t = threadIdx.x;
    const int w = t >> 6;
    const int l = t & 63;
    const int row0 = blockIdx.x * 128;
    const int col0 = blockIdx.y * 64;
    const int wr = (w >> 1) * 32;              // wave grid 4x2: MI=2
    const int wc = (w & 1) * 32;               // NI=2

    const int srow = l >> 3;
    const int sbyte = ((l & 7) ^ srow) * 16;   // byte offset (fp8: byte == element)

    auto stage = [&](char* buf, int k0) {      // LA = 3 per wave
        unsigned char* As_ = (unsigned char*)buf;
        unsigned char* Bs_ = (unsigned char*)(buf + ABYTES);
        #pragma unroll
        for (int i = 0; i < 2; ++i) {
            const int c = w + i * 8;
            const int row = c * 8 + srow;
            gl2lds16(A + (size_t)(row0 + row) * K + k0 + sbyte, As_ + c * 1024);
        }
        {
            const int row = w * 8 + srow;
            gl2lds16(BT + (size_t)(col0 + row) * K + k0 + sbyte, Bs_ + w * 1024);
        }
    };

    f32x4 acc[2][2] = {};
    const int nt = K / 128;                    // 8

    stage(lds, 0);
    stage(lds + BUFB, 128);

    for (int tt = 0; tt < nt; ++tt) {
        if (tt + 1 < nt) asm volatile("s_waitcnt vmcnt(3)" ::: "memory");
        else             asm volatile("s_waitcnt vmcnt(0)" ::: "memory");
        __builtin_amdgcn_s_barrier();
        __builtin_amdgcn_sched_barrier(0);

        const char* Ab = lds + (size_t)(tt & 1) * BUFB;
        const char* Bb = Ab + ABYTES;
        #pragma unroll
        for (int ks = 0; ks < 4; ++ks) {
            const int kb = ks * 32 + (l >> 4) * 8;
            long af[2], bfr[2];
            #pragma unroll
            for (int mi = 0; mi < 2; ++mi) {
                const int row = wr + mi * 16 + (l & 15);
                af[mi] = *(const long*)(Ab + row * 128 + (kb ^ ((row & 7) << 4)));
            }
            #pragma unroll
            for (int ni = 0; ni < 2; ++ni) {
                const int row = wc + ni * 16 + (l & 15);
                bfr[ni] = *(const long*)(Bb + row * 128 + (kb ^ ((row & 7) << 4)));
            }
            #pragma unroll
            for (int mi = 0; mi < 2; ++mi)
                #pragma unroll
                for (int ni = 0; ni < 2; ++ni)
                    acc[mi][ni] = __builtin_amdgcn_mfma_f32_16x16x32_fp8_fp8(
                        af[mi], bfr[ni], acc[mi][ni], 0, 0, 0);
        }
        __builtin_amdgcn_s_barrier();
        __builtin_amdgcn_sched_barrier(0);
        if (tt + 2 < nt) stage(lds + (size_t)(tt & 1) * BUFB, (tt + 2) * 128);
    }

    const int lrow = (l >> 4) * 4;
    const int lcol = l & 15;
    #pragma unroll
    for (int ni = 0; ni < 2; ++ni) {
        const int col = wc + ni * 16 + lcol;
        const float bb = bias[col0 + col];
        #pragma unroll
        for (int mi = 0; mi < 2; ++mi) {
            #pragma unroll
            for (int r = 0; r < 4; ++r) {
                const int row = wr + mi * 16 + lrow + r;
                *(float*)(lds + row * 256 + ((col * 4) ^ ((row & 7) << 4)))
                    = acc[mi][ni][r] * 0.03125f + bb;
            }
        }
    }
    __syncthreads();
    const int ck = t & 15;
    #pragma unroll
    for (int it = 0; it < 4; ++it) {
        const int row = (t >> 4) + it * 32;
        const int bo = ck * 16;
        float4 val = *(const float4*)(lds + row * 256 + (bo ^ ((row & 7) << 4)));
        const ushort4 rv = *(const ushort4*)(x2b + (size_t)(row0 + row) * N + col0 + bo / 4);
        val.x += bf2f(rv.x); val.y += bf2f(rv.y); val.z += bf2f(rv.z); val.w += bf2f(rv.w);
        *(float4*)(Out + (size_t)(row0 + row) * N + col0 + bo / 4) = val;
    }
}

// ---------------- Fused w_out GEMM + residual + LN2 (BM=32: 512 blocks, 2/CU) ----------
// R18: writes x2 as bf16 (for w2's residual) + y = LN2(x2) bf16; no f32 out write.
__global__ __launch_bounds__(512) void wout_ln2_kernel(
        const unsigned short* __restrict__ A,   // agg [M,256] bf16
        const unsigned short* __restrict__ BT,  // woutT [256,256] bf16
        const float* __restrict__ bias,         // b_out
        const float* __restrict__ resid,        // x [M,256] f32
        const float* __restrict__ g2, const float* __restrict__ b2,
        unsigned short* __restrict__ X2,        // x2 [M,256] bf16 (disjoint from A)
        unsigned short* __restrict__ Y) {       // y [M,256] bf16 (disjoint from A)
    constexpr int BM = 32, K = 256;
    constexpr int ABYTES = BM * 128;            // 4 KB
    constexpr int BUFB = ABYTES + 256 * 128;    // 36 KB
    __shared__ __align__(16) char lds[2 * BUFB];// 72 KB (epilogue reuses 32 KB)
    const int t = threadIdx.x;
    const int w = t >> 6;
    const int l = t & 63;
    const int row0 = blockIdx.x * BM;
    const int wr = (w >> 2) * 16;               // wave grid 2x4: MI=1, NI=4
    const int wc = (w & 3) * 64;

    const int srow = l >> 3;
    const int selem = ((l & 7) ^ srow) * 8;

    auto stage = [&](char* buf, int k0) {       // LA: waves 0-3 = 5, waves 4-7 = 4
        unsigned short* As_ = (unsigned short*)buf;
        unsigned short* Bs_ = (unsigned short*)(buf + ABYTES);
        if (w < 4) {                            // A: 4 chunks, waves 0-3
            const int row = w * 8 + srow;
            gl2lds16(A + (size_t)(row0 + row) * K + k0 + selem, As_ + w * 512);
        }
        #pragma unroll
        for (int i = 0; i < 4; ++i) {           // B: 32 chunks, 4 per wave
            const int c = w + i * 8;
            const int row = c * 8 + srow;
            gl2lds16(BT + (size_t)row * K + k0 + selem, Bs_ + c * 512);
        }
    };

    f32x4 acc[1][4] = {};
    stage(lds, 0);
    stage(lds + BUFB, 64);

    for (int tt = 0; tt < 4; ++tt) {
        if (tt + 1 < 4) {                       // per-wave counted wait (uniform branch)
            if (w < 4) asm volatile("s_waitcnt vmcnt(5)" ::: "memory");
            else       asm volatile("s_waitcnt vmcnt(4)" ::: "memory");
        } else {
            asm volatile("s_waitcnt vmcnt(0)" ::: "memory");
        }
        __builtin_amdgcn_s_barrier();
        __builtin_amdgcn_sched_barrier(0);

        const char* Ab = lds + (size_t)(tt & 1) * BUFB;
        const char* Bb = Ab + ABYTES;
        #pragma unroll
        for (int ks = 0; ks < 2; ++ks) {
            const int kb = ks * 64 + (l >> 4) * 16;
            bf16x8 af, bfr[4];
            {
                const int row = wr + (l & 15);
                af = *(const bf16x8*)(Ab + row * 128 + (kb ^ ((row & 7) << 4)));
            }
            #pragma unroll
            for (int ni = 0; ni < 4; ++ni) {
                const int row = wc + ni * 16 + (l & 15);
                bfr[ni] = *(const bf16x8*)(Bb + row * 128 + (kb ^ ((row & 7) << 4)));
            }
            #pragma unroll
            for (int ni = 0; ni < 4; ++ni)
                acc[0][ni] = __builtin_amdgcn_mfma_f32_16x16x32_bf16(
                    af, bfr[ni], acc[0][ni], 0, 0, 0);
        }
        __builtin_amdgcn_s_barrier();
        __builtin_amdgcn_sched_barrier(0);
        if (tt + 2 < 4) stage(lds + (size_t)(tt & 1) * BUFB, (tt + 2) * 64);
    }

    // epilogue 1: f32 C-tile, 32 rows x 1024 B, row-XOR swizzle
    const int lrow = (l >> 4) * 4;
    const int lcol = l & 15;
    #pragma unroll
    for (int ni = 0; ni < 4; ++ni) {
        const int col = wc + ni * 16 + lcol;
        const float bb = bias[col];
        #pragma unroll
        for (int r = 0; r < 4; ++r) {
            const int row = wr + lrow + r;
            *(float*)(lds + row * 1024 + ((col * 4) ^ ((row & 7) << 4))) = acc[0][ni][r] + bb;
        }
    }
    __syncthreads();
    // epilogue 2: one wave per row: + x residual (f32), LN stats, dual bf16 write
    const float4 gv = *reinterpret_cast<const float4*>(g2 + l * 4);
    const float4 bv = *reinterpret_cast<const float4*>(b2 + l * 4);
    #pragma unroll
    for (int it = 0; it < 4; ++it) {
        const int r = w + it * 8;
        float4 v = *(const float4*)(lds + r * 1024 + ((l * 16) ^ ((r & 7) << 4)));
        const float4 rv = *(const float4*)(resid + (size_t)(row0 + r) * Cc + l * 4);
        v.x += rv.x; v.y += rv.y; v.z += rv.z; v.w += rv.w;
        float s  = v.x + v.y + v.z + v.w;
        float s2 = v.x * v.x + v.y * v.y + v.z * v.z + v.w * v.w;
        #pragma unroll
        for (int o = 32; o > 0; o >>= 1) { s += __shfl_down(s, o); s2 += __shfl_down(s2, o); }
        s = __shfl(s, 0); s2 = __shfl(s2, 0);
        const float mean = s * (1.0f / Cc);
        const float rstd = rsqrtf(s2 * (1.0f / Cc) - mean * mean + 1e-5f);
        ushort4 xo;
        xo.x = f2bf(v.x); xo.y = f2bf(v.y); xo.z = f2bf(v.z); xo.w = f2bf(v.w);
        *(ushort4*)(X2 + (size_t)(row0 + r) * Cc + l * 4) = xo;
        ushort4 o;
        o.x = f2bf((v.x - mean) * rstd * gv.x + bv.x);
        o.y = f2bf((v.y - mean) * rstd * gv.y + bv.y);
        o.z = f2bf((v.z - mean) * rstd * gv.z + bv.z);
        o.w = f2bf((v.w - mean) * rstd * gv.w + bv.w);
        *(ushort4*)(Y + (size_t)(row0 + r) * Cc + l * 4) = o;
    }
}

// ---------------- Deformable sampling: fp8 v gather + bf16 off/attn ----------------
__global__ __launch_bounds__(256) void sample_kernel(const unsigned char* __restrict__ Fv,
        const unsigned short* __restrict__ Foa,
        const float* __restrict__ refp, unsigned short* __restrict__ agg) {
    constexpr int PPB = 4;                       // pixels per block
    constexpr int nblk = Mrows / PPB;            // 4096
    const int bid = blockIdx.x;
    const int qi = (bid & 7) * (nblk / 8) + (bid >> 3);   // XCD-chunked swizzle
    const int m0 = qi * PPB;
    const int b = m0 / NPIX;
    const int pix0 = m0 - b * NPIX;
    const int t = threadIdx.x;
    __shared__ int4   s_idx[PPB][72];
    __shared__ float4 s_w[PPB][72];
    __shared__ float  s_lg[PPB][72];

    for (int idx = t; idx < PPB * 72; idx += 256) {
        const int p = idx / 72, hk = idx - p * 72;
        const int head = hk / 9, k = hk - head * 9;
        const int m = m0 + p, pix = pix0 + p;
        const size_t fb = (size_t)m * 256;
        const unsigned int ou = *(const unsigned int*)(Foa + fb + head * 18 + k * 2);
        const float ox = __uint_as_float(ou << 16);
        const float oy = __uint_as_float(ou & 0xffff0000u);
        const float2 rr = *(const float2*)(refp + ((size_t)pix * KPT + k) * 2);
        const float cx = (rr.x + ox + 1.0f) * 0.5f * (Wc - 1);
        const float cy = (rr.y + oy + 1.0f) * 0.5f * (Hc - 1);
        const float fx = floorf(cx), fy = floorf(cy);
        const float wx = cx - fx, wy = cy - fy;
        const int x0 = min(max((int)fx, 0), Wc - 1);
        const int x1 = min(max((int)fx + 1, 0), Wc - 1);
        const int y0 = min(max((int)fy, 0), Hc - 1);
        const int y1 = min(max((int)fy + 1, 0), Hc - 1);
        s_idx[p][hk] = make_int4(y0 * Wc + x0, y0 * Wc + x1, y1 * Wc + x0, y1 * Wc + x1);
        s_w[p][hk] = make_float4((1.0f - wy) * (1.0f - wx), (1.0f - wy) * wx,
                                 wy * (1.0f - wx), wy * wx);
        s_lg[p][hk] = bf2f(Foa[fb + 144 + hk]);
    }
    __syncthreads();
    for (int idx = t; idx < PPB * 72; idx += 256) {
        const int p = idx / 72, hk = idx - p * 72;
        const int h9 = (hk / 9) * 9;
        float mx = -1e30f;
        #pragma unroll
        for (int k = 0; k < 9; ++k) mx = fmaxf(mx, s_lg[p][h9 + k]);
        float sm = 0.0f;
        #pragma unroll
        for (int k = 0; k < 9; ++k) sm += __expf(s_lg[p][h9 + k] - mx);
        const float a = __expf(s_lg[p][hk] - mx) / sm;
        float4 w = s_w[p][hk];
        w.x *= a; w.y *= a; w.z *= a; w.w *= a;
        s_w[p][hk] = w;
    }
    __syncthreads();
    const int p = t >> 6, tl = t & 63;
    const int head = tl >> 3, dq = tl & 7;
    const unsigned char* vb = Fv + (size_t)b * NPIX * 256 + head * HD + dq * 4;
    float a0 = 0.f, a1 = 0.f, a2 = 0.f, a3 = 0.f;
    #pragma unroll
    for (int k = 0; k < 9; ++k) {
        const int hk = head * 9 + k;
        const int4   ix = s_idx[p][hk];
        const float4 ww = s_w[p][hk];
        {
            const uchar4 u = *(const uchar4*)(vb + (size_t)ix.x * 256);
            a0 += fp82f(u.x) * ww.x; a1 += fp82f(u.y) * ww.x;
            a2 += fp82f(u.z) * ww.x; a3 += fp82f(u.w) * ww.x;
        }
        {
            const uchar4 u = *(const uchar4*)(vb + (size_t)ix.y * 256);
            a0 += fp82f(u.x) * ww.y; a1 += fp82f(u.y) * ww.y;
            a2 += fp82f(u.z) * ww.y; a3 += fp82f(u.w) * ww.y;
        }
        {
            const uchar4 u = *(const uchar4*)(vb + (size_t)ix.z * 256);
            a0 += fp82f(u.x) * ww.z; a1 += fp82f(u.y) * ww.z;
            a2 += fp82f(u.z) * ww.z; a3 += fp82f(u.w) * ww.z;
        }
        {
            const uchar4 u = *(const uchar4*)(vb + (size_t)ix.w * 256);
            a0 += fp82f(u.x) * ww.w; a1 += fp82f(u.y) * ww.w;
            a2 += fp82f(u.z) * ww.w; a3 += fp82f(u.w) * ww.w;
        }
    }
    ushort4 o;
    o.x = f2bf(a0); o.y = f2bf(a1); o.z = f2bf(a2); o.w = f2bf(a3);
    *reinterpret_cast<ushort4*>(agg + (size_t)(m0 + p) * Cc + tl * 4) = o;
}

// ---------------- Depthwise 3x3 conv (circular W, zero H) + GELU, fp8 in / fp8 out ----
__global__ __launch_bounds__(256) void dwconv_kernel(const unsigned char* __restrict__ h,
        const float* __restrict__ wdwT, const float* __restrict__ bdw,
        unsigned char* __restrict__ h2) {
    constexpr int NQ = 8;                     // x-positions per block
    constexpr int nblk = Mrows / NQ;          // 2048
    const int bid = blockIdx.x;
    const int qi = (bid & 7) * (nblk / 8) + (bid >> 3);   // XCD-chunked swizzle
    const int m0 = qi * NQ;
    const int b = m0 / NPIX;
    const int pix0 = m0 - b * NPIX;
    const int y = pix0 / Wc, x0 = pix0 - y * Wc;
    const int t = threadIdx.x;
    const int c0 = t * 4;

    float wreg[9][4];
    #pragma unroll
    for (int j = 0; j < 9; ++j) {
        const float4 wv = *reinterpret_cast<const float4*>(wdwT + j * HIDDEN + c0);
        wreg[j][0] = wv.x; wreg[j][1] = wv.y; wreg[j][2] = wv.z; wreg[j][3] = wv.w;
    }

    float acc[NQ][4] = {};
    #pragma unroll
    for (int dy = -1; dy <= 1; ++dy) {
        const int yy = y + dy;
        if (yy < 0 || yy >= Hc) continue;     // zero pad along height
        const size_t rowbase = ((size_t)b * NPIX + (size_t)yy * Wc) * HIDDEN + c0;
        #pragma unroll
        for (int j = 0; j < NQ + 2; ++j) {    // columns x0-1 .. x0+NQ (circular)
            const int xx = (x0 + j - 1 + Wc) & (Wc - 1);
            const uchar4 hv = *reinterpret_cast<const uchar4*>(h + rowbase + (size_t)xx * HIDDEN);
            const float f0 = fp82f(hv.x), f1 = fp82f(hv.y), f2 = fp82f(hv.z), f3 = fp82f(hv.w);
            #pragma unroll
            for (int q = 0; q < NQ; ++q) {
                if (q >= j - 2 && q <= j) {
                    const int wj = (dy + 1) * 3 + (j - q);
                    acc[q][0] += f0 * wreg[wj][0];
                    acc[q][1] += f1 * wreg[wj][1];
                    acc[q][2] += f2 * wreg[wj][2];
                    acc[q][3] += f3 * wreg[wj][3];
                }
            }
        }
    }
    const float4 bb = *reinterpret_cast<const float4*>(bdw + c0);
    #pragma unroll
    for (int q = 0; q < NQ; ++q) {
        uchar4 o;
        o.x = f2fp8(gelu_exact(acc[q][0] + bb.x));
        o.y = f2fp8(gelu_exact(acc[q][1] + bb.y));
        o.z = f2fp8(gelu_exact(acc[q][2] + bb.z));
        o.w = f2fp8(gelu_exact(acc[q][3] + bb.w));
        *reinterpret_cast<uchar4*>(h2 + (size_t)(m0 + q) * HIDDEN + c0) = o;
    }
}

extern "C" void kernel_launch(void* const* d_in, const int* in_sizes, int n_in,
                              void* d_out, int out_size, void* d_ws, size_t ws_size,
                              hipStream_t stream) {
    const float* x      = (const float*)d_in[0];
    const float* refp   = (const float*)d_in[1];
    const float* ln1_g  = (const float*)d_in[2];
    const float* ln1_b  = (const float*)d_in[3];
    const float* w_v    = (const float*)d_in[4];
    const float* b_v    = (const float*)d_in[5];
    const float* w_off  = (const float*)d_in[6];
    const float* b_off  = (const float*)d_in[7];
    const float* w_attn = (const float*)d_in[8];
    const float* b_attn = (const float*)d_in[9];
    const float* w_out  = (const float*)d_in[10];
    const float* b_out  = (const float*)d_in[11];
    const float* ln2_g  = (const float*)d_in[12];
    const float* ln2_b  = (const float*)d_in[13];
    const float* w1     = (const float*)d_in[14];
    const float* b1     = (const float*)d_in[15];
    const float* w_dw   = (const float*)d_in[16];
    const float* b_dw   = (const float*)d_in[17];
    const float* w2     = (const float*)d_in[18];
    const float* b2     = (const float*)d_in[19];
    float* out = (float*)d_out;

    // Workspace layout (bytes). Each region written by one kernel, read by LATER
    // kernels only; no intra-kernel read/write aliasing (R12 lesson).
    //  [0,  8M): A    = xn (s1) -> agg (s3); dead after s4
    //  [8, 16M): Foa  bf16 off/attn (s2); dead after s3
    //  [16,20M): Fv   fp8 v (s2); dead after s3
    //  [8, 16M): y    = LN2 out bf16 (s4, reuses dead Foa); dead after s5
    //  [16,24M): x2b  bf16 (s4, reuses dead Fv); read by s7
    //  [32,48M): h    fp8 (s5); dead after s6
    //  [48,64M): h2   fp8 (s6, fresh); dead after s7
    //  [64M,..): weights: qkvT/woutT/w1T bf16, w2T8 fp8(x32), wdwT f32, qkvB
    char* wsb = (char*)d_ws;
    unsigned short* Abuf = (unsigned short*)(wsb);
    unsigned short* Foa  = (unsigned short*)(wsb + (8ull  << 20));
    unsigned char*  Fv   = (unsigned char*)(wsb + (16ull << 20));
    unsigned short* ybuf = (unsigned short*)(wsb + (8ull  << 20));
    unsigned short* x2b  = (unsigned short*)(wsb + (16ull << 20));
    unsigned char*  hbuf = (unsigned char*)(wsb + (32ull << 20));
    unsigned char*  h2   = (unsigned char*)(wsb + (48ull << 20));
    size_t woff = 64ull << 20;
    unsigned short* qkvT = (unsigned short*)(wsb + woff); woff += (size_t)NQKV * 256 * 2;
    unsigned short* woutT= (unsigned short*)(wsb + woff); woff += 256 * 256 * 2;
    unsigned short* w1T  = (unsigned short*)(wsb + woff); woff += 1024 * 256 * 2;
    unsigned char*  w2T8 = (unsigned char*)(wsb + woff);  woff += 256 * 1024;
    float*          wdwT = (float*)(wsb + woff);          woff += 9 * 1024 * 4;
    float*          qkvB = (float*)(wsb + woff);

    // 1. merged LN1 + weight prep (one dispatch)
    prepln_kernel<<<Mrows / 4 + NQKV + 256 + 1024 + 256 + 9, 256, 0, stream>>>(
        x, ln1_g, ln1_b, Abuf,
        w_v, b_v, w_off, b_off, w_attn, b_attn, w_out, w1, w2, w_dw,
        qkvT, qkvB, woutT, w1T, w2T8, wdwT);
    // 2. QKV GEMM, dual epilogue: v -> Fv fp8, off/attn -> Foa bf16
    qkv_gemm<<<dim3(Mrows / 128, NQKV / 128), 512, 0, stream>>>(
        Abuf, qkvT, qkvB, Fv, Foa, 256);
    // 3. deformable sampling (fp8 v gather) -> agg (A region)
    sample_kernel<<<Mrows / 4, 256, 0, stream>>>(Fv, Foa, refp, Abuf);
    // 4. fused: x2 = x + agg @ w_out + b_out (bf16) ; y = LN2(x2) (bf16)
    wout_ln2_kernel<<<Mrows / 32, 512, 0, stream>>>(
        Abuf, woutT, b_out, x, ln2_g, ln2_b, x2b, ybuf);
    // 5. h = gelu(y @ w1 + b1) -> fp8 e4m3
    mfma_gemm<128, true, false, unsigned char><<<dim3(Mrows / 128, 1024 / 128), 512, 0, stream>>>(
        ybuf, w1T, b1, nullptr, hbuf, 1024, 256);
    // 6. depthwise conv + gelu: fp8 in -> fp8 h2
    dwconv_kernel<<<Mrows / 8, 256, 0, stream>>>(hbuf, wdwT, b_dw, h2);
    // 7. out = x2b + (h2 @ w2T8^T)/32 + b2  (sole writer of d_out)
    w2_gemm_fp8<<<dim3(Mrows / 128, 256 / 64), 512, 0, stream>>>(
        h2, w2T8, b2, x2b, out, 256, 1024);
}